// Round 7
// baseline (195.548 us; speedup 1.0000x reference)
//
#include <hip/hip_runtime.h>

// DetectPostProcess: softmax -> decode -> per-(b,c) top-200 -> greedy NMS.
// Decisions (ordering, top-K membership, IoU>0.5) identical to the round-2..6
// passing kernels (f64 everywhere it matters; f32 IoU fast path guarded by
// exact f64 recompute within |margin|<=1e-5, error bound ~3e-7).
// Round 7: select split into high-occupancy collect_kernel (pivot + global
// candidate append) and slim per-(b,c) nms_kernel.
// Outputs: objs [B,NC,K,5] then keep [B,NC,K] (as 0.0/1.0), flat in d_out.

constexpr int B = 32;
constexpr int A = 32768;     // power of two
constexpr int ABITS = 15;    // log2(A)
constexpr int NCP1 = 21;
constexpr int NC = 20;
constexpr int K = 200;
constexpr int NBIN = 576;    // key range 0x3D4C..0x3F80 = 564 values
constexpr int CAP = 512;     // candidate capacity per (b,c)
#define KBASE 0x3D4Cu        // bits(0.05f) >> 16; min nonzero key

#define TH_CONF 0.05
#define TH_IOU  0.5

// ============================ FAST PATH =====================================
// prep_fast: per (b,a): m (f32 max), S (f64 sum), and 20 transposed u16 keys.
__global__ __launch_bounds__(256) void prep_fast(
    const float* __restrict__ conf, float* __restrict__ marr,
    double* __restrict__ sarr, unsigned short* __restrict__ keys) {
  int idx = blockIdx.x * 256 + threadIdx.x;   // 0 .. B*A-1
  int b = idx >> ABITS;
  int a = idx & (A - 1);
  const float* cp = conf + (size_t)idx * NCP1;
  float x[NCP1];
#pragma unroll
  for (int i = 0; i < NCP1; ++i) x[i] = cp[i];
  float m = x[0];
#pragma unroll
  for (int i = 1; i < NCP1; ++i) m = fmaxf(m, x[i]);
  double e[NCP1];
  double S = 0.0;
#pragma unroll
  for (int i = 0; i < NCP1; ++i) {
    e[i] = exp((double)x[i] - (double)m);
    S += e[i];
  }
  marr[idx] = m;
  sarr[idx] = S;
  double rs = 1.0 / S;
  size_t kbase = ((size_t)(b * NC) << ABITS) + a;
#pragma unroll
  for (int c = 0; c < NC; ++c) {
    double sd = e[c + 1] * rs;                 // ~1ulp from e/S; key-grade only
    unsigned short key = 0;
    if (sd >= TH_CONF) {
      float f = (float)sd;
      key = (unsigned short)(__float_as_uint(f) >> 16);
    }
    keys[kbase + ((size_t)c << ABITS)] = key;
  }
}

// prehist: 4 blocks per (b,c); LDS-aggregated 576-bin histogram -> global.
__global__ __launch_bounds__(256) void prehist_kernel(
    const unsigned short* __restrict__ keys, unsigned* __restrict__ ghist) {
  __shared__ unsigned h[NBIN];
  int tid = threadIdx.x;
  int blk = blockIdx.x;          // 0..B*NC*4-1
  int bc = blk >> 2, chunk = blk & 3;
  for (int i = tid; i < NBIN; i += 256) h[i] = 0;
  __syncthreads();
  const uint4* kv = (const uint4*)(keys + ((size_t)bc << ABITS) + chunk * (A / 4));
  for (int i = tid; i < A / 4 / 8; i += 256) {   // 1024 uint4s
    uint4 v = kv[i];
    unsigned w[4] = {v.x, v.y, v.z, v.w};
#pragma unroll
    for (int q = 0; q < 4; ++q) {
      unsigned lo = w[q] & 0xFFFFu, hi = w[q] >> 16;
      if (lo) atomicAdd(&h[min(lo - KBASE, (unsigned)(NBIN - 1))], 1u);
      if (hi) atomicAdd(&h[min(hi - KBASE, (unsigned)(NBIN - 1))], 1u);
    }
  }
  __syncthreads();
  unsigned* grow = ghist + (size_t)bc * NBIN;
  for (int i = tid; i < NBIN; i += 256) {
    unsigned cnt = h[i];
    if (cnt) atomicAdd(&grow[i], cnt);
  }
}

// collect_kernel: 4 blocks per (b,c). Wave 0 derives the pivot from ghist
// (same crossing condition as rounds 4-6), then all threads scan their key
// chunk appending candidate anchor ids to global clist via gctr.
__global__ __launch_bounds__(256) void collect_kernel(
    const unsigned short* __restrict__ keys, const unsigned* __restrict__ ghist,
    unsigned* __restrict__ gctr, int* __restrict__ clist) {
  __shared__ unsigned sh_pivot;
  int tid = threadIdx.x;
  int blk = blockIdx.x;
  int bc = blk >> 2, chunk = blk & 3;

  if (tid < 64) {
    const unsigned* grow = ghist + (size_t)bc * NBIN;
    unsigned h[9];
    unsigned lsum = 0;
#pragma unroll
    for (int j = 0; j < 9; ++j) { h[j] = grow[tid * 9 + j]; lsum += h[j]; }
    unsigned S = lsum;                    // inclusive suffix over lanes
#pragma unroll
    for (int d = 1; d < 64; d <<= 1) {
      unsigned o = __shfl_down(S, d, 64);
      if (tid + d < 64) S += o;
    }
    unsigned total = __shfl(S, 0, 64);
    unsigned t = S - lsum;                // cnt_ge(first bin of lane tid+1)
    unsigned selbin = 0xFFFFFFFFu;
#pragma unroll
    for (int j = 8; j >= 0; --j) {        // walk bins high -> low
      unsigned tj = t + h[j];             // cnt_ge(tid*9 + j)
      if (tj >= (unsigned)K && t < (unsigned)K) selbin = tid * 9 + j;
      t = tj;
    }
#pragma unroll
    for (int d = 1; d < 64; d <<= 1) {    // unique -> min-reduce
      unsigned o = __shfl_xor(selbin, d, 64);
      selbin = min(selbin, o);
    }
    if (tid == 0)
      sh_pivot = (total <= (unsigned)K || selbin == 0xFFFFFFFFu)
                     ? KBASE : (KBASE + selbin);
  }
  __syncthreads();
  unsigned pivot16 = sh_pivot;

  const uint4* kv = (const uint4*)(keys + ((size_t)bc << ABITS) + chunk * (A / 4));
  int abase = chunk * (A / 4);
  for (int i = tid; i < A / 4 / 8; i += 256) {   // 1024 uint4s
    uint4 v = kv[i];
    unsigned w[4] = {v.x, v.y, v.z, v.w};
#pragma unroll
    for (int q = 0; q < 4; ++q) {
      unsigned lo = w[q] & 0xFFFFu, hi = w[q] >> 16;
      if (lo >= pivot16) {
        unsigned pos = atomicAdd(&gctr[bc], 1u);
        if (pos < (unsigned)CAP) clist[bc * CAP + pos] = abase + i * 8 + q * 2 + 0;
      }
      if (hi >= pivot16) {
        unsigned pos = atomicAdd(&gctr[bc], 1u);
        if (pos < (unsigned)CAP) clist[bc * CAP + pos] = abase + i * 8 + q * 2 + 1;
      }
    }
  }
}

// f64 box decode for one anchor.
__device__ __forceinline__ void decode_d(const float* __restrict__ loc,
                                         const float* __restrict__ anchor,
                                         size_t ba, int a, double* o) {
  const float* lp = loc + ba * 4;
  const float* ap = anchor + (size_t)a * 4;
  double l0 = lp[0], l1 = lp[1], l2 = lp[2], l3 = lp[3];
  double cx = ap[0], cy = ap[1], aw = ap[2], ah = ap[3];
  double X = (l0 * 0.125) * aw + cx;
  double Y = (l1 * 0.125) * ah + cy;
  double bw = exp(l2 * 0.125) * aw;
  double bh = exp(l3 * 0.125) * ah;
  o[0] = X - bw * 0.5;
  o[1] = Y - bh * 0.5;
  o[2] = X + bw * 0.5;
  o[3] = Y + bh * 0.5;
}

// nms_kernel: one block per (b,c). Exact f64 rescore of candidates, shfl
// bitonic sort, f64 decode, f32 IoU with exact f64 guard, greedy scan, write.
__global__ __launch_bounds__(512) void nms_kernel(
    const float* __restrict__ conf, const float* __restrict__ marr,
    const double* __restrict__ sarr, const float* __restrict__ loc,
    const float* __restrict__ anchor, const unsigned* __restrict__ gctr,
    const int* __restrict__ clist, float* __restrict__ out) {
  constexpr int NT = 512;
  __shared__ unsigned long long cand[512];
  __shared__ double cbd5[K * 5];        // f64 x0,y0,x1,y1,area (guard path)
  __shared__ float cb32[K * 5];         // f32 copy (fast path)
  __shared__ unsigned rows[K * 8];
  __shared__ unsigned kp[K];

  int tid = threadIdx.x;
  int bc = blockIdx.x;
  int b = bc / NC, c = bc % NC;
  size_t base = (size_t)b << ABITS;

  unsigned ccount = gctr[bc];
  if (ccount > (unsigned)CAP) ccount = CAP;
  unsigned Ct = ccount < (unsigned)K ? ccount : (unsigned)K;

  // ---- 1. exact f64 scores for candidates; build sort keys ----
  for (int i = tid; i < 512; i += NT) {
    unsigned long long key = 0ull;
    if ((unsigned)i < ccount) {
      int a = clist[bc * CAP + i];
      size_t ba = base + a;
      double sd = exp((double)conf[ba * NCP1 + (c + 1)] - (double)marr[ba]) / sarr[ba];
      if (sd >= TH_CONF) {
        unsigned long long db = (unsigned long long)__double_as_longlong(sd);
        key = (db & 0xFFFFFFFFFFFF0000ull) |
              (unsigned long long)(65535u - (unsigned)a);
      }
    }
    cand[i] = key;
  }
  __syncthreads();

  // ---- 2. bitonic sort desc (shfl for j<64): (score bits desc, idx asc) ----
  unsigned n2 = (ccount <= 256u) ? 256u : 512u;
  unsigned long long v = ((unsigned)tid < n2) ? cand[tid] : 0ull;
  for (unsigned k2 = 2; k2 <= n2; k2 <<= 1) {
    for (unsigned j = k2 >> 1; j > 0; j >>= 1) {
      unsigned long long p;
      if (j >= 64) {
        __syncthreads();
        if ((unsigned)tid < n2) cand[tid] = v;
        __syncthreads();
        p = ((unsigned)tid < n2) ? cand[tid ^ j] : 0ull;
      } else {
        p = __shfl_xor(v, (int)j, 64);
      }
      if ((unsigned)tid < n2) {
        bool desc = ((tid & (int)k2) == 0);
        bool lower = ((tid & (int)j) == 0);
        bool takemax = (lower == desc);
        bool vge = (v >= p);
        v = takemax ? (vge ? v : p) : (vge ? p : v);
      }
    }
  }
  __syncthreads();
  if ((unsigned)tid < n2) cand[tid] = v;
  __syncthreads();

  // ---- 3. decode candidate boxes (f64) + f32 mirror ----
  if ((unsigned)tid < Ct) {
    unsigned long long key = cand[tid];
    bool valid = (key >> 16) != 0ull;
    double o[4] = {0.0, 0.0, 0.0, 0.0};
    double aa = 0.0;
    if (valid) {
      unsigned a = (65535u - (unsigned)(key & 0xFFFFull)) & (A - 1);
      decode_d(loc, anchor, base + a, a, o);
      aa = (o[2] - o[0]) * (o[3] - o[1]);
    }
    cbd5[tid * 5 + 0] = o[0]; cbd5[tid * 5 + 1] = o[1];
    cbd5[tid * 5 + 2] = o[2]; cbd5[tid * 5 + 3] = o[3];
    cbd5[tid * 5 + 4] = aa;
    cb32[tid * 5 + 0] = (float)o[0]; cb32[tid * 5 + 1] = (float)o[1];
    cb32[tid * 5 + 2] = (float)o[2]; cb32[tid * 5 + 3] = (float)o[3];
    cb32[tid * 5 + 4] = (float)aa;
  }
  __syncthreads();

  // ---- 4. IoU rows: f32 fast path, exact f64 when |margin| <= 1e-5 ----
  int Cti = (int)Ct;
  int total_iw = Cti * 8;
  for (int id = tid; id < total_iw; id += NT) {
    int i = id % Cti;
    int w = id / Cti;
    float xi0 = cb32[i * 5 + 0], yi0 = cb32[i * 5 + 1];
    float xi1 = cb32[i * 5 + 2], yi1 = cb32[i * 5 + 3];
    float ai = cb32[i * 5 + 4];
    unsigned bits = 0;
    int j0 = w * 32;
    for (int jj = 0; jj < 32; ++jj) {
      int j = j0 + jj;
      if (j < Cti) {
        float ltx = fmaxf(xi0, cb32[j * 5 + 0]);
        float lty = fmaxf(yi0, cb32[j * 5 + 1]);
        float rbx = fminf(xi1, cb32[j * 5 + 2]);
        float rby = fminf(yi1, cb32[j * 5 + 3]);
        float iw = fmaxf(rbx - ltx, 0.f);
        float ih = fmaxf(rby - lty, 0.f);
        float inter = iw * ih;
        float den = ai + cb32[j * 5 + 4] - inter + 1e-9f;
        float dmar = inter - 0.5f * den;
        bool bit;
        if (fabsf(dmar) > 1e-5f) {
          bit = dmar > 0.f;
        } else {
          double LTX = fmax(cbd5[i * 5 + 0], cbd5[j * 5 + 0]);
          double LTY = fmax(cbd5[i * 5 + 1], cbd5[j * 5 + 1]);
          double RBX = fmin(cbd5[i * 5 + 2], cbd5[j * 5 + 2]);
          double RBY = fmin(cbd5[i * 5 + 3], cbd5[j * 5 + 3]);
          double IW = fmax(RBX - LTX, 0.0);
          double IH = fmax(RBY - LTY, 0.0);
          double INTER = IW * IH;
          double DEN = cbd5[i * 5 + 4] + cbd5[j * 5 + 4] - INTER + 1e-9;
          bit = INTER > 0.5 * DEN;
        }
        if (bit) bits |= (1u << jj);
      }
    }
    rows[i * 8 + w] = bits;
  }
  __syncthreads();

  // ---- 5. greedy scan (wave 0; matches lax.scan semantics) ----
  if (tid < 64) {
    unsigned supp = 0;
    for (int i = 0; i < Cti; ++i) {
      unsigned wsrc = __shfl(supp, i >> 5);
      bool kkeep = ((wsrc >> (i & 31)) & 1u) == 0u;
      if (tid == 0) kp[i] = kkeep ? 1u : 0u;
      unsigned rw = (tid < 8) ? rows[i * 8 + tid] : 0u;
      if (kkeep) supp |= rw;
    }
  }
  __syncthreads();

  // ---- 6. write objs + keep ----
  if (tid < K) {
    bool kkeep = ((unsigned)tid < Ct) && (kp[tid] != 0u) && ((cand[tid] >> 16) != 0ull);
    float o0 = 0.f, o1 = 0.f, o2 = 0.f, o3 = 0.f, o4 = 0.f;
    if (kkeep) {
      o0 = (float)cbd5[tid * 5 + 0]; o1 = (float)cbd5[tid * 5 + 1];
      o2 = (float)cbd5[tid * 5 + 2]; o3 = (float)cbd5[tid * 5 + 3];
      double sd = __longlong_as_double(
          (long long)(cand[tid] & 0xFFFFFFFFFFFF0000ull));
      o4 = (float)sd;
    }
    size_t ob = ((size_t)bc * K + tid) * 5;
    out[ob + 0] = o0; out[ob + 1] = o1; out[ob + 2] = o2;
    out[ob + 3] = o3; out[ob + 4] = o4;
    out[(size_t)B * NC * K * 5 + (size_t)bc * K + tid] = kkeep ? 1.f : 0.f;
  }
}

// ==================== FALLBACK: round-6 fused select (passing) ==============
__global__ __launch_bounds__(512) void select_fast(
    const float* __restrict__ conf, const float* __restrict__ marr,
    const double* __restrict__ sarr, const float* __restrict__ loc,
    const float* __restrict__ anchor, const unsigned short* __restrict__ keys,
    const unsigned* __restrict__ ghist, float* __restrict__ out) {
  constexpr int NT = 512;
  __shared__ unsigned hist[NBIN];
  __shared__ unsigned wtot[8], wsuf[8];
  __shared__ unsigned long long cand[512];
  __shared__ int clist[512];
  __shared__ double cbd5[K * 5];
  __shared__ unsigned rows[K * 8];
  __shared__ unsigned kp[K];
  __shared__ unsigned sh_cnt, sh_selbin, sh_total;

  int tid = threadIdx.x;
  unsigned lane = tid & 63, wid = tid >> 6;
  int bc = blockIdx.x;
  int b = bc / NC, c = bc % NC;
  size_t base = (size_t)b << ABITS;
  const unsigned short* krow = keys + ((size_t)bc << ABITS);
  const uint4* kv = (const uint4*)krow;

  if (tid == 0) sh_cnt = 0;

  unsigned h0 = 0, h1 = 0;
  if (ghist) {
    if (tid < NBIN / 2) {
      uint2 hh = ((const uint2*)(ghist + (size_t)bc * NBIN))[tid];
      h0 = hh.x; h1 = hh.y;
    }
  } else {
    for (int i = tid; i < NBIN; i += NT) hist[i] = 0;
    __syncthreads();
    for (int i = tid; i < A / 8; i += NT) {
      uint4 v = kv[i];
      unsigned w[4] = {v.x, v.y, v.z, v.w};
#pragma unroll
      for (int q = 0; q < 4; ++q) {
        unsigned lo = w[q] & 0xFFFFu, hi = w[q] >> 16;
        if (lo) atomicAdd(&hist[min(lo - KBASE, (unsigned)(NBIN - 1))], 1u);
        if (hi) atomicAdd(&hist[min(hi - KBASE, (unsigned)(NBIN - 1))], 1u);
      }
    }
    __syncthreads();
    if (tid < NBIN / 2) { h0 = hist[2 * tid]; h1 = hist[2 * tid + 1]; }
  }

  unsigned s = h0 + h1;
  unsigned S = s;
#pragma unroll
  for (int d = 1; d < 64; d <<= 1) {
    unsigned o = __shfl_down(S, d, 64);
    if (lane + d < 64) S += o;
  }
  if (lane == 0) wtot[wid] = S;
  __syncthreads();
  if (tid < 8) {
    unsigned acc = 0;
    for (int w2 = tid + 1; w2 < 8; ++w2) acc += wtot[w2];
    wsuf[tid] = acc;
    if (tid == 0) sh_total = acc + wtot[0];
  }
  __syncthreads();
  unsigned Sfull = S + wsuf[wid];
  unsigned above2 = Sfull - s;
  unsigned cg1 = h1 + above2;
  unsigned cg0 = h0 + cg1;
  if (cg1 >= (unsigned)K && above2 < (unsigned)K) sh_selbin = tid * 2 + 1;
  if (cg0 >= (unsigned)K && cg1 < (unsigned)K) sh_selbin = tid * 2 + 0;
  __syncthreads();
  unsigned pivot16 = (sh_total <= (unsigned)K) ? KBASE : (KBASE + sh_selbin);

  for (int i = tid; i < A / 8; i += NT) {
    uint4 v = kv[i];
    unsigned w[4] = {v.x, v.y, v.z, v.w};
#pragma unroll
    for (int q = 0; q < 4; ++q) {
      unsigned lo = w[q] & 0xFFFFu, hi = w[q] >> 16;
      if (lo >= pivot16) {
        unsigned pos = atomicAdd(&sh_cnt, 1u);
        if (pos < 512) clist[pos] = i * 8 + q * 2 + 0;
      }
      if (hi >= pivot16) {
        unsigned pos = atomicAdd(&sh_cnt, 1u);
        if (pos < 512) clist[pos] = i * 8 + q * 2 + 1;
      }
    }
  }
  __syncthreads();
  unsigned ccount = sh_cnt < 512u ? sh_cnt : 512u;
  unsigned Ct = ccount < (unsigned)K ? ccount : (unsigned)K;

  for (int i = tid; i < 512; i += NT) {
    unsigned long long key = 0ull;
    if ((unsigned)i < ccount) {
      int a = clist[i];
      size_t ba = base + a;
      double sd = exp((double)conf[ba * NCP1 + (c + 1)] - (double)marr[ba]) / sarr[ba];
      if (sd >= TH_CONF) {
        unsigned long long db = (unsigned long long)__double_as_longlong(sd);
        key = (db & 0xFFFFFFFFFFFF0000ull) |
              (unsigned long long)(65535u - (unsigned)a);
      }
    }
    cand[i] = key;
  }
  __syncthreads();

  unsigned n2 = (ccount <= 256u) ? 256u : 512u;
  unsigned long long v = ((unsigned)tid < n2) ? cand[tid] : 0ull;
  for (unsigned k2 = 2; k2 <= n2; k2 <<= 1) {
    for (unsigned j = k2 >> 1; j > 0; j >>= 1) {
      unsigned long long p;
      if (j >= 64) {
        __syncthreads();
        if ((unsigned)tid < n2) cand[tid] = v;
        __syncthreads();
        p = ((unsigned)tid < n2) ? cand[tid ^ j] : 0ull;
      } else {
        p = __shfl_xor(v, (int)j, 64);
      }
      if ((unsigned)tid < n2) {
        bool desc = ((tid & (int)k2) == 0);
        bool lower = ((tid & (int)j) == 0);
        bool takemax = (lower == desc);
        bool vge = (v >= p);
        v = takemax ? (vge ? v : p) : (vge ? p : v);
      }
    }
  }
  __syncthreads();
  if ((unsigned)tid < n2) cand[tid] = v;
  __syncthreads();

  if ((unsigned)tid < Ct) {
    unsigned long long key = cand[tid];
    bool valid = (key >> 16) != 0ull;
    double o[4] = {0.0, 0.0, 0.0, 0.0};
    double aa = 0.0;
    if (valid) {
      unsigned a = (65535u - (unsigned)(key & 0xFFFFull)) & (A - 1);
      decode_d(loc, anchor, base + a, a, o);
      aa = (o[2] - o[0]) * (o[3] - o[1]);
    }
    cbd5[tid * 5 + 0] = o[0]; cbd5[tid * 5 + 1] = o[1];
    cbd5[tid * 5 + 2] = o[2]; cbd5[tid * 5 + 3] = o[3];
    cbd5[tid * 5 + 4] = aa;
  }
  __syncthreads();

  int total_iw = (int)Ct * 8;
  for (int id = tid; id < total_iw; id += NT) {
    int i = id % (int)Ct;
    int w = id / (int)Ct;
    double xi0 = cbd5[i * 5 + 0], yi0 = cbd5[i * 5 + 1];
    double xi1 = cbd5[i * 5 + 2], yi1 = cbd5[i * 5 + 3];
    double ai = cbd5[i * 5 + 4];
    unsigned bits = 0;
    int j0 = w * 32;
    for (int jj = 0; jj < 32; ++jj) {
      int j = j0 + jj;
      if (j < (int)Ct) {
        double ltx = fmax(xi0, cbd5[j * 5 + 0]);
        double lty = fmax(yi0, cbd5[j * 5 + 1]);
        double rbx = fmin(xi1, cbd5[j * 5 + 2]);
        double rby = fmin(yi1, cbd5[j * 5 + 3]);
        double iw = fmax(rbx - ltx, 0.0);
        double ih = fmax(rby - lty, 0.0);
        double inter = iw * ih;
        double den = ai + cbd5[j * 5 + 4] - inter + 1e-9;
        if (inter > 0.5 * den) bits |= (1u << jj);
      }
    }
    rows[i * 8 + w] = bits;
  }
  __syncthreads();

  if (tid < 64) {
    unsigned supp = 0;
    for (int i = 0; i < (int)Ct; ++i) {
      unsigned wsrc = __shfl(supp, i >> 5);
      bool kkeep = ((wsrc >> (i & 31)) & 1u) == 0u;
      if (tid == 0) kp[i] = kkeep ? 1u : 0u;
      unsigned rw = (tid < 8) ? rows[i * 8 + tid] : 0u;
      if (kkeep) supp |= rw;
    }
  }
  __syncthreads();

  if (tid < K) {
    bool kkeep = ((unsigned)tid < Ct) && (kp[tid] != 0u) && ((cand[tid] >> 16) != 0ull);
    float o0 = 0.f, o1 = 0.f, o2 = 0.f, o3 = 0.f, o4 = 0.f;
    if (kkeep) {
      o0 = (float)cbd5[tid * 5 + 0]; o1 = (float)cbd5[tid * 5 + 1];
      o2 = (float)cbd5[tid * 5 + 2]; o3 = (float)cbd5[tid * 5 + 3];
      double sd = __longlong_as_double(
          (long long)(cand[tid] & 0xFFFFFFFFFFFF0000ull));
      o4 = (float)sd;
    }
    size_t ob = ((size_t)bc * K + tid) * 5;
    out[ob + 0] = o0; out[ob + 1] = o1; out[ob + 2] = o2;
    out[ob + 3] = o3; out[ob + 4] = o4;
    out[(size_t)B * NC * K * 5 + (size_t)bc * K + tid] = kkeep ? 1.f : 0.f;
  }
}

// ============================ FALLBACK PATH (round-2, passing) ==============
__global__ __launch_bounds__(256) void prep_kernel(
    const float* __restrict__ conf, float* __restrict__ marr,
    double* __restrict__ sarr) {
  int idx = blockIdx.x * 256 + threadIdx.x;
  const float* cp = conf + (size_t)idx * NCP1;
  float x[NCP1];
#pragma unroll
  for (int i = 0; i < NCP1; ++i) x[i] = cp[i];
  float m = x[0];
#pragma unroll
  for (int i = 1; i < NCP1; ++i) m = fmaxf(m, x[i]);
  double S = 0.0;
#pragma unroll
  for (int i = 0; i < NCP1; ++i) S += exp((double)x[i] - (double)m);
  marr[idx] = m;
  sarr[idx] = S;
}

__device__ __forceinline__ double get_sd(const float* __restrict__ conf,
                                         const float* __restrict__ marr,
                                         const double* __restrict__ sarr,
                                         size_t ba, int c) {
  const float* cp = conf + ba * NCP1;
  float m;
  double S;
  if (sarr) {
    m = marr[ba];
    S = sarr[ba];
  } else {
    m = cp[0];
    for (int i = 1; i < NCP1; ++i) m = fmaxf(m, cp[i]);
    S = 0.0;
    for (int i = 0; i < NCP1; ++i) S += exp((double)cp[i] - (double)m);
  }
  return exp((double)cp[c + 1] - (double)m) / S;
}

__global__ __launch_bounds__(256) void select_nms_kernel(
    const float* __restrict__ conf, const float* __restrict__ marr,
    const double* __restrict__ sarr, const float* __restrict__ loc,
    const float* __restrict__ anchor, float* __restrict__ out) {
  __shared__ __align__(16) unsigned short s16[A];
  __shared__ unsigned hist[256];
  __shared__ unsigned scan0[256];
  __shared__ unsigned long long cand[512];
  __shared__ unsigned sh_cnt, sh_selbin, sh_need, sh_ctot;

  double* cbd = (double*)s16;
  double* ar = cbd + K * 4;
  unsigned* rows = (unsigned*)(ar + K);
  unsigned* kp = rows + K * 8;

  int tid = threadIdx.x;
  int bc = blockIdx.x;
  int b = bc / NC, c = bc % NC;
  size_t base = (size_t)b << ABITS;

  for (int a = tid; a < A; a += 256) {
    double sd = get_sd(conf, marr, sarr, base + a, c);
    unsigned short key = 0;
    if (sd >= TH_CONF) {
      float f = (float)sd;
      key = (unsigned short)(__float_as_uint(f) >> 16);
    }
    s16[a] = key;
  }
  __syncthreads();

  unsigned need = K, pfx = 0;
  bool smallcase = false;
  for (int p = 0; p < 2; ++p) {
    hist[tid] = 0;
    __syncthreads();
    for (int a = tid; a < A; a += 256) {
      unsigned v = s16[a];
      if (v && (p == 0 || (v >> 8) == pfx))
        atomicAdd(&hist[(p == 0) ? (v >> 8) : (v & 0xFFu)], 1u);
    }
    __syncthreads();
    scan0[tid] = hist[tid];
    __syncthreads();
    for (int st = 1; st < 256; st <<= 1) {
      unsigned mine = scan0[tid];
      unsigned oth = (tid + st < 256) ? scan0[tid + st] : 0u;
      __syncthreads();
      scan0[tid] = mine + oth;
      __syncthreads();
    }
    if (p == 0) {
      if (tid == 0) sh_ctot = scan0[0];
      __syncthreads();
      if (sh_ctot <= (unsigned)K) { smallcase = true; break; }
    }
    unsigned nxt = (tid == 255) ? 0u : scan0[tid + 1];
    if (scan0[tid] >= need && nxt < need) { sh_selbin = tid; sh_need = need - nxt; }
    __syncthreads();
    pfx = (pfx << 8) | sh_selbin;
    need = sh_need;
    __syncthreads();
  }
  unsigned pivot16 = smallcase ? 0x3D4Cu : pfx;

  if (tid == 0) sh_cnt = 0;
  __syncthreads();
  for (int a = tid; a < A; a += 256) {
    double sd = get_sd(conf, marr, sarr, base + a, c);
    if (sd >= TH_CONF) {
      float f = (float)sd;
      if ((__float_as_uint(f) >> 16) >= pivot16) {
        unsigned pos = atomicAdd(&sh_cnt, 1u);
        if (pos < 512) {
          unsigned long long db = (unsigned long long)__double_as_longlong(sd);
          cand[pos] = (db & 0xFFFFFFFFFFFF0000ull) |
                      (unsigned long long)(65535u - (unsigned)a);
        }
      }
    }
  }
  __syncthreads();
  unsigned ccount = sh_cnt < 512u ? sh_cnt : 512u;
  unsigned Ct = ccount < (unsigned)K ? ccount : (unsigned)K;
  for (int i = tid; i < 512; i += 256)
    if ((unsigned)i >= ccount) cand[i] = 0ull;
  __syncthreads();

  for (unsigned k2 = 2; k2 <= 512; k2 <<= 1) {
    for (unsigned j = k2 >> 1; j > 0; j >>= 1) {
      for (unsigned i = tid; i < 512; i += 256) {
        unsigned ixj = i ^ j;
        if (ixj > i) {
          unsigned long long va = cand[i], vb = cand[ixj];
          bool desc = ((i & k2) == 0);
          if (desc ? (va < vb) : (va > vb)) { cand[i] = vb; cand[ixj] = va; }
        }
      }
      __syncthreads();
    }
  }

  if ((unsigned)tid < Ct) {
    unsigned a = 65535u - (unsigned)(cand[tid] & 0xFFFFull);
    double o[4];
    decode_d(loc, anchor, base + a, a, o);
    cbd[tid * 4 + 0] = o[0]; cbd[tid * 4 + 1] = o[1];
    cbd[tid * 4 + 2] = o[2]; cbd[tid * 4 + 3] = o[3];
    ar[tid] = (o[2] - o[0]) * (o[3] - o[1]);
  }
  __syncthreads();

  for (int id = tid; id < (int)Ct * 8; id += 256) {
    int i = id >> 3, w = id & 7;
    double xi0 = cbd[i * 4 + 0], yi0 = cbd[i * 4 + 1];
    double xi1 = cbd[i * 4 + 2], yi1 = cbd[i * 4 + 3];
    double ai = ar[i];
    unsigned bits = 0;
    int j0 = w * 32;
    for (int jj = 0; jj < 32; ++jj) {
      int j = j0 + jj;
      if (j < (int)Ct) {
        double ltx = fmax(xi0, cbd[j * 4 + 0]);
        double lty = fmax(yi0, cbd[j * 4 + 1]);
        double rbx = fmin(xi1, cbd[j * 4 + 2]);
        double rby = fmin(yi1, cbd[j * 4 + 3]);
        double iw = fmax(rbx - ltx, 0.0);
        double ih = fmax(rby - lty, 0.0);
        double inter = iw * ih;
        double iou = inter / (ai + ar[j] - inter + 1e-9);
        if (iou > TH_IOU) bits |= (1u << jj);
      }
    }
    rows[i * 8 + w] = bits;
  }
  __syncthreads();

  if (tid < 64) {
    unsigned supp = 0;
    for (int i = 0; i < (int)Ct; ++i) {
      unsigned wsrc = __shfl(supp, i >> 5);
      bool kkeep = ((wsrc >> (i & 31)) & 1u) == 0u;
      if (tid == 0) kp[i] = kkeep ? 1u : 0u;
      unsigned rw = (tid < 8) ? rows[i * 8 + tid] : 0u;
      if (kkeep) supp |= rw;
    }
  }
  __syncthreads();

  if (tid < K) {
    bool kkeep = ((unsigned)tid < Ct) && (kp[tid] != 0u);
    float o0 = 0.f, o1 = 0.f, o2 = 0.f, o3 = 0.f, o4 = 0.f;
    if (kkeep) {
      o0 = (float)cbd[tid * 4 + 0]; o1 = (float)cbd[tid * 4 + 1];
      o2 = (float)cbd[tid * 4 + 2]; o3 = (float)cbd[tid * 4 + 3];
      double sd = __longlong_as_double(
          (long long)(cand[tid] & 0xFFFFFFFFFFFF0000ull));
      o4 = (float)sd;
    }
    size_t ob = ((size_t)bc * K + tid) * 5;
    out[ob + 0] = o0; out[ob + 1] = o1; out[ob + 2] = o2;
    out[ob + 3] = o3; out[ob + 4] = o4;
    out[(size_t)B * NC * K * 5 + (size_t)bc * K + tid] = kkeep ? 1.f : 0.f;
  }
}

extern "C" void kernel_launch(void* const* d_in, const int* in_sizes, int n_in,
                              void* d_out, int out_size, void* d_ws, size_t ws_size,
                              hipStream_t stream) {
  (void)in_sizes; (void)n_in; (void)out_size;
  const float* conf = (const float*)d_in[0];
  const float* loc = (const float*)d_in[1];
  const float* anchor = (const float*)d_in[2];
  float* out = (float*)d_out;

  size_t nBA = (size_t)B * A;
  size_t off_sarr = 0;
  size_t off_marr = off_sarr + nBA * sizeof(double);
  size_t off_keys = off_marr + nBA * sizeof(float);
  size_t off_ghist = off_keys + nBA * NC * sizeof(unsigned short);
  size_t ghist_bytes = (size_t)B * NC * NBIN * sizeof(unsigned);
  size_t off_gctr = off_ghist + ghist_bytes;
  size_t gctr_bytes = (size_t)B * NC * sizeof(unsigned);
  size_t off_clist = off_gctr + gctr_bytes;
  size_t clist_bytes = (size_t)B * NC * CAP * sizeof(int);
  size_t need_v7 = off_clist + clist_bytes;         // ~57.3 MB
  size_t need_fast2 = off_gctr;                     // round-6 tier
  size_t need_fast = off_ghist;                     // round-3 tier
  size_t need_mid = nBA * (sizeof(float) + sizeof(double));  // 12 MB

  if (ws_size >= need_fast) {
    double* sarr = (double*)((char*)d_ws + off_sarr);
    float* marr = (float*)((char*)d_ws + off_marr);
    unsigned short* keys = (unsigned short*)((char*)d_ws + off_keys);
    prep_fast<<<(B * A) / 256, 256, 0, stream>>>(conf, marr, sarr, keys);
    if (ws_size >= need_v7) {
      unsigned* ghist = (unsigned*)((char*)d_ws + off_ghist);
      unsigned* gctr = (unsigned*)((char*)d_ws + off_gctr);
      int* clist = (int*)((char*)d_ws + off_clist);
      hipMemsetAsync(ghist, 0, ghist_bytes + gctr_bytes, stream);
      prehist_kernel<<<B * NC * 4, 256, 0, stream>>>(keys, ghist);
      collect_kernel<<<B * NC * 4, 256, 0, stream>>>(keys, ghist, gctr, clist);
      nms_kernel<<<B * NC, 512, 0, stream>>>(conf, marr, sarr, loc, anchor,
                                             gctr, clist, out);
    } else if (ws_size >= need_fast2) {
      unsigned* ghist = (unsigned*)((char*)d_ws + off_ghist);
      hipMemsetAsync(ghist, 0, ghist_bytes, stream);
      prehist_kernel<<<B * NC * 4, 256, 0, stream>>>(keys, ghist);
      select_fast<<<B * NC, 512, 0, stream>>>(conf, marr, sarr, loc, anchor,
                                              keys, ghist, out);
    } else {
      select_fast<<<B * NC, 512, 0, stream>>>(conf, marr, sarr, loc, anchor,
                                              keys, nullptr, out);
    }
  } else if (ws_size >= need_mid) {
    float* marr = (float*)d_ws;
    double* sarr = (double*)((char*)d_ws + nBA * sizeof(float));
    prep_kernel<<<(B * A) / 256, 256, 0, stream>>>(conf, marr, sarr);
    select_nms_kernel<<<B * NC, 256, 0, stream>>>(conf, marr, sarr, loc, anchor, out);
  } else {
    select_nms_kernel<<<B * NC, 256, 0, stream>>>(conf, nullptr, nullptr, loc, anchor, out);
  }
}

// Round 8
// 115.620 us; speedup vs baseline: 1.6913x; 1.6913x over previous
//
#include <hip/hip_runtime.h>

// DetectPostProcess: softmax -> decode -> per-(b,c) top-200 -> greedy NMS.
// Decisions (ordering, top-K membership, IoU>0.5) identical to the round-2..7
// passing kernels (f64 everywhere it matters; f32 IoU fast path guarded by
// exact f64 recompute within |margin|<=1e-5, error bound ~3e-7).
// Round 8: collect_kernel appends via LDS staging + ONE global atomic per
// block (round 7's per-candidate global atomics serialized at 92us).
// Outputs: objs [B,NC,K,5] then keep [B,NC,K] (as 0.0/1.0), flat in d_out.

constexpr int B = 32;
constexpr int A = 32768;     // power of two
constexpr int ABITS = 15;    // log2(A)
constexpr int NCP1 = 21;
constexpr int NC = 20;
constexpr int K = 200;
constexpr int NBIN = 576;    // key range 0x3D4C..0x3F80 = 564 values
constexpr int CAP = 512;     // candidate capacity per (b,c)
#define KBASE 0x3D4Cu        // bits(0.05f) >> 16; min nonzero key

#define TH_CONF 0.05
#define TH_IOU  0.5

// ============================ FAST PATH =====================================
// prep_fast: per (b,a): m (f32 max), S (f64 sum), and 20 transposed u16 keys.
__global__ __launch_bounds__(256) void prep_fast(
    const float* __restrict__ conf, float* __restrict__ marr,
    double* __restrict__ sarr, unsigned short* __restrict__ keys) {
  int idx = blockIdx.x * 256 + threadIdx.x;   // 0 .. B*A-1
  int b = idx >> ABITS;
  int a = idx & (A - 1);
  const float* cp = conf + (size_t)idx * NCP1;
  float x[NCP1];
#pragma unroll
  for (int i = 0; i < NCP1; ++i) x[i] = cp[i];
  float m = x[0];
#pragma unroll
  for (int i = 1; i < NCP1; ++i) m = fmaxf(m, x[i]);
  double e[NCP1];
  double S = 0.0;
#pragma unroll
  for (int i = 0; i < NCP1; ++i) {
    e[i] = exp((double)x[i] - (double)m);
    S += e[i];
  }
  marr[idx] = m;
  sarr[idx] = S;
  double rs = 1.0 / S;
  size_t kbase = ((size_t)(b * NC) << ABITS) + a;
#pragma unroll
  for (int c = 0; c < NC; ++c) {
    double sd = e[c + 1] * rs;                 // ~1ulp from e/S; key-grade only
    unsigned short key = 0;
    if (sd >= TH_CONF) {
      float f = (float)sd;
      key = (unsigned short)(__float_as_uint(f) >> 16);
    }
    keys[kbase + ((size_t)c << ABITS)] = key;
  }
}

// prehist: 4 blocks per (b,c); LDS-aggregated 576-bin histogram -> global.
__global__ __launch_bounds__(256) void prehist_kernel(
    const unsigned short* __restrict__ keys, unsigned* __restrict__ ghist) {
  __shared__ unsigned h[NBIN];
  int tid = threadIdx.x;
  int blk = blockIdx.x;          // 0..B*NC*4-1
  int bc = blk >> 2, chunk = blk & 3;
  for (int i = tid; i < NBIN; i += 256) h[i] = 0;
  __syncthreads();
  const uint4* kv = (const uint4*)(keys + ((size_t)bc << ABITS) + chunk * (A / 4));
  for (int i = tid; i < A / 4 / 8; i += 256) {   // 1024 uint4s
    uint4 v = kv[i];
    unsigned w[4] = {v.x, v.y, v.z, v.w};
#pragma unroll
    for (int q = 0; q < 4; ++q) {
      unsigned lo = w[q] & 0xFFFFu, hi = w[q] >> 16;
      if (lo) atomicAdd(&h[min(lo - KBASE, (unsigned)(NBIN - 1))], 1u);
      if (hi) atomicAdd(&h[min(hi - KBASE, (unsigned)(NBIN - 1))], 1u);
    }
  }
  __syncthreads();
  unsigned* grow = ghist + (size_t)bc * NBIN;
  for (int i = tid; i < NBIN; i += 256) {
    unsigned cnt = h[i];
    if (cnt) atomicAdd(&grow[i], cnt);
  }
}

// collect_kernel: 4 blocks per (b,c). Wave 0 derives the pivot from ghist
// (same crossing condition as rounds 4-7); candidates staged in LDS, then
// ONE global atomic per block reserves a clist range (coalesced copy-out).
__global__ __launch_bounds__(256) void collect_kernel(
    const unsigned short* __restrict__ keys, const unsigned* __restrict__ ghist,
    unsigned* __restrict__ gctr, int* __restrict__ clist) {
  __shared__ unsigned sh_pivot;
  __shared__ int lbuf[CAP];
  __shared__ unsigned lcnt, lbase;
  int tid = threadIdx.x;
  int blk = blockIdx.x;
  int bc = blk >> 2, chunk = blk & 3;

  if (tid == 0) lcnt = 0;
  if (tid < 64) {
    const unsigned* grow = ghist + (size_t)bc * NBIN;
    unsigned h[9];
    unsigned lsum = 0;
#pragma unroll
    for (int j = 0; j < 9; ++j) { h[j] = grow[tid * 9 + j]; lsum += h[j]; }
    unsigned S = lsum;                    // inclusive suffix over lanes
#pragma unroll
    for (int d = 1; d < 64; d <<= 1) {
      unsigned o = __shfl_down(S, d, 64);
      if (tid + d < 64) S += o;
    }
    unsigned total = __shfl(S, 0, 64);
    unsigned t = S - lsum;                // cnt_ge(first bin of lane tid+1)
    unsigned selbin = 0xFFFFFFFFu;
#pragma unroll
    for (int j = 8; j >= 0; --j) {        // walk bins high -> low
      unsigned tj = t + h[j];             // cnt_ge(tid*9 + j)
      if (tj >= (unsigned)K && t < (unsigned)K) selbin = tid * 9 + j;
      t = tj;
    }
#pragma unroll
    for (int d = 1; d < 64; d <<= 1) {    // unique -> min-reduce
      unsigned o = __shfl_xor(selbin, d, 64);
      selbin = min(selbin, o);
    }
    if (tid == 0)
      sh_pivot = (total <= (unsigned)K || selbin == 0xFFFFFFFFu)
                     ? KBASE : (KBASE + selbin);
  }
  __syncthreads();
  unsigned pivot16 = sh_pivot;

  const uint4* kv = (const uint4*)(keys + ((size_t)bc << ABITS) + chunk * (A / 4));
  int abase = chunk * (A / 4);
  for (int i = tid; i < A / 4 / 8; i += 256) {   // 1024 uint4s
    uint4 v = kv[i];
    unsigned w[4] = {v.x, v.y, v.z, v.w};
#pragma unroll
    for (int q = 0; q < 4; ++q) {
      unsigned lo = w[q] & 0xFFFFu, hi = w[q] >> 16;
      if (lo >= pivot16) {
        unsigned pos = atomicAdd(&lcnt, 1u);
        if (pos < (unsigned)CAP) lbuf[pos] = abase + i * 8 + q * 2 + 0;
      }
      if (hi >= pivot16) {
        unsigned pos = atomicAdd(&lcnt, 1u);
        if (pos < (unsigned)CAP) lbuf[pos] = abase + i * 8 + q * 2 + 1;
      }
    }
  }
  __syncthreads();
  unsigned n = lcnt < (unsigned)CAP ? lcnt : (unsigned)CAP;
  if (tid == 0) lbase = atomicAdd(&gctr[bc], n);
  __syncthreads();
  unsigned bpos = lbase;
  for (unsigned i = tid; i < n; i += 256) {
    unsigned pos = bpos + i;
    if (pos < (unsigned)CAP) clist[bc * CAP + pos] = lbuf[i];
  }
}

// f64 box decode for one anchor.
__device__ __forceinline__ void decode_d(const float* __restrict__ loc,
                                         const float* __restrict__ anchor,
                                         size_t ba, int a, double* o) {
  const float* lp = loc + ba * 4;
  const float* ap = anchor + (size_t)a * 4;
  double l0 = lp[0], l1 = lp[1], l2 = lp[2], l3 = lp[3];
  double cx = ap[0], cy = ap[1], aw = ap[2], ah = ap[3];
  double X = (l0 * 0.125) * aw + cx;
  double Y = (l1 * 0.125) * ah + cy;
  double bw = exp(l2 * 0.125) * aw;
  double bh = exp(l3 * 0.125) * ah;
  o[0] = X - bw * 0.5;
  o[1] = Y - bh * 0.5;
  o[2] = X + bw * 0.5;
  o[3] = Y + bh * 0.5;
}

// nms_kernel: one block per (b,c). Exact f64 rescore of candidates, shfl
// bitonic sort, f64 decode, f32 IoU with exact f64 guard, greedy scan, write.
__global__ __launch_bounds__(512) void nms_kernel(
    const float* __restrict__ conf, const float* __restrict__ marr,
    const double* __restrict__ sarr, const float* __restrict__ loc,
    const float* __restrict__ anchor, const unsigned* __restrict__ gctr,
    const int* __restrict__ clist, float* __restrict__ out) {
  constexpr int NT = 512;
  __shared__ unsigned long long cand[512];
  __shared__ double cbd5[K * 5];        // f64 x0,y0,x1,y1,area (guard path)
  __shared__ float cb32[K * 5];         // f32 copy (fast path)
  __shared__ unsigned rows[K * 8];
  __shared__ unsigned kp[K];

  int tid = threadIdx.x;
  int bc = blockIdx.x;
  int b = bc / NC, c = bc % NC;
  size_t base = (size_t)b << ABITS;

  unsigned ccount = gctr[bc];
  if (ccount > (unsigned)CAP) ccount = CAP;
  unsigned Ct = ccount < (unsigned)K ? ccount : (unsigned)K;

  // ---- 1. exact f64 scores for candidates; build sort keys ----
  for (int i = tid; i < 512; i += NT) {
    unsigned long long key = 0ull;
    if ((unsigned)i < ccount) {
      int a = clist[bc * CAP + i];
      size_t ba = base + a;
      double sd = exp((double)conf[ba * NCP1 + (c + 1)] - (double)marr[ba]) / sarr[ba];
      if (sd >= TH_CONF) {
        unsigned long long db = (unsigned long long)__double_as_longlong(sd);
        key = (db & 0xFFFFFFFFFFFF0000ull) |
              (unsigned long long)(65535u - (unsigned)a);
      }
    }
    cand[i] = key;
  }
  __syncthreads();

  // ---- 2. bitonic sort desc (shfl for j<64): (score bits desc, idx asc) ----
  unsigned n2 = (ccount <= 256u) ? 256u : 512u;
  unsigned long long v = ((unsigned)tid < n2) ? cand[tid] : 0ull;
  for (unsigned k2 = 2; k2 <= n2; k2 <<= 1) {
    for (unsigned j = k2 >> 1; j > 0; j >>= 1) {
      unsigned long long p;
      if (j >= 64) {
        __syncthreads();
        if ((unsigned)tid < n2) cand[tid] = v;
        __syncthreads();
        p = ((unsigned)tid < n2) ? cand[tid ^ j] : 0ull;
      } else {
        p = __shfl_xor(v, (int)j, 64);
      }
      if ((unsigned)tid < n2) {
        bool desc = ((tid & (int)k2) == 0);
        bool lower = ((tid & (int)j) == 0);
        bool takemax = (lower == desc);
        bool vge = (v >= p);
        v = takemax ? (vge ? v : p) : (vge ? p : v);
      }
    }
  }
  __syncthreads();
  if ((unsigned)tid < n2) cand[tid] = v;
  __syncthreads();

  // ---- 3. decode candidate boxes (f64) + f32 mirror ----
  if ((unsigned)tid < Ct) {
    unsigned long long key = cand[tid];
    bool valid = (key >> 16) != 0ull;
    double o[4] = {0.0, 0.0, 0.0, 0.0};
    double aa = 0.0;
    if (valid) {
      unsigned a = (65535u - (unsigned)(key & 0xFFFFull)) & (A - 1);
      decode_d(loc, anchor, base + a, a, o);
      aa = (o[2] - o[0]) * (o[3] - o[1]);
    }
    cbd5[tid * 5 + 0] = o[0]; cbd5[tid * 5 + 1] = o[1];
    cbd5[tid * 5 + 2] = o[2]; cbd5[tid * 5 + 3] = o[3];
    cbd5[tid * 5 + 4] = aa;
    cb32[tid * 5 + 0] = (float)o[0]; cb32[tid * 5 + 1] = (float)o[1];
    cb32[tid * 5 + 2] = (float)o[2]; cb32[tid * 5 + 3] = (float)o[3];
    cb32[tid * 5 + 4] = (float)aa;
  }
  __syncthreads();

  // ---- 4. IoU rows: f32 fast path, exact f64 when |margin| <= 1e-5 ----
  int Cti = (int)Ct;
  int total_iw = Cti * 8;
  for (int id = tid; id < total_iw; id += NT) {
    int i = id % Cti;
    int w = id / Cti;
    float xi0 = cb32[i * 5 + 0], yi0 = cb32[i * 5 + 1];
    float xi1 = cb32[i * 5 + 2], yi1 = cb32[i * 5 + 3];
    float ai = cb32[i * 5 + 4];
    unsigned bits = 0;
    int j0 = w * 32;
    for (int jj = 0; jj < 32; ++jj) {
      int j = j0 + jj;
      if (j < Cti) {
        float ltx = fmaxf(xi0, cb32[j * 5 + 0]);
        float lty = fmaxf(yi0, cb32[j * 5 + 1]);
        float rbx = fminf(xi1, cb32[j * 5 + 2]);
        float rby = fminf(yi1, cb32[j * 5 + 3]);
        float iw = fmaxf(rbx - ltx, 0.f);
        float ih = fmaxf(rby - lty, 0.f);
        float inter = iw * ih;
        float den = ai + cb32[j * 5 + 4] - inter + 1e-9f;
        float dmar = inter - 0.5f * den;
        bool bit;
        if (fabsf(dmar) > 1e-5f) {
          bit = dmar > 0.f;
        } else {
          double LTX = fmax(cbd5[i * 5 + 0], cbd5[j * 5 + 0]);
          double LTY = fmax(cbd5[i * 5 + 1], cbd5[j * 5 + 1]);
          double RBX = fmin(cbd5[i * 5 + 2], cbd5[j * 5 + 2]);
          double RBY = fmin(cbd5[i * 5 + 3], cbd5[j * 5 + 3]);
          double IW = fmax(RBX - LTX, 0.0);
          double IH = fmax(RBY - LTY, 0.0);
          double INTER = IW * IH;
          double DEN = cbd5[i * 5 + 4] + cbd5[j * 5 + 4] - INTER + 1e-9;
          bit = INTER > 0.5 * DEN;
        }
        if (bit) bits |= (1u << jj);
      }
    }
    rows[i * 8 + w] = bits;
  }
  __syncthreads();

  // ---- 5. greedy scan (wave 0; matches lax.scan semantics) ----
  if (tid < 64) {
    unsigned supp = 0;
    for (int i = 0; i < Cti; ++i) {
      unsigned wsrc = __shfl(supp, i >> 5);
      bool kkeep = ((wsrc >> (i & 31)) & 1u) == 0u;
      if (tid == 0) kp[i] = kkeep ? 1u : 0u;
      unsigned rw = (tid < 8) ? rows[i * 8 + tid] : 0u;
      if (kkeep) supp |= rw;
    }
  }
  __syncthreads();

  // ---- 6. write objs + keep ----
  if (tid < K) {
    bool kkeep = ((unsigned)tid < Ct) && (kp[tid] != 0u) && ((cand[tid] >> 16) != 0ull);
    float o0 = 0.f, o1 = 0.f, o2 = 0.f, o3 = 0.f, o4 = 0.f;
    if (kkeep) {
      o0 = (float)cbd5[tid * 5 + 0]; o1 = (float)cbd5[tid * 5 + 1];
      o2 = (float)cbd5[tid * 5 + 2]; o3 = (float)cbd5[tid * 5 + 3];
      double sd = __longlong_as_double(
          (long long)(cand[tid] & 0xFFFFFFFFFFFF0000ull));
      o4 = (float)sd;
    }
    size_t ob = ((size_t)bc * K + tid) * 5;
    out[ob + 0] = o0; out[ob + 1] = o1; out[ob + 2] = o2;
    out[ob + 3] = o3; out[ob + 4] = o4;
    out[(size_t)B * NC * K * 5 + (size_t)bc * K + tid] = kkeep ? 1.f : 0.f;
  }
}

// ==================== FALLBACK: round-6 fused select (passing) ==============
__global__ __launch_bounds__(512) void select_fast(
    const float* __restrict__ conf, const float* __restrict__ marr,
    const double* __restrict__ sarr, const float* __restrict__ loc,
    const float* __restrict__ anchor, const unsigned short* __restrict__ keys,
    const unsigned* __restrict__ ghist, float* __restrict__ out) {
  constexpr int NT = 512;
  __shared__ unsigned hist[NBIN];
  __shared__ unsigned wtot[8], wsuf[8];
  __shared__ unsigned long long cand[512];
  __shared__ int clist[512];
  __shared__ double cbd5[K * 5];
  __shared__ unsigned rows[K * 8];
  __shared__ unsigned kp[K];
  __shared__ unsigned sh_cnt, sh_selbin, sh_total;

  int tid = threadIdx.x;
  unsigned lane = tid & 63, wid = tid >> 6;
  int bc = blockIdx.x;
  int b = bc / NC, c = bc % NC;
  size_t base = (size_t)b << ABITS;
  const unsigned short* krow = keys + ((size_t)bc << ABITS);
  const uint4* kv = (const uint4*)krow;

  if (tid == 0) sh_cnt = 0;

  unsigned h0 = 0, h1 = 0;
  if (ghist) {
    if (tid < NBIN / 2) {
      uint2 hh = ((const uint2*)(ghist + (size_t)bc * NBIN))[tid];
      h0 = hh.x; h1 = hh.y;
    }
  } else {
    for (int i = tid; i < NBIN; i += NT) hist[i] = 0;
    __syncthreads();
    for (int i = tid; i < A / 8; i += NT) {
      uint4 v = kv[i];
      unsigned w[4] = {v.x, v.y, v.z, v.w};
#pragma unroll
      for (int q = 0; q < 4; ++q) {
        unsigned lo = w[q] & 0xFFFFu, hi = w[q] >> 16;
        if (lo) atomicAdd(&hist[min(lo - KBASE, (unsigned)(NBIN - 1))], 1u);
        if (hi) atomicAdd(&hist[min(hi - KBASE, (unsigned)(NBIN - 1))], 1u);
      }
    }
    __syncthreads();
    if (tid < NBIN / 2) { h0 = hist[2 * tid]; h1 = hist[2 * tid + 1]; }
  }

  unsigned s = h0 + h1;
  unsigned S = s;
#pragma unroll
  for (int d = 1; d < 64; d <<= 1) {
    unsigned o = __shfl_down(S, d, 64);
    if (lane + d < 64) S += o;
  }
  if (lane == 0) wtot[wid] = S;
  __syncthreads();
  if (tid < 8) {
    unsigned acc = 0;
    for (int w2 = tid + 1; w2 < 8; ++w2) acc += wtot[w2];
    wsuf[tid] = acc;
    if (tid == 0) sh_total = acc + wtot[0];
  }
  __syncthreads();
  unsigned Sfull = S + wsuf[wid];
  unsigned above2 = Sfull - s;
  unsigned cg1 = h1 + above2;
  unsigned cg0 = h0 + cg1;
  if (cg1 >= (unsigned)K && above2 < (unsigned)K) sh_selbin = tid * 2 + 1;
  if (cg0 >= (unsigned)K && cg1 < (unsigned)K) sh_selbin = tid * 2 + 0;
  __syncthreads();
  unsigned pivot16 = (sh_total <= (unsigned)K) ? KBASE : (KBASE + sh_selbin);

  for (int i = tid; i < A / 8; i += NT) {
    uint4 v = kv[i];
    unsigned w[4] = {v.x, v.y, v.z, v.w};
#pragma unroll
    for (int q = 0; q < 4; ++q) {
      unsigned lo = w[q] & 0xFFFFu, hi = w[q] >> 16;
      if (lo >= pivot16) {
        unsigned pos = atomicAdd(&sh_cnt, 1u);
        if (pos < 512) clist[pos] = i * 8 + q * 2 + 0;
      }
      if (hi >= pivot16) {
        unsigned pos = atomicAdd(&sh_cnt, 1u);
        if (pos < 512) clist[pos] = i * 8 + q * 2 + 1;
      }
    }
  }
  __syncthreads();
  unsigned ccount = sh_cnt < 512u ? sh_cnt : 512u;
  unsigned Ct = ccount < (unsigned)K ? ccount : (unsigned)K;

  for (int i = tid; i < 512; i += NT) {
    unsigned long long key = 0ull;
    if ((unsigned)i < ccount) {
      int a = clist[i];
      size_t ba = base + a;
      double sd = exp((double)conf[ba * NCP1 + (c + 1)] - (double)marr[ba]) / sarr[ba];
      if (sd >= TH_CONF) {
        unsigned long long db = (unsigned long long)__double_as_longlong(sd);
        key = (db & 0xFFFFFFFFFFFF0000ull) |
              (unsigned long long)(65535u - (unsigned)a);
      }
    }
    cand[i] = key;
  }
  __syncthreads();

  unsigned n2 = (ccount <= 256u) ? 256u : 512u;
  unsigned long long v = ((unsigned)tid < n2) ? cand[tid] : 0ull;
  for (unsigned k2 = 2; k2 <= n2; k2 <<= 1) {
    for (unsigned j = k2 >> 1; j > 0; j >>= 1) {
      unsigned long long p;
      if (j >= 64) {
        __syncthreads();
        if ((unsigned)tid < n2) cand[tid] = v;
        __syncthreads();
        p = ((unsigned)tid < n2) ? cand[tid ^ j] : 0ull;
      } else {
        p = __shfl_xor(v, (int)j, 64);
      }
      if ((unsigned)tid < n2) {
        bool desc = ((tid & (int)k2) == 0);
        bool lower = ((tid & (int)j) == 0);
        bool takemax = (lower == desc);
        bool vge = (v >= p);
        v = takemax ? (vge ? v : p) : (vge ? p : v);
      }
    }
  }
  __syncthreads();
  if ((unsigned)tid < n2) cand[tid] = v;
  __syncthreads();

  if ((unsigned)tid < Ct) {
    unsigned long long key = cand[tid];
    bool valid = (key >> 16) != 0ull;
    double o[4] = {0.0, 0.0, 0.0, 0.0};
    double aa = 0.0;
    if (valid) {
      unsigned a = (65535u - (unsigned)(key & 0xFFFFull)) & (A - 1);
      decode_d(loc, anchor, base + a, a, o);
      aa = (o[2] - o[0]) * (o[3] - o[1]);
    }
    cbd5[tid * 5 + 0] = o[0]; cbd5[tid * 5 + 1] = o[1];
    cbd5[tid * 5 + 2] = o[2]; cbd5[tid * 5 + 3] = o[3];
    cbd5[tid * 5 + 4] = aa;
  }
  __syncthreads();

  int total_iw = (int)Ct * 8;
  for (int id = tid; id < total_iw; id += NT) {
    int i = id % (int)Ct;
    int w = id / (int)Ct;
    double xi0 = cbd5[i * 5 + 0], yi0 = cbd5[i * 5 + 1];
    double xi1 = cbd5[i * 5 + 2], yi1 = cbd5[i * 5 + 3];
    double ai = cbd5[i * 5 + 4];
    unsigned bits = 0;
    int j0 = w * 32;
    for (int jj = 0; jj < 32; ++jj) {
      int j = j0 + jj;
      if (j < (int)Ct) {
        double ltx = fmax(xi0, cbd5[j * 5 + 0]);
        double lty = fmax(yi0, cbd5[j * 5 + 1]);
        double rbx = fmin(xi1, cbd5[j * 5 + 2]);
        double rby = fmin(yi1, cbd5[j * 5 + 3]);
        double iw = fmax(rbx - ltx, 0.0);
        double ih = fmax(rby - lty, 0.0);
        double inter = iw * ih;
        double den = ai + cbd5[j * 5 + 4] - inter + 1e-9;
        if (inter > 0.5 * den) bits |= (1u << jj);
      }
    }
    rows[i * 8 + w] = bits;
  }
  __syncthreads();

  if (tid < 64) {
    unsigned supp = 0;
    for (int i = 0; i < (int)Ct; ++i) {
      unsigned wsrc = __shfl(supp, i >> 5);
      bool kkeep = ((wsrc >> (i & 31)) & 1u) == 0u;
      if (tid == 0) kp[i] = kkeep ? 1u : 0u;
      unsigned rw = (tid < 8) ? rows[i * 8 + tid] : 0u;
      if (kkeep) supp |= rw;
    }
  }
  __syncthreads();

  if (tid < K) {
    bool kkeep = ((unsigned)tid < Ct) && (kp[tid] != 0u) && ((cand[tid] >> 16) != 0ull);
    float o0 = 0.f, o1 = 0.f, o2 = 0.f, o3 = 0.f, o4 = 0.f;
    if (kkeep) {
      o0 = (float)cbd5[tid * 5 + 0]; o1 = (float)cbd5[tid * 5 + 1];
      o2 = (float)cbd5[tid * 5 + 2]; o3 = (float)cbd5[tid * 5 + 3];
      double sd = __longlong_as_double(
          (long long)(cand[tid] & 0xFFFFFFFFFFFF0000ull));
      o4 = (float)sd;
    }
    size_t ob = ((size_t)bc * K + tid) * 5;
    out[ob + 0] = o0; out[ob + 1] = o1; out[ob + 2] = o2;
    out[ob + 3] = o3; out[ob + 4] = o4;
    out[(size_t)B * NC * K * 5 + (size_t)bc * K + tid] = kkeep ? 1.f : 0.f;
  }
}

// ============================ FALLBACK PATH (round-2, passing) ==============
__global__ __launch_bounds__(256) void prep_kernel(
    const float* __restrict__ conf, float* __restrict__ marr,
    double* __restrict__ sarr) {
  int idx = blockIdx.x * 256 + threadIdx.x;
  const float* cp = conf + (size_t)idx * NCP1;
  float x[NCP1];
#pragma unroll
  for (int i = 0; i < NCP1; ++i) x[i] = cp[i];
  float m = x[0];
#pragma unroll
  for (int i = 1; i < NCP1; ++i) m = fmaxf(m, x[i]);
  double S = 0.0;
#pragma unroll
  for (int i = 0; i < NCP1; ++i) S += exp((double)x[i] - (double)m);
  marr[idx] = m;
  sarr[idx] = S;
}

__device__ __forceinline__ double get_sd(const float* __restrict__ conf,
                                         const float* __restrict__ marr,
                                         const double* __restrict__ sarr,
                                         size_t ba, int c) {
  const float* cp = conf + ba * NCP1;
  float m;
  double S;
  if (sarr) {
    m = marr[ba];
    S = sarr[ba];
  } else {
    m = cp[0];
    for (int i = 1; i < NCP1; ++i) m = fmaxf(m, cp[i]);
    S = 0.0;
    for (int i = 0; i < NCP1; ++i) S += exp((double)cp[i] - (double)m);
  }
  return exp((double)cp[c + 1] - (double)m) / S;
}

__global__ __launch_bounds__(256) void select_nms_kernel(
    const float* __restrict__ conf, const float* __restrict__ marr,
    const double* __restrict__ sarr, const float* __restrict__ loc,
    const float* __restrict__ anchor, float* __restrict__ out) {
  __shared__ __align__(16) unsigned short s16[A];
  __shared__ unsigned hist[256];
  __shared__ unsigned scan0[256];
  __shared__ unsigned long long cand[512];
  __shared__ unsigned sh_cnt, sh_selbin, sh_need, sh_ctot;

  double* cbd = (double*)s16;
  double* ar = cbd + K * 4;
  unsigned* rows = (unsigned*)(ar + K);
  unsigned* kp = rows + K * 8;

  int tid = threadIdx.x;
  int bc = blockIdx.x;
  int b = bc / NC, c = bc % NC;
  size_t base = (size_t)b << ABITS;

  for (int a = tid; a < A; a += 256) {
    double sd = get_sd(conf, marr, sarr, base + a, c);
    unsigned short key = 0;
    if (sd >= TH_CONF) {
      float f = (float)sd;
      key = (unsigned short)(__float_as_uint(f) >> 16);
    }
    s16[a] = key;
  }
  __syncthreads();

  unsigned need = K, pfx = 0;
  bool smallcase = false;
  for (int p = 0; p < 2; ++p) {
    hist[tid] = 0;
    __syncthreads();
    for (int a = tid; a < A; a += 256) {
      unsigned v = s16[a];
      if (v && (p == 0 || (v >> 8) == pfx))
        atomicAdd(&hist[(p == 0) ? (v >> 8) : (v & 0xFFu)], 1u);
    }
    __syncthreads();
    scan0[tid] = hist[tid];
    __syncthreads();
    for (int st = 1; st < 256; st <<= 1) {
      unsigned mine = scan0[tid];
      unsigned oth = (tid + st < 256) ? scan0[tid + st] : 0u;
      __syncthreads();
      scan0[tid] = mine + oth;
      __syncthreads();
    }
    if (p == 0) {
      if (tid == 0) sh_ctot = scan0[0];
      __syncthreads();
      if (sh_ctot <= (unsigned)K) { smallcase = true; break; }
    }
    unsigned nxt = (tid == 255) ? 0u : scan0[tid + 1];
    if (scan0[tid] >= need && nxt < need) { sh_selbin = tid; sh_need = need - nxt; }
    __syncthreads();
    pfx = (pfx << 8) | sh_selbin;
    need = sh_need;
    __syncthreads();
  }
  unsigned pivot16 = smallcase ? 0x3D4Cu : pfx;

  if (tid == 0) sh_cnt = 0;
  __syncthreads();
  for (int a = tid; a < A; a += 256) {
    double sd = get_sd(conf, marr, sarr, base + a, c);
    if (sd >= TH_CONF) {
      float f = (float)sd;
      if ((__float_as_uint(f) >> 16) >= pivot16) {
        unsigned pos = atomicAdd(&sh_cnt, 1u);
        if (pos < 512) {
          unsigned long long db = (unsigned long long)__double_as_longlong(sd);
          cand[pos] = (db & 0xFFFFFFFFFFFF0000ull) |
                      (unsigned long long)(65535u - (unsigned)a);
        }
      }
    }
  }
  __syncthreads();
  unsigned ccount = sh_cnt < 512u ? sh_cnt : 512u;
  unsigned Ct = ccount < (unsigned)K ? ccount : (unsigned)K;
  for (int i = tid; i < 512; i += 256)
    if ((unsigned)i >= ccount) cand[i] = 0ull;
  __syncthreads();

  for (unsigned k2 = 2; k2 <= 512; k2 <<= 1) {
    for (unsigned j = k2 >> 1; j > 0; j >>= 1) {
      for (unsigned i = tid; i < 512; i += 256) {
        unsigned ixj = i ^ j;
        if (ixj > i) {
          unsigned long long va = cand[i], vb = cand[ixj];
          bool desc = ((i & k2) == 0);
          if (desc ? (va < vb) : (va > vb)) { cand[i] = vb; cand[ixj] = va; }
        }
      }
      __syncthreads();
    }
  }

  if ((unsigned)tid < Ct) {
    unsigned a = 65535u - (unsigned)(cand[tid] & 0xFFFFull);
    double o[4];
    decode_d(loc, anchor, base + a, a, o);
    cbd[tid * 4 + 0] = o[0]; cbd[tid * 4 + 1] = o[1];
    cbd[tid * 4 + 2] = o[2]; cbd[tid * 4 + 3] = o[3];
    ar[tid] = (o[2] - o[0]) * (o[3] - o[1]);
  }
  __syncthreads();

  for (int id = tid; id < (int)Ct * 8; id += 256) {
    int i = id >> 3, w = id & 7;
    double xi0 = cbd[i * 4 + 0], yi0 = cbd[i * 4 + 1];
    double xi1 = cbd[i * 4 + 2], yi1 = cbd[i * 4 + 3];
    double ai = ar[i];
    unsigned bits = 0;
    int j0 = w * 32;
    for (int jj = 0; jj < 32; ++jj) {
      int j = j0 + jj;
      if (j < (int)Ct) {
        double ltx = fmax(xi0, cbd[j * 4 + 0]);
        double lty = fmax(yi0, cbd[j * 4 + 1]);
        double rbx = fmin(xi1, cbd[j * 4 + 2]);
        double rby = fmin(yi1, cbd[j * 4 + 3]);
        double iw = fmax(rbx - ltx, 0.0);
        double ih = fmax(rby - lty, 0.0);
        double inter = iw * ih;
        double iou = inter / (ai + ar[j] - inter + 1e-9);
        if (iou > TH_IOU) bits |= (1u << jj);
      }
    }
    rows[i * 8 + w] = bits;
  }
  __syncthreads();

  if (tid < 64) {
    unsigned supp = 0;
    for (int i = 0; i < (int)Ct; ++i) {
      unsigned wsrc = __shfl(supp, i >> 5);
      bool kkeep = ((wsrc >> (i & 31)) & 1u) == 0u;
      if (tid == 0) kp[i] = kkeep ? 1u : 0u;
      unsigned rw = (tid < 8) ? rows[i * 8 + tid] : 0u;
      if (kkeep) supp |= rw;
    }
  }
  __syncthreads();

  if (tid < K) {
    bool kkeep = ((unsigned)tid < Ct) && (kp[tid] != 0u);
    float o0 = 0.f, o1 = 0.f, o2 = 0.f, o3 = 0.f, o4 = 0.f;
    if (kkeep) {
      o0 = (float)cbd[tid * 4 + 0]; o1 = (float)cbd[tid * 4 + 1];
      o2 = (float)cbd[tid * 4 + 2]; o3 = (float)cbd[tid * 4 + 3];
      double sd = __longlong_as_double(
          (long long)(cand[tid] & 0xFFFFFFFFFFFF0000ull));
      o4 = (float)sd;
    }
    size_t ob = ((size_t)bc * K + tid) * 5;
    out[ob + 0] = o0; out[ob + 1] = o1; out[ob + 2] = o2;
    out[ob + 3] = o3; out[ob + 4] = o4;
    out[(size_t)B * NC * K * 5 + (size_t)bc * K + tid] = kkeep ? 1.f : 0.f;
  }
}

extern "C" void kernel_launch(void* const* d_in, const int* in_sizes, int n_in,
                              void* d_out, int out_size, void* d_ws, size_t ws_size,
                              hipStream_t stream) {
  (void)in_sizes; (void)n_in; (void)out_size;
  const float* conf = (const float*)d_in[0];
  const float* loc = (const float*)d_in[1];
  const float* anchor = (const float*)d_in[2];
  float* out = (float*)d_out;

  size_t nBA = (size_t)B * A;
  size_t off_sarr = 0;
  size_t off_marr = off_sarr + nBA * sizeof(double);
  size_t off_keys = off_marr + nBA * sizeof(float);
  size_t off_ghist = off_keys + nBA * NC * sizeof(unsigned short);
  size_t ghist_bytes = (size_t)B * NC * NBIN * sizeof(unsigned);
  size_t off_gctr = off_ghist + ghist_bytes;
  size_t gctr_bytes = (size_t)B * NC * sizeof(unsigned);
  size_t off_clist = off_gctr + gctr_bytes;
  size_t clist_bytes = (size_t)B * NC * CAP * sizeof(int);
  size_t need_v7 = off_clist + clist_bytes;         // ~57.3 MB
  size_t need_fast2 = off_gctr;                     // round-6 tier
  size_t need_fast = off_ghist;                     // round-3 tier
  size_t need_mid = nBA * (sizeof(float) + sizeof(double));  // 12 MB

  if (ws_size >= need_fast) {
    double* sarr = (double*)((char*)d_ws + off_sarr);
    float* marr = (float*)((char*)d_ws + off_marr);
    unsigned short* keys = (unsigned short*)((char*)d_ws + off_keys);
    prep_fast<<<(B * A) / 256, 256, 0, stream>>>(conf, marr, sarr, keys);
    if (ws_size >= need_v7) {
      unsigned* ghist = (unsigned*)((char*)d_ws + off_ghist);
      unsigned* gctr = (unsigned*)((char*)d_ws + off_gctr);
      int* clist = (int*)((char*)d_ws + off_clist);
      hipMemsetAsync(ghist, 0, ghist_bytes + gctr_bytes, stream);
      prehist_kernel<<<B * NC * 4, 256, 0, stream>>>(keys, ghist);
      collect_kernel<<<B * NC * 4, 256, 0, stream>>>(keys, ghist, gctr, clist);
      nms_kernel<<<B * NC, 512, 0, stream>>>(conf, marr, sarr, loc, anchor,
                                             gctr, clist, out);
    } else if (ws_size >= need_fast2) {
      unsigned* ghist = (unsigned*)((char*)d_ws + off_ghist);
      hipMemsetAsync(ghist, 0, ghist_bytes, stream);
      prehist_kernel<<<B * NC * 4, 256, 0, stream>>>(keys, ghist);
      select_fast<<<B * NC, 512, 0, stream>>>(conf, marr, sarr, loc, anchor,
                                              keys, ghist, out);
    } else {
      select_fast<<<B * NC, 512, 0, stream>>>(conf, marr, sarr, loc, anchor,
                                              keys, nullptr, out);
    }
  } else if (ws_size >= need_mid) {
    float* marr = (float*)d_ws;
    double* sarr = (double*)((char*)d_ws + nBA * sizeof(float));
    prep_kernel<<<(B * A) / 256, 256, 0, stream>>>(conf, marr, sarr);
    select_nms_kernel<<<B * NC, 256, 0, stream>>>(conf, marr, sarr, loc, anchor, out);
  } else {
    select_nms_kernel<<<B * NC, 256, 0, stream>>>(conf, nullptr, nullptr, loc, anchor, out);
  }
}

// Round 9
// 111.053 us; speedup vs baseline: 1.7609x; 1.0411x over previous
//
#include <hip/hip_runtime.h>

// DetectPostProcess: softmax -> decode -> per-(b,c) top-200 -> greedy NMS.
// Decisions (ordering, top-K membership, IoU>0.5) identical to rounds 2..8
// (f64 everywhere it matters; f32 IoU fast path guarded by exact f64
// recompute within |margin|<=1e-5, error bound ~3e-7).
// Round 9: nms IoU phase computes UPPER TRIANGLE ONLY (bits j<=i are never
// read by the forward greedy scan) and uses float4/double4 packed boxes
// (2 LDS instrs per pair-eval instead of 5). ~4x less LDS-pipe traffic.
// Outputs: objs [B,NC,K,5] then keep [B,NC,K] (as 0.0/1.0), flat in d_out.

constexpr int B = 32;
constexpr int A = 32768;     // power of two
constexpr int ABITS = 15;    // log2(A)
constexpr int NCP1 = 21;
constexpr int NC = 20;
constexpr int K = 200;
constexpr int NBIN = 576;    // key range 0x3D4C..0x3F80 = 564 values
constexpr int CAP = 512;     // candidate capacity per (b,c)
#define KBASE 0x3D4Cu        // bits(0.05f) >> 16; min nonzero key

#define TH_CONF 0.05
#define TH_IOU  0.5

// ============================ FAST PATH =====================================
// prep_fast: per (b,a): m (f32 max), S (f64 sum), and 20 transposed u16 keys.
__global__ __launch_bounds__(256) void prep_fast(
    const float* __restrict__ conf, float* __restrict__ marr,
    double* __restrict__ sarr, unsigned short* __restrict__ keys) {
  int idx = blockIdx.x * 256 + threadIdx.x;   // 0 .. B*A-1
  int b = idx >> ABITS;
  int a = idx & (A - 1);
  const float* cp = conf + (size_t)idx * NCP1;
  float x[NCP1];
#pragma unroll
  for (int i = 0; i < NCP1; ++i) x[i] = cp[i];
  float m = x[0];
#pragma unroll
  for (int i = 1; i < NCP1; ++i) m = fmaxf(m, x[i]);
  double e[NCP1];
  double S = 0.0;
#pragma unroll
  for (int i = 0; i < NCP1; ++i) {
    e[i] = exp((double)x[i] - (double)m);
    S += e[i];
  }
  marr[idx] = m;
  sarr[idx] = S;
  double rs = 1.0 / S;
  size_t kbase = ((size_t)(b * NC) << ABITS) + a;
#pragma unroll
  for (int c = 0; c < NC; ++c) {
    double sd = e[c + 1] * rs;                 // ~1ulp from e/S; key-grade only
    unsigned short key = 0;
    if (sd >= TH_CONF) {
      float f = (float)sd;
      key = (unsigned short)(__float_as_uint(f) >> 16);
    }
    keys[kbase + ((size_t)c << ABITS)] = key;
  }
}

// prehist: 4 blocks per (b,c); LDS-aggregated 576-bin histogram -> global.
__global__ __launch_bounds__(256) void prehist_kernel(
    const unsigned short* __restrict__ keys, unsigned* __restrict__ ghist) {
  __shared__ unsigned h[NBIN];
  int tid = threadIdx.x;
  int blk = blockIdx.x;          // 0..B*NC*4-1
  int bc = blk >> 2, chunk = blk & 3;
  for (int i = tid; i < NBIN; i += 256) h[i] = 0;
  __syncthreads();
  const uint4* kv = (const uint4*)(keys + ((size_t)bc << ABITS) + chunk * (A / 4));
  for (int i = tid; i < A / 4 / 8; i += 256) {   // 1024 uint4s
    uint4 v = kv[i];
    unsigned w[4] = {v.x, v.y, v.z, v.w};
#pragma unroll
    for (int q = 0; q < 4; ++q) {
      unsigned lo = w[q] & 0xFFFFu, hi = w[q] >> 16;
      if (lo) atomicAdd(&h[min(lo - KBASE, (unsigned)(NBIN - 1))], 1u);
      if (hi) atomicAdd(&h[min(hi - KBASE, (unsigned)(NBIN - 1))], 1u);
    }
  }
  __syncthreads();
  unsigned* grow = ghist + (size_t)bc * NBIN;
  for (int i = tid; i < NBIN; i += 256) {
    unsigned cnt = h[i];
    if (cnt) atomicAdd(&grow[i], cnt);
  }
}

// collect_kernel: 4 blocks per (b,c). Wave 0 derives the pivot from ghist
// (same crossing condition as rounds 4-8); candidates staged in LDS, then
// ONE global atomic per block reserves a clist range (coalesced copy-out).
__global__ __launch_bounds__(256) void collect_kernel(
    const unsigned short* __restrict__ keys, const unsigned* __restrict__ ghist,
    unsigned* __restrict__ gctr, int* __restrict__ clist) {
  __shared__ unsigned sh_pivot;
  __shared__ int lbuf[CAP];
  __shared__ unsigned lcnt, lbase;
  int tid = threadIdx.x;
  int blk = blockIdx.x;
  int bc = blk >> 2, chunk = blk & 3;

  if (tid == 0) lcnt = 0;
  if (tid < 64) {
    const unsigned* grow = ghist + (size_t)bc * NBIN;
    unsigned h[9];
    unsigned lsum = 0;
#pragma unroll
    for (int j = 0; j < 9; ++j) { h[j] = grow[tid * 9 + j]; lsum += h[j]; }
    unsigned S = lsum;                    // inclusive suffix over lanes
#pragma unroll
    for (int d = 1; d < 64; d <<= 1) {
      unsigned o = __shfl_down(S, d, 64);
      if (tid + d < 64) S += o;
    }
    unsigned total = __shfl(S, 0, 64);
    unsigned t = S - lsum;                // cnt_ge(first bin of lane tid+1)
    unsigned selbin = 0xFFFFFFFFu;
#pragma unroll
    for (int j = 8; j >= 0; --j) {        // walk bins high -> low
      unsigned tj = t + h[j];             // cnt_ge(tid*9 + j)
      if (tj >= (unsigned)K && t < (unsigned)K) selbin = tid * 9 + j;
      t = tj;
    }
#pragma unroll
    for (int d = 1; d < 64; d <<= 1) {    // unique -> min-reduce
      unsigned o = __shfl_xor(selbin, d, 64);
      selbin = min(selbin, o);
    }
    if (tid == 0)
      sh_pivot = (total <= (unsigned)K || selbin == 0xFFFFFFFFu)
                     ? KBASE : (KBASE + selbin);
  }
  __syncthreads();
  unsigned pivot16 = sh_pivot;

  const uint4* kv = (const uint4*)(keys + ((size_t)bc << ABITS) + chunk * (A / 4));
  int abase = chunk * (A / 4);
  for (int i = tid; i < A / 4 / 8; i += 256) {   // 1024 uint4s
    uint4 v = kv[i];
    unsigned w[4] = {v.x, v.y, v.z, v.w};
#pragma unroll
    for (int q = 0; q < 4; ++q) {
      unsigned lo = w[q] & 0xFFFFu, hi = w[q] >> 16;
      if (lo >= pivot16) {
        unsigned pos = atomicAdd(&lcnt, 1u);
        if (pos < (unsigned)CAP) lbuf[pos] = abase + i * 8 + q * 2 + 0;
      }
      if (hi >= pivot16) {
        unsigned pos = atomicAdd(&lcnt, 1u);
        if (pos < (unsigned)CAP) lbuf[pos] = abase + i * 8 + q * 2 + 1;
      }
    }
  }
  __syncthreads();
  unsigned n = lcnt < (unsigned)CAP ? lcnt : (unsigned)CAP;
  if (tid == 0) lbase = atomicAdd(&gctr[bc], n);
  __syncthreads();
  unsigned bpos = lbase;
  for (unsigned i = tid; i < n; i += 256) {
    unsigned pos = bpos + i;
    if (pos < (unsigned)CAP) clist[bc * CAP + pos] = lbuf[i];
  }
}

// f64 box decode for one anchor.
__device__ __forceinline__ void decode_d(const float* __restrict__ loc,
                                         const float* __restrict__ anchor,
                                         size_t ba, int a, double* o) {
  const float* lp = loc + ba * 4;
  const float* ap = anchor + (size_t)a * 4;
  double l0 = lp[0], l1 = lp[1], l2 = lp[2], l3 = lp[3];
  double cx = ap[0], cy = ap[1], aw = ap[2], ah = ap[3];
  double X = (l0 * 0.125) * aw + cx;
  double Y = (l1 * 0.125) * ah + cy;
  double bw = exp(l2 * 0.125) * aw;
  double bh = exp(l3 * 0.125) * ah;
  o[0] = X - bw * 0.5;
  o[1] = Y - bh * 0.5;
  o[2] = X + bw * 0.5;
  o[3] = Y + bh * 0.5;
}

// nms_kernel: one block per (b,c). Exact f64 rescore, shfl bitonic sort,
// f64 decode, upper-triangle f32 IoU (f64 guard), greedy scan, write.
__global__ __launch_bounds__(512) void nms_kernel(
    const float* __restrict__ conf, const float* __restrict__ marr,
    const double* __restrict__ sarr, const float* __restrict__ loc,
    const float* __restrict__ anchor, const unsigned* __restrict__ gctr,
    const int* __restrict__ clist, float* __restrict__ out) {
  constexpr int NT = 512;
  __shared__ unsigned long long cand[512];
  __shared__ float4 cf4[K];             // f32 box (fast path)
  __shared__ float car[K];              // f32 area
  __shared__ double4 cd4[K];            // f64 box (guard path)
  __shared__ double dar[K];             // f64 area
  __shared__ unsigned rows[K * 8];
  __shared__ unsigned kp[K];

  int tid = threadIdx.x;
  int bc = blockIdx.x;
  int b = bc / NC, c = bc % NC;
  size_t base = (size_t)b << ABITS;

  unsigned ccount = gctr[bc];
  if (ccount > (unsigned)CAP) ccount = CAP;
  unsigned Ct = ccount < (unsigned)K ? ccount : (unsigned)K;

  // ---- 1. exact f64 scores for candidates; build sort keys ----
  for (int i = tid; i < 512; i += NT) {
    unsigned long long key = 0ull;
    if ((unsigned)i < ccount) {
      int a = clist[bc * CAP + i];
      size_t ba = base + a;
      double sd = exp((double)conf[ba * NCP1 + (c + 1)] - (double)marr[ba]) / sarr[ba];
      if (sd >= TH_CONF) {
        unsigned long long db = (unsigned long long)__double_as_longlong(sd);
        key = (db & 0xFFFFFFFFFFFF0000ull) |
              (unsigned long long)(65535u - (unsigned)a);
      }
    }
    cand[i] = key;
  }
  __syncthreads();

  // ---- 2. bitonic sort desc (shfl for j<64): (score bits desc, idx asc) ----
  unsigned n2 = (ccount <= 256u) ? 256u : 512u;
  unsigned long long v = ((unsigned)tid < n2) ? cand[tid] : 0ull;
  for (unsigned k2 = 2; k2 <= n2; k2 <<= 1) {
    for (unsigned j = k2 >> 1; j > 0; j >>= 1) {
      unsigned long long p;
      if (j >= 64) {
        __syncthreads();
        if ((unsigned)tid < n2) cand[tid] = v;
        __syncthreads();
        p = ((unsigned)tid < n2) ? cand[tid ^ j] : 0ull;
      } else {
        p = __shfl_xor(v, (int)j, 64);
      }
      if ((unsigned)tid < n2) {
        bool desc = ((tid & (int)k2) == 0);
        bool lower = ((tid & (int)j) == 0);
        bool takemax = (lower == desc);
        bool vge = (v >= p);
        v = takemax ? (vge ? v : p) : (vge ? p : v);
      }
    }
  }
  __syncthreads();
  if ((unsigned)tid < n2) cand[tid] = v;
  __syncthreads();

  // ---- 3. decode candidate boxes (f64) + packed f32/f64 mirrors ----
  if ((unsigned)tid < Ct) {
    unsigned long long key = cand[tid];
    bool valid = (key >> 16) != 0ull;
    double o[4] = {0.0, 0.0, 0.0, 0.0};
    double aa = 0.0;
    if (valid) {
      unsigned a = (65535u - (unsigned)(key & 0xFFFFull)) & (A - 1);
      decode_d(loc, anchor, base + a, a, o);
      aa = (o[2] - o[0]) * (o[3] - o[1]);
    }
    cd4[tid] = make_double4(o[0], o[1], o[2], o[3]);
    dar[tid] = aa;
    cf4[tid] = make_float4((float)o[0], (float)o[1], (float)o[2], (float)o[3]);
    car[tid] = (float)aa;
  }
  __syncthreads();

  // ---- 4. IoU rows, UPPER TRIANGLE ONLY (bits j<=i never read by scan);
  //         f32 fast path, exact f64 guard when |margin| <= 1e-5 ----
  int Cti = (int)Ct;
  int total_iw = Cti * 8;
  for (int id = tid; id < total_iw; id += NT) {
    int i = id % Cti;
    int w = id / Cti;
    int j0 = w * 32;
    unsigned bits = 0;
    if (j0 + 32 > i + 1) {              // window contains some j > i
      float4 bi = cf4[i];
      float ai = car[i];
      int jlo = (j0 > i) ? j0 : (i + 1);
      int jhi = (j0 + 32 < Cti) ? (j0 + 32) : Cti;
      for (int j = jlo; j < jhi; ++j) {
        float4 bj = cf4[j];
        float ltx = fmaxf(bi.x, bj.x);
        float lty = fmaxf(bi.y, bj.y);
        float rbx = fminf(bi.z, bj.z);
        float rby = fminf(bi.w, bj.w);
        float iw = fmaxf(rbx - ltx, 0.f);
        float ih = fmaxf(rby - lty, 0.f);
        float inter = iw * ih;
        float den = ai + car[j] - inter + 1e-9f;
        float dmar = inter - 0.5f * den;
        bool bit;
        if (fabsf(dmar) > 1e-5f) {
          bit = dmar > 0.f;
        } else {
          double4 Bi = cd4[i], Bj = cd4[j];
          double LTX = fmax(Bi.x, Bj.x);
          double LTY = fmax(Bi.y, Bj.y);
          double RBX = fmin(Bi.z, Bj.z);
          double RBY = fmin(Bi.w, Bj.w);
          double IW = fmax(RBX - LTX, 0.0);
          double IH = fmax(RBY - LTY, 0.0);
          double INTER = IW * IH;
          double DEN = dar[i] + dar[j] - INTER + 1e-9;
          bit = INTER > 0.5 * DEN;
        }
        if (bit) bits |= 1u << (j - j0);
      }
    }
    rows[i * 8 + w] = bits;
  }
  __syncthreads();

  // ---- 5. greedy scan (wave 0; matches lax.scan semantics) ----
  if (tid < 64) {
    unsigned supp = 0;
    for (int i = 0; i < Cti; ++i) {
      unsigned wsrc = __shfl(supp, i >> 5);
      bool kkeep = ((wsrc >> (i & 31)) & 1u) == 0u;
      if (tid == 0) kp[i] = kkeep ? 1u : 0u;
      unsigned rw = (tid < 8) ? rows[i * 8 + tid] : 0u;
      if (kkeep) supp |= rw;
    }
  }
  __syncthreads();

  // ---- 6. write objs + keep ----
  if (tid < K) {
    bool kkeep = ((unsigned)tid < Ct) && (kp[tid] != 0u) && ((cand[tid] >> 16) != 0ull);
    float o0 = 0.f, o1 = 0.f, o2 = 0.f, o3 = 0.f, o4 = 0.f;
    if (kkeep) {
      double4 Bi = cd4[tid];
      o0 = (float)Bi.x; o1 = (float)Bi.y; o2 = (float)Bi.z; o3 = (float)Bi.w;
      double sd = __longlong_as_double(
          (long long)(cand[tid] & 0xFFFFFFFFFFFF0000ull));
      o4 = (float)sd;
    }
    size_t ob = ((size_t)bc * K + tid) * 5;
    out[ob + 0] = o0; out[ob + 1] = o1; out[ob + 2] = o2;
    out[ob + 3] = o3; out[ob + 4] = o4;
    out[(size_t)B * NC * K * 5 + (size_t)bc * K + tid] = kkeep ? 1.f : 0.f;
  }
}

// ==================== FALLBACK: round-6 fused select (passing) ==============
__global__ __launch_bounds__(512) void select_fast(
    const float* __restrict__ conf, const float* __restrict__ marr,
    const double* __restrict__ sarr, const float* __restrict__ loc,
    const float* __restrict__ anchor, const unsigned short* __restrict__ keys,
    const unsigned* __restrict__ ghist, float* __restrict__ out) {
  constexpr int NT = 512;
  __shared__ unsigned hist[NBIN];
  __shared__ unsigned wtot[8], wsuf[8];
  __shared__ unsigned long long cand[512];
  __shared__ int clist[512];
  __shared__ double cbd5[K * 5];
  __shared__ unsigned rows[K * 8];
  __shared__ unsigned kp[K];
  __shared__ unsigned sh_cnt, sh_selbin, sh_total;

  int tid = threadIdx.x;
  unsigned lane = tid & 63, wid = tid >> 6;
  int bc = blockIdx.x;
  int b = bc / NC, c = bc % NC;
  size_t base = (size_t)b << ABITS;
  const unsigned short* krow = keys + ((size_t)bc << ABITS);
  const uint4* kv = (const uint4*)krow;

  if (tid == 0) sh_cnt = 0;

  unsigned h0 = 0, h1 = 0;
  if (ghist) {
    if (tid < NBIN / 2) {
      uint2 hh = ((const uint2*)(ghist + (size_t)bc * NBIN))[tid];
      h0 = hh.x; h1 = hh.y;
    }
  } else {
    for (int i = tid; i < NBIN; i += NT) hist[i] = 0;
    __syncthreads();
    for (int i = tid; i < A / 8; i += NT) {
      uint4 v = kv[i];
      unsigned w[4] = {v.x, v.y, v.z, v.w};
#pragma unroll
      for (int q = 0; q < 4; ++q) {
        unsigned lo = w[q] & 0xFFFFu, hi = w[q] >> 16;
        if (lo) atomicAdd(&hist[min(lo - KBASE, (unsigned)(NBIN - 1))], 1u);
        if (hi) atomicAdd(&hist[min(hi - KBASE, (unsigned)(NBIN - 1))], 1u);
      }
    }
    __syncthreads();
    if (tid < NBIN / 2) { h0 = hist[2 * tid]; h1 = hist[2 * tid + 1]; }
  }

  unsigned s = h0 + h1;
  unsigned S = s;
#pragma unroll
  for (int d = 1; d < 64; d <<= 1) {
    unsigned o = __shfl_down(S, d, 64);
    if (lane + d < 64) S += o;
  }
  if (lane == 0) wtot[wid] = S;
  __syncthreads();
  if (tid < 8) {
    unsigned acc = 0;
    for (int w2 = tid + 1; w2 < 8; ++w2) acc += wtot[w2];
    wsuf[tid] = acc;
    if (tid == 0) sh_total = acc + wtot[0];
  }
  __syncthreads();
  unsigned Sfull = S + wsuf[wid];
  unsigned above2 = Sfull - s;
  unsigned cg1 = h1 + above2;
  unsigned cg0 = h0 + cg1;
  if (cg1 >= (unsigned)K && above2 < (unsigned)K) sh_selbin = tid * 2 + 1;
  if (cg0 >= (unsigned)K && cg1 < (unsigned)K) sh_selbin = tid * 2 + 0;
  __syncthreads();
  unsigned pivot16 = (sh_total <= (unsigned)K) ? KBASE : (KBASE + sh_selbin);

  for (int i = tid; i < A / 8; i += NT) {
    uint4 v = kv[i];
    unsigned w[4] = {v.x, v.y, v.z, v.w};
#pragma unroll
    for (int q = 0; q < 4; ++q) {
      unsigned lo = w[q] & 0xFFFFu, hi = w[q] >> 16;
      if (lo >= pivot16) {
        unsigned pos = atomicAdd(&sh_cnt, 1u);
        if (pos < 512) clist[pos] = i * 8 + q * 2 + 0;
      }
      if (hi >= pivot16) {
        unsigned pos = atomicAdd(&sh_cnt, 1u);
        if (pos < 512) clist[pos] = i * 8 + q * 2 + 1;
      }
    }
  }
  __syncthreads();
  unsigned ccount = sh_cnt < 512u ? sh_cnt : 512u;
  unsigned Ct = ccount < (unsigned)K ? ccount : (unsigned)K;

  for (int i = tid; i < 512; i += NT) {
    unsigned long long key = 0ull;
    if ((unsigned)i < ccount) {
      int a = clist[i];
      size_t ba = base + a;
      double sd = exp((double)conf[ba * NCP1 + (c + 1)] - (double)marr[ba]) / sarr[ba];
      if (sd >= TH_CONF) {
        unsigned long long db = (unsigned long long)__double_as_longlong(sd);
        key = (db & 0xFFFFFFFFFFFF0000ull) |
              (unsigned long long)(65535u - (unsigned)a);
      }
    }
    cand[i] = key;
  }
  __syncthreads();

  unsigned n2 = (ccount <= 256u) ? 256u : 512u;
  unsigned long long v = ((unsigned)tid < n2) ? cand[tid] : 0ull;
  for (unsigned k2 = 2; k2 <= n2; k2 <<= 1) {
    for (unsigned j = k2 >> 1; j > 0; j >>= 1) {
      unsigned long long p;
      if (j >= 64) {
        __syncthreads();
        if ((unsigned)tid < n2) cand[tid] = v;
        __syncthreads();
        p = ((unsigned)tid < n2) ? cand[tid ^ j] : 0ull;
      } else {
        p = __shfl_xor(v, (int)j, 64);
      }
      if ((unsigned)tid < n2) {
        bool desc = ((tid & (int)k2) == 0);
        bool lower = ((tid & (int)j) == 0);
        bool takemax = (lower == desc);
        bool vge = (v >= p);
        v = takemax ? (vge ? v : p) : (vge ? p : v);
      }
    }
  }
  __syncthreads();
  if ((unsigned)tid < n2) cand[tid] = v;
  __syncthreads();

  if ((unsigned)tid < Ct) {
    unsigned long long key = cand[tid];
    bool valid = (key >> 16) != 0ull;
    double o[4] = {0.0, 0.0, 0.0, 0.0};
    double aa = 0.0;
    if (valid) {
      unsigned a = (65535u - (unsigned)(key & 0xFFFFull)) & (A - 1);
      decode_d(loc, anchor, base + a, a, o);
      aa = (o[2] - o[0]) * (o[3] - o[1]);
    }
    cbd5[tid * 5 + 0] = o[0]; cbd5[tid * 5 + 1] = o[1];
    cbd5[tid * 5 + 2] = o[2]; cbd5[tid * 5 + 3] = o[3];
    cbd5[tid * 5 + 4] = aa;
  }
  __syncthreads();

  int total_iw = (int)Ct * 8;
  for (int id = tid; id < total_iw; id += NT) {
    int i = id % (int)Ct;
    int w = id / (int)Ct;
    double xi0 = cbd5[i * 5 + 0], yi0 = cbd5[i * 5 + 1];
    double xi1 = cbd5[i * 5 + 2], yi1 = cbd5[i * 5 + 3];
    double ai = cbd5[i * 5 + 4];
    unsigned bits = 0;
    int j0 = w * 32;
    for (int jj = 0; jj < 32; ++jj) {
      int j = j0 + jj;
      if (j < (int)Ct) {
        double ltx = fmax(xi0, cbd5[j * 5 + 0]);
        double lty = fmax(yi0, cbd5[j * 5 + 1]);
        double rbx = fmin(xi1, cbd5[j * 5 + 2]);
        double rby = fmin(yi1, cbd5[j * 5 + 3]);
        double iw = fmax(rbx - ltx, 0.0);
        double ih = fmax(rby - lty, 0.0);
        double inter = iw * ih;
        double den = ai + cbd5[j * 5 + 4] - inter + 1e-9;
        if (inter > 0.5 * den) bits |= (1u << jj);
      }
    }
    rows[i * 8 + w] = bits;
  }
  __syncthreads();

  if (tid < 64) {
    unsigned supp = 0;
    for (int i = 0; i < (int)Ct; ++i) {
      unsigned wsrc = __shfl(supp, i >> 5);
      bool kkeep = ((wsrc >> (i & 31)) & 1u) == 0u;
      if (tid == 0) kp[i] = kkeep ? 1u : 0u;
      unsigned rw = (tid < 8) ? rows[i * 8 + tid] : 0u;
      if (kkeep) supp |= rw;
    }
  }
  __syncthreads();

  if (tid < K) {
    bool kkeep = ((unsigned)tid < Ct) && (kp[tid] != 0u) && ((cand[tid] >> 16) != 0ull);
    float o0 = 0.f, o1 = 0.f, o2 = 0.f, o3 = 0.f, o4 = 0.f;
    if (kkeep) {
      o0 = (float)cbd5[tid * 5 + 0]; o1 = (float)cbd5[tid * 5 + 1];
      o2 = (float)cbd5[tid * 5 + 2]; o3 = (float)cbd5[tid * 5 + 3];
      double sd = __longlong_as_double(
          (long long)(cand[tid] & 0xFFFFFFFFFFFF0000ull));
      o4 = (float)sd;
    }
    size_t ob = ((size_t)bc * K + tid) * 5;
    out[ob + 0] = o0; out[ob + 1] = o1; out[ob + 2] = o2;
    out[ob + 3] = o3; out[ob + 4] = o4;
    out[(size_t)B * NC * K * 5 + (size_t)bc * K + tid] = kkeep ? 1.f : 0.f;
  }
}

// ============================ FALLBACK PATH (round-2, passing) ==============
__global__ __launch_bounds__(256) void prep_kernel(
    const float* __restrict__ conf, float* __restrict__ marr,
    double* __restrict__ sarr) {
  int idx = blockIdx.x * 256 + threadIdx.x;
  const float* cp = conf + (size_t)idx * NCP1;
  float x[NCP1];
#pragma unroll
  for (int i = 0; i < NCP1; ++i) x[i] = cp[i];
  float m = x[0];
#pragma unroll
  for (int i = 1; i < NCP1; ++i) m = fmaxf(m, x[i]);
  double S = 0.0;
#pragma unroll
  for (int i = 0; i < NCP1; ++i) S += exp((double)x[i] - (double)m);
  marr[idx] = m;
  sarr[idx] = S;
}

__device__ __forceinline__ double get_sd(const float* __restrict__ conf,
                                         const float* __restrict__ marr,
                                         const double* __restrict__ sarr,
                                         size_t ba, int c) {
  const float* cp = conf + ba * NCP1;
  float m;
  double S;
  if (sarr) {
    m = marr[ba];
    S = sarr[ba];
  } else {
    m = cp[0];
    for (int i = 1; i < NCP1; ++i) m = fmaxf(m, cp[i]);
    S = 0.0;
    for (int i = 0; i < NCP1; ++i) S += exp((double)cp[i] - (double)m);
  }
  return exp((double)cp[c + 1] - (double)m) / S;
}

__global__ __launch_bounds__(256) void select_nms_kernel(
    const float* __restrict__ conf, const float* __restrict__ marr,
    const double* __restrict__ sarr, const float* __restrict__ loc,
    const float* __restrict__ anchor, float* __restrict__ out) {
  __shared__ __align__(16) unsigned short s16[A];
  __shared__ unsigned hist[256];
  __shared__ unsigned scan0[256];
  __shared__ unsigned long long cand[512];
  __shared__ unsigned sh_cnt, sh_selbin, sh_need, sh_ctot;

  double* cbd = (double*)s16;
  double* ar = cbd + K * 4;
  unsigned* rows = (unsigned*)(ar + K);
  unsigned* kp = rows + K * 8;

  int tid = threadIdx.x;
  int bc = blockIdx.x;
  int b = bc / NC, c = bc % NC;
  size_t base = (size_t)b << ABITS;

  for (int a = tid; a < A; a += 256) {
    double sd = get_sd(conf, marr, sarr, base + a, c);
    unsigned short key = 0;
    if (sd >= TH_CONF) {
      float f = (float)sd;
      key = (unsigned short)(__float_as_uint(f) >> 16);
    }
    s16[a] = key;
  }
  __syncthreads();

  unsigned need = K, pfx = 0;
  bool smallcase = false;
  for (int p = 0; p < 2; ++p) {
    hist[tid] = 0;
    __syncthreads();
    for (int a = tid; a < A; a += 256) {
      unsigned v = s16[a];
      if (v && (p == 0 || (v >> 8) == pfx))
        atomicAdd(&hist[(p == 0) ? (v >> 8) : (v & 0xFFu)], 1u);
    }
    __syncthreads();
    scan0[tid] = hist[tid];
    __syncthreads();
    for (int st = 1; st < 256; st <<= 1) {
      unsigned mine = scan0[tid];
      unsigned oth = (tid + st < 256) ? scan0[tid + st] : 0u;
      __syncthreads();
      scan0[tid] = mine + oth;
      __syncthreads();
    }
    if (p == 0) {
      if (tid == 0) sh_ctot = scan0[0];
      __syncthreads();
      if (sh_ctot <= (unsigned)K) { smallcase = true; break; }
    }
    unsigned nxt = (tid == 255) ? 0u : scan0[tid + 1];
    if (scan0[tid] >= need && nxt < need) { sh_selbin = tid; sh_need = need - nxt; }
    __syncthreads();
    pfx = (pfx << 8) | sh_selbin;
    need = sh_need;
    __syncthreads();
  }
  unsigned pivot16 = smallcase ? 0x3D4Cu : pfx;

  if (tid == 0) sh_cnt = 0;
  __syncthreads();
  for (int a = tid; a < A; a += 256) {
    double sd = get_sd(conf, marr, sarr, base + a, c);
    if (sd >= TH_CONF) {
      float f = (float)sd;
      if ((__float_as_uint(f) >> 16) >= pivot16) {
        unsigned pos = atomicAdd(&sh_cnt, 1u);
        if (pos < 512) {
          unsigned long long db = (unsigned long long)__double_as_longlong(sd);
          cand[pos] = (db & 0xFFFFFFFFFFFF0000ull) |
                      (unsigned long long)(65535u - (unsigned)a);
        }
      }
    }
  }
  __syncthreads();
  unsigned ccount = sh_cnt < 512u ? sh_cnt : 512u;
  unsigned Ct = ccount < (unsigned)K ? ccount : (unsigned)K;
  for (int i = tid; i < 512; i += 256)
    if ((unsigned)i >= ccount) cand[i] = 0ull;
  __syncthreads();

  for (unsigned k2 = 2; k2 <= 512; k2 <<= 1) {
    for (unsigned j = k2 >> 1; j > 0; j >>= 1) {
      for (unsigned i = tid; i < 512; i += 256) {
        unsigned ixj = i ^ j;
        if (ixj > i) {
          unsigned long long va = cand[i], vb = cand[ixj];
          bool desc = ((i & k2) == 0);
          if (desc ? (va < vb) : (va > vb)) { cand[i] = vb; cand[ixj] = va; }
        }
      }
      __syncthreads();
    }
  }

  if ((unsigned)tid < Ct) {
    unsigned a = 65535u - (unsigned)(cand[tid] & 0xFFFFull);
    double o[4];
    decode_d(loc, anchor, base + a, a, o);
    cbd[tid * 4 + 0] = o[0]; cbd[tid * 4 + 1] = o[1];
    cbd[tid * 4 + 2] = o[2]; cbd[tid * 4 + 3] = o[3];
    ar[tid] = (o[2] - o[0]) * (o[3] - o[1]);
  }
  __syncthreads();

  for (int id = tid; id < (int)Ct * 8; id += 256) {
    int i = id >> 3, w = id & 7;
    double xi0 = cbd[i * 4 + 0], yi0 = cbd[i * 4 + 1];
    double xi1 = cbd[i * 4 + 2], yi1 = cbd[i * 4 + 3];
    double ai = ar[i];
    unsigned bits = 0;
    int j0 = w * 32;
    for (int jj = 0; jj < 32; ++jj) {
      int j = j0 + jj;
      if (j < (int)Ct) {
        double ltx = fmax(xi0, cbd[j * 4 + 0]);
        double lty = fmax(yi0, cbd[j * 4 + 1]);
        double rbx = fmin(xi1, cbd[j * 4 + 2]);
        double rby = fmin(yi1, cbd[j * 4 + 3]);
        double iw = fmax(rbx - ltx, 0.0);
        double ih = fmax(rby - lty, 0.0);
        double inter = iw * ih;
        double iou = inter / (ai + ar[j] - inter + 1e-9);
        if (iou > TH_IOU) bits |= (1u << jj);
      }
    }
    rows[i * 8 + w] = bits;
  }
  __syncthreads();

  if (tid < 64) {
    unsigned supp = 0;
    for (int i = 0; i < (int)Ct; ++i) {
      unsigned wsrc = __shfl(supp, i >> 5);
      bool kkeep = ((wsrc >> (i & 31)) & 1u) == 0u;
      if (tid == 0) kp[i] = kkeep ? 1u : 0u;
      unsigned rw = (tid < 8) ? rows[i * 8 + tid] : 0u;
      if (kkeep) supp |= rw;
    }
  }
  __syncthreads();

  if (tid < K) {
    bool kkeep = ((unsigned)tid < Ct) && (kp[tid] != 0u);
    float o0 = 0.f, o1 = 0.f, o2 = 0.f, o3 = 0.f, o4 = 0.f;
    if (kkeep) {
      o0 = (float)cbd[tid * 4 + 0]; o1 = (float)cbd[tid * 4 + 1];
      o2 = (float)cbd[tid * 4 + 2]; o3 = (float)cbd[tid * 4 + 3];
      double sd = __longlong_as_double(
          (long long)(cand[tid] & 0xFFFFFFFFFFFF0000ull));
      o4 = (float)sd;
    }
    size_t ob = ((size_t)bc * K + tid) * 5;
    out[ob + 0] = o0; out[ob + 1] = o1; out[ob + 2] = o2;
    out[ob + 3] = o3; out[ob + 4] = o4;
    out[(size_t)B * NC * K * 5 + (size_t)bc * K + tid] = kkeep ? 1.f : 0.f;
  }
}

extern "C" void kernel_launch(void* const* d_in, const int* in_sizes, int n_in,
                              void* d_out, int out_size, void* d_ws, size_t ws_size,
                              hipStream_t stream) {
  (void)in_sizes; (void)n_in; (void)out_size;
  const float* conf = (const float*)d_in[0];
  const float* loc = (const float*)d_in[1];
  const float* anchor = (const float*)d_in[2];
  float* out = (float*)d_out;

  size_t nBA = (size_t)B * A;
  size_t off_sarr = 0;
  size_t off_marr = off_sarr + nBA * sizeof(double);
  size_t off_keys = off_marr + nBA * sizeof(float);
  size_t off_ghist = off_keys + nBA * NC * sizeof(unsigned short);
  size_t ghist_bytes = (size_t)B * NC * NBIN * sizeof(unsigned);
  size_t off_gctr = off_ghist + ghist_bytes;
  size_t gctr_bytes = (size_t)B * NC * sizeof(unsigned);
  size_t off_clist = off_gctr + gctr_bytes;
  size_t clist_bytes = (size_t)B * NC * CAP * sizeof(int);
  size_t need_v7 = off_clist + clist_bytes;         // ~57.3 MB
  size_t need_fast2 = off_gctr;                     // round-6 tier
  size_t need_fast = off_ghist;                     // round-3 tier
  size_t need_mid = nBA * (sizeof(float) + sizeof(double));  // 12 MB

  if (ws_size >= need_fast) {
    double* sarr = (double*)((char*)d_ws + off_sarr);
    float* marr = (float*)((char*)d_ws + off_marr);
    unsigned short* keys = (unsigned short*)((char*)d_ws + off_keys);
    prep_fast<<<(B * A) / 256, 256, 0, stream>>>(conf, marr, sarr, keys);
    if (ws_size >= need_v7) {
      unsigned* ghist = (unsigned*)((char*)d_ws + off_ghist);
      unsigned* gctr = (unsigned*)((char*)d_ws + off_gctr);
      int* clist = (int*)((char*)d_ws + off_clist);
      hipMemsetAsync(ghist, 0, ghist_bytes + gctr_bytes, stream);
      prehist_kernel<<<B * NC * 4, 256, 0, stream>>>(keys, ghist);
      collect_kernel<<<B * NC * 4, 256, 0, stream>>>(keys, ghist, gctr, clist);
      nms_kernel<<<B * NC, 512, 0, stream>>>(conf, marr, sarr, loc, anchor,
                                             gctr, clist, out);
    } else if (ws_size >= need_fast2) {
      unsigned* ghist = (unsigned*)((char*)d_ws + off_ghist);
      hipMemsetAsync(ghist, 0, ghist_bytes, stream);
      prehist_kernel<<<B * NC * 4, 256, 0, stream>>>(keys, ghist);
      select_fast<<<B * NC, 512, 0, stream>>>(conf, marr, sarr, loc, anchor,
                                              keys, ghist, out);
    } else {
      select_fast<<<B * NC, 512, 0, stream>>>(conf, marr, sarr, loc, anchor,
                                              keys, nullptr, out);
    }
  } else if (ws_size >= need_mid) {
    float* marr = (float*)d_ws;
    double* sarr = (double*)((char*)d_ws + nBA * sizeof(float));
    prep_kernel<<<(B * A) / 256, 256, 0, stream>>>(conf, marr, sarr);
    select_nms_kernel<<<B * NC, 256, 0, stream>>>(conf, marr, sarr, loc, anchor, out);
  } else {
    select_nms_kernel<<<B * NC, 256, 0, stream>>>(conf, nullptr, nullptr, loc, anchor, out);
  }
}

// Round 10
// 98.982 us; speedup vs baseline: 1.9756x; 1.1220x over previous
//
#include <hip/hip_runtime.h>

// DetectPostProcess: softmax -> decode -> per-(b,c) top-200 -> greedy NMS.
// Decisions (ordering, top-K membership, IoU>0.5) identical to rounds 2..9
// (f64 everywhere it matters; f32 IoU fast path guarded by exact f64
// recompute within |margin|<=1e-5).
// Round 10: greedy scan made LDS-free — IoU bits stored COLUMN-major, scan
// holds column words + suppressed flags in REGISTERS, broadcast via
// v_readlane (VALU) instead of ds_bpermute. Removes ~240 LDS-latency cycles
// per scan iteration (~20us/block -> ~1.5us).
// Outputs: objs [B,NC,K,5] then keep [B,NC,K] (as 0.0/1.0), flat in d_out.

constexpr int B = 32;
constexpr int A = 32768;     // power of two
constexpr int ABITS = 15;    // log2(A)
constexpr int NCP1 = 21;
constexpr int NC = 20;
constexpr int K = 200;
constexpr int NBIN = 576;    // key range 0x3D4C..0x3F80 = 564 values
constexpr int CAP = 512;     // candidate capacity per (b,c)
#define KBASE 0x3D4Cu        // bits(0.05f) >> 16; min nonzero key

#define TH_CONF 0.05
#define TH_IOU  0.5

// ============================ FAST PATH =====================================
// prep_fast: per (b,a): m (f32 max), S (f64 sum), and 20 transposed u16 keys.
__global__ __launch_bounds__(256) void prep_fast(
    const float* __restrict__ conf, float* __restrict__ marr,
    double* __restrict__ sarr, unsigned short* __restrict__ keys) {
  int idx = blockIdx.x * 256 + threadIdx.x;   // 0 .. B*A-1
  int b = idx >> ABITS;
  int a = idx & (A - 1);
  const float* cp = conf + (size_t)idx * NCP1;
  float x[NCP1];
#pragma unroll
  for (int i = 0; i < NCP1; ++i) x[i] = cp[i];
  float m = x[0];
#pragma unroll
  for (int i = 1; i < NCP1; ++i) m = fmaxf(m, x[i]);
  double e[NCP1];
  double S = 0.0;
#pragma unroll
  for (int i = 0; i < NCP1; ++i) {
    e[i] = exp((double)x[i] - (double)m);
    S += e[i];
  }
  marr[idx] = m;
  sarr[idx] = S;
  double rs = 1.0 / S;
  size_t kbase = ((size_t)(b * NC) << ABITS) + a;
#pragma unroll
  for (int c = 0; c < NC; ++c) {
    double sd = e[c + 1] * rs;                 // ~1ulp from e/S; key-grade only
    unsigned short key = 0;
    if (sd >= TH_CONF) {
      float f = (float)sd;
      key = (unsigned short)(__float_as_uint(f) >> 16);
    }
    keys[kbase + ((size_t)c << ABITS)] = key;
  }
}

// prehist: 4 blocks per (b,c); LDS-aggregated 576-bin histogram -> global.
__global__ __launch_bounds__(256) void prehist_kernel(
    const unsigned short* __restrict__ keys, unsigned* __restrict__ ghist) {
  __shared__ unsigned h[NBIN];
  int tid = threadIdx.x;
  int blk = blockIdx.x;          // 0..B*NC*4-1
  int bc = blk >> 2, chunk = blk & 3;
  for (int i = tid; i < NBIN; i += 256) h[i] = 0;
  __syncthreads();
  const uint4* kv = (const uint4*)(keys + ((size_t)bc << ABITS) + chunk * (A / 4));
  for (int i = tid; i < A / 4 / 8; i += 256) {   // 1024 uint4s
    uint4 v = kv[i];
    unsigned w[4] = {v.x, v.y, v.z, v.w};
#pragma unroll
    for (int q = 0; q < 4; ++q) {
      unsigned lo = w[q] & 0xFFFFu, hi = w[q] >> 16;
      if (lo) atomicAdd(&h[min(lo - KBASE, (unsigned)(NBIN - 1))], 1u);
      if (hi) atomicAdd(&h[min(hi - KBASE, (unsigned)(NBIN - 1))], 1u);
    }
  }
  __syncthreads();
  unsigned* grow = ghist + (size_t)bc * NBIN;
  for (int i = tid; i < NBIN; i += 256) {
    unsigned cnt = h[i];
    if (cnt) atomicAdd(&grow[i], cnt);
  }
}

// collect_kernel: 4 blocks per (b,c). Wave 0 derives the pivot from ghist;
// candidates staged in LDS, ONE global atomic per block reserves clist range.
__global__ __launch_bounds__(256) void collect_kernel(
    const unsigned short* __restrict__ keys, const unsigned* __restrict__ ghist,
    unsigned* __restrict__ gctr, int* __restrict__ clist) {
  __shared__ unsigned sh_pivot;
  __shared__ int lbuf[CAP];
  __shared__ unsigned lcnt, lbase;
  int tid = threadIdx.x;
  int blk = blockIdx.x;
  int bc = blk >> 2, chunk = blk & 3;

  if (tid == 0) lcnt = 0;
  if (tid < 64) {
    const unsigned* grow = ghist + (size_t)bc * NBIN;
    unsigned h[9];
    unsigned lsum = 0;
#pragma unroll
    for (int j = 0; j < 9; ++j) { h[j] = grow[tid * 9 + j]; lsum += h[j]; }
    unsigned S = lsum;                    // inclusive suffix over lanes
#pragma unroll
    for (int d = 1; d < 64; d <<= 1) {
      unsigned o = __shfl_down(S, d, 64);
      if (tid + d < 64) S += o;
    }
    unsigned total = __shfl(S, 0, 64);
    unsigned t = S - lsum;                // cnt_ge(first bin of lane tid+1)
    unsigned selbin = 0xFFFFFFFFu;
#pragma unroll
    for (int j = 8; j >= 0; --j) {        // walk bins high -> low
      unsigned tj = t + h[j];             // cnt_ge(tid*9 + j)
      if (tj >= (unsigned)K && t < (unsigned)K) selbin = tid * 9 + j;
      t = tj;
    }
#pragma unroll
    for (int d = 1; d < 64; d <<= 1) {    // unique -> min-reduce
      unsigned o = __shfl_xor(selbin, d, 64);
      selbin = min(selbin, o);
    }
    if (tid == 0)
      sh_pivot = (total <= (unsigned)K || selbin == 0xFFFFFFFFu)
                     ? KBASE : (KBASE + selbin);
  }
  __syncthreads();
  unsigned pivot16 = sh_pivot;

  const uint4* kv = (const uint4*)(keys + ((size_t)bc << ABITS) + chunk * (A / 4));
  int abase = chunk * (A / 4);
  for (int i = tid; i < A / 4 / 8; i += 256) {   // 1024 uint4s
    uint4 v = kv[i];
    unsigned w[4] = {v.x, v.y, v.z, v.w};
#pragma unroll
    for (int q = 0; q < 4; ++q) {
      unsigned lo = w[q] & 0xFFFFu, hi = w[q] >> 16;
      if (lo >= pivot16) {
        unsigned pos = atomicAdd(&lcnt, 1u);
        if (pos < (unsigned)CAP) lbuf[pos] = abase + i * 8 + q * 2 + 0;
      }
      if (hi >= pivot16) {
        unsigned pos = atomicAdd(&lcnt, 1u);
        if (pos < (unsigned)CAP) lbuf[pos] = abase + i * 8 + q * 2 + 1;
      }
    }
  }
  __syncthreads();
  unsigned n = lcnt < (unsigned)CAP ? lcnt : (unsigned)CAP;
  if (tid == 0) lbase = atomicAdd(&gctr[bc], n);
  __syncthreads();
  unsigned bpos = lbase;
  for (unsigned i = tid; i < n; i += 256) {
    unsigned pos = bpos + i;
    if (pos < (unsigned)CAP) clist[bc * CAP + pos] = lbuf[i];
  }
}

// f64 box decode for one anchor.
__device__ __forceinline__ void decode_d(const float* __restrict__ loc,
                                         const float* __restrict__ anchor,
                                         size_t ba, int a, double* o) {
  const float* lp = loc + ba * 4;
  const float* ap = anchor + (size_t)a * 4;
  double l0 = lp[0], l1 = lp[1], l2 = lp[2], l3 = lp[3];
  double cx = ap[0], cy = ap[1], aw = ap[2], ah = ap[3];
  double X = (l0 * 0.125) * aw + cx;
  double Y = (l1 * 0.125) * ah + cy;
  double bw = exp(l2 * 0.125) * aw;
  double bh = exp(l3 * 0.125) * ah;
  o[0] = X - bw * 0.5;
  o[1] = Y - bh * 0.5;
  o[2] = X + bw * 0.5;
  o[3] = Y + bh * 0.5;
}

// nms_kernel: one block per (b,c). Exact f64 rescore, shfl bitonic sort,
// f64 decode, column-major upper-triangle IoU, register-resident greedy scan.
__global__ __launch_bounds__(512) void nms_kernel(
    const float* __restrict__ conf, const float* __restrict__ marr,
    const double* __restrict__ sarr, const float* __restrict__ loc,
    const float* __restrict__ anchor, const unsigned* __restrict__ gctr,
    const int* __restrict__ clist, float* __restrict__ out) {
  constexpr int NT = 512;
  __shared__ unsigned long long cand[512];
  __shared__ float4 cf4[K];             // f32 box (fast path)
  __shared__ float car[K];              // f32 area
  __shared__ double4 cd4[K];            // f64 box (guard path)
  __shared__ double dar[K];             // f64 area
  __shared__ unsigned cols[K * 8];      // column-major IoU bits: cols[j*8+w5]
  __shared__ unsigned kpw[8];           // keep bit words

  int tid = threadIdx.x;
  int bc = blockIdx.x;
  int b = bc / NC, c = bc % NC;
  size_t base = (size_t)b << ABITS;

  unsigned ccount = gctr[bc];
  if (ccount > (unsigned)CAP) ccount = CAP;
  unsigned Ct = ccount < (unsigned)K ? ccount : (unsigned)K;

  // ---- 1. exact f64 scores for candidates; build sort keys ----
  for (int i = tid; i < 512; i += NT) {
    unsigned long long key = 0ull;
    if ((unsigned)i < ccount) {
      int a = clist[bc * CAP + i];
      size_t ba = base + a;
      double sd = exp((double)conf[ba * NCP1 + (c + 1)] - (double)marr[ba]) / sarr[ba];
      if (sd >= TH_CONF) {
        unsigned long long db = (unsigned long long)__double_as_longlong(sd);
        key = (db & 0xFFFFFFFFFFFF0000ull) |
              (unsigned long long)(65535u - (unsigned)a);
      }
    }
    cand[i] = key;
  }
  __syncthreads();

  // ---- 2. bitonic sort desc (shfl for j<64): (score bits desc, idx asc) ----
  unsigned n2 = (ccount <= 256u) ? 256u : 512u;
  unsigned long long v = ((unsigned)tid < n2) ? cand[tid] : 0ull;
  for (unsigned k2 = 2; k2 <= n2; k2 <<= 1) {
    for (unsigned j = k2 >> 1; j > 0; j >>= 1) {
      unsigned long long p;
      if (j >= 64) {
        __syncthreads();
        if ((unsigned)tid < n2) cand[tid] = v;
        __syncthreads();
        p = ((unsigned)tid < n2) ? cand[tid ^ j] : 0ull;
      } else {
        p = __shfl_xor(v, (int)j, 64);
      }
      if ((unsigned)tid < n2) {
        bool desc = ((tid & (int)k2) == 0);
        bool lower = ((tid & (int)j) == 0);
        bool takemax = (lower == desc);
        bool vge = (v >= p);
        v = takemax ? (vge ? v : p) : (vge ? p : v);
      }
    }
  }
  __syncthreads();
  if ((unsigned)tid < n2) cand[tid] = v;
  __syncthreads();

  // ---- 3. decode candidate boxes (f64) + packed f32/f64 mirrors ----
  if ((unsigned)tid < Ct) {
    unsigned long long key = cand[tid];
    bool valid = (key >> 16) != 0ull;
    double o[4] = {0.0, 0.0, 0.0, 0.0};
    double aa = 0.0;
    if (valid) {
      unsigned a = (65535u - (unsigned)(key & 0xFFFFull)) & (A - 1);
      decode_d(loc, anchor, base + a, a, o);
      aa = (o[2] - o[0]) * (o[3] - o[1]);
    }
    cd4[tid] = make_double4(o[0], o[1], o[2], o[3]);
    dar[tid] = aa;
    cf4[tid] = make_float4((float)o[0], (float)o[1], (float)o[2], (float)o[3]);
    car[tid] = (float)aa;
  }
  __syncthreads();

  // ---- 4. IoU COLUMN words (upper triangle i<j only; bits i>=j never read);
  //         f32 fast path, exact f64 guard when |margin| <= 1e-5 ----
  int Cti = (int)Ct;
  int total_jw = Cti * 7;
  for (int id = tid; id < total_jw; id += NT) {
    int j = id % Cti;
    int w5 = id / Cti;                  // 0..6
    int ilo = w5 * 32;
    unsigned bits = 0;
    if (ilo < j) {
      int ihi = (ilo + 32 < j) ? (ilo + 32) : j;
      float4 bj = cf4[j];
      float aj = car[j];
      for (int i = ilo; i < ihi; ++i) {
        float4 bi = cf4[i];
        float ltx = fmaxf(bi.x, bj.x);
        float lty = fmaxf(bi.y, bj.y);
        float rbx = fminf(bi.z, bj.z);
        float rby = fminf(bi.w, bj.w);
        float iw = fmaxf(rbx - ltx, 0.f);
        float ih = fmaxf(rby - lty, 0.f);
        float inter = iw * ih;
        float den = car[i] + aj - inter + 1e-9f;
        float dmar = inter - 0.5f * den;
        bool bit;
        if (fabsf(dmar) > 1e-5f) {
          bit = dmar > 0.f;
        } else {
          double4 Bi = cd4[i], Bj = cd4[j];
          double LTX = fmax(Bi.x, Bj.x);
          double LTY = fmax(Bi.y, Bj.y);
          double RBX = fmin(Bi.z, Bj.z);
          double RBY = fmin(Bi.w, Bj.w);
          double IW = fmax(RBX - LTX, 0.0);
          double IH = fmax(RBY - LTY, 0.0);
          double INTER = IW * IH;
          double DEN = dar[i] + dar[j] - INTER + 1e-9;
          bit = INTER > 0.5 * DEN;
        }
        if (bit) bits |= 1u << (i - ilo);
      }
    }
    cols[j * 8 + w5] = bits;
  }
  __syncthreads();

  // ---- 5. register-resident greedy scan (wave 0; matches lax.scan) ----
  if (tid < 64) {
    unsigned cb[4][7];                  // [slot][w5]; column j = slot*64 + tid
#pragma unroll
    for (int s = 0; s < 4; ++s) {
      int j = s * 64 + tid;
#pragma unroll
      for (int w5 = 0; w5 < 7; ++w5)
        cb[s][w5] = (j < Cti) ? cols[j * 8 + w5] : 0u;
    }
    unsigned sup[4] = {0u, 0u, 0u, 0u}; // suppressed flag per owned column
    unsigned kw[7] = {0u, 0u, 0u, 0u, 0u, 0u, 0u};
#pragma unroll
    for (int w5 = 0; w5 < 7; ++w5) {
      const int slot = w5 >> 1;
#pragma unroll
      for (int ii = 0; ii < 32; ++ii) {
        int i = w5 * 32 + ii;
        if (i < Cti) {
          int lane = (w5 & 1) * 32 + ii;            // = i & 63 (uniform)
          unsigned sflag = (unsigned)__builtin_amdgcn_readlane(
              (int)sup[slot], lane);
          unsigned km = (sflag == 0u) ? 0xFFFFFFFFu : 0u;
          kw[w5] |= (km & 1u) << ii;
#pragma unroll
          for (int s = 0; s < 4; ++s)
            sup[s] |= ((cb[s][w5] >> ii) & 1u) & km;
        }
      }
    }
    if (tid == 0) {
#pragma unroll
      for (int w5 = 0; w5 < 7; ++w5) kpw[w5] = kw[w5];
      kpw[7] = 0u;
    }
  }
  __syncthreads();

  // ---- 6. write objs + keep ----
  if (tid < K) {
    bool kkeep = ((unsigned)tid < Ct) &&
                 (((kpw[tid >> 5] >> (tid & 31)) & 1u) != 0u) &&
                 ((cand[tid] >> 16) != 0ull);
    float o0 = 0.f, o1 = 0.f, o2 = 0.f, o3 = 0.f, o4 = 0.f;
    if (kkeep) {
      double4 Bi = cd4[tid];
      o0 = (float)Bi.x; o1 = (float)Bi.y; o2 = (float)Bi.z; o3 = (float)Bi.w;
      double sd = __longlong_as_double(
          (long long)(cand[tid] & 0xFFFFFFFFFFFF0000ull));
      o4 = (float)sd;
    }
    size_t ob = ((size_t)bc * K + tid) * 5;
    out[ob + 0] = o0; out[ob + 1] = o1; out[ob + 2] = o2;
    out[ob + 3] = o3; out[ob + 4] = o4;
    out[(size_t)B * NC * K * 5 + (size_t)bc * K + tid] = kkeep ? 1.f : 0.f;
  }
}

// ==================== FALLBACK: round-6 fused select (passing) ==============
__global__ __launch_bounds__(512) void select_fast(
    const float* __restrict__ conf, const float* __restrict__ marr,
    const double* __restrict__ sarr, const float* __restrict__ loc,
    const float* __restrict__ anchor, const unsigned short* __restrict__ keys,
    const unsigned* __restrict__ ghist, float* __restrict__ out) {
  constexpr int NT = 512;
  __shared__ unsigned hist[NBIN];
  __shared__ unsigned wtot[8], wsuf[8];
  __shared__ unsigned long long cand[512];
  __shared__ int clist[512];
  __shared__ double cbd5[K * 5];
  __shared__ unsigned rows[K * 8];
  __shared__ unsigned kp[K];
  __shared__ unsigned sh_cnt, sh_selbin, sh_total;

  int tid = threadIdx.x;
  unsigned lane = tid & 63, wid = tid >> 6;
  int bc = blockIdx.x;
  int b = bc / NC, c = bc % NC;
  size_t base = (size_t)b << ABITS;
  const unsigned short* krow = keys + ((size_t)bc << ABITS);
  const uint4* kv = (const uint4*)krow;

  if (tid == 0) sh_cnt = 0;

  unsigned h0 = 0, h1 = 0;
  if (ghist) {
    if (tid < NBIN / 2) {
      uint2 hh = ((const uint2*)(ghist + (size_t)bc * NBIN))[tid];
      h0 = hh.x; h1 = hh.y;
    }
  } else {
    for (int i = tid; i < NBIN; i += NT) hist[i] = 0;
    __syncthreads();
    for (int i = tid; i < A / 8; i += NT) {
      uint4 v = kv[i];
      unsigned w[4] = {v.x, v.y, v.z, v.w};
#pragma unroll
      for (int q = 0; q < 4; ++q) {
        unsigned lo = w[q] & 0xFFFFu, hi = w[q] >> 16;
        if (lo) atomicAdd(&hist[min(lo - KBASE, (unsigned)(NBIN - 1))], 1u);
        if (hi) atomicAdd(&hist[min(hi - KBASE, (unsigned)(NBIN - 1))], 1u);
      }
    }
    __syncthreads();
    if (tid < NBIN / 2) { h0 = hist[2 * tid]; h1 = hist[2 * tid + 1]; }
  }

  unsigned s = h0 + h1;
  unsigned S = s;
#pragma unroll
  for (int d = 1; d < 64; d <<= 1) {
    unsigned o = __shfl_down(S, d, 64);
    if (lane + d < 64) S += o;
  }
  if (lane == 0) wtot[wid] = S;
  __syncthreads();
  if (tid < 8) {
    unsigned acc = 0;
    for (int w2 = tid + 1; w2 < 8; ++w2) acc += wtot[w2];
    wsuf[tid] = acc;
    if (tid == 0) sh_total = acc + wtot[0];
  }
  __syncthreads();
  unsigned Sfull = S + wsuf[wid];
  unsigned above2 = Sfull - s;
  unsigned cg1 = h1 + above2;
  unsigned cg0 = h0 + cg1;
  if (cg1 >= (unsigned)K && above2 < (unsigned)K) sh_selbin = tid * 2 + 1;
  if (cg0 >= (unsigned)K && cg1 < (unsigned)K) sh_selbin = tid * 2 + 0;
  __syncthreads();
  unsigned pivot16 = (sh_total <= (unsigned)K) ? KBASE : (KBASE + sh_selbin);

  for (int i = tid; i < A / 8; i += NT) {
    uint4 v = kv[i];
    unsigned w[4] = {v.x, v.y, v.z, v.w};
#pragma unroll
    for (int q = 0; q < 4; ++q) {
      unsigned lo = w[q] & 0xFFFFu, hi = w[q] >> 16;
      if (lo >= pivot16) {
        unsigned pos = atomicAdd(&sh_cnt, 1u);
        if (pos < 512) clist[pos] = i * 8 + q * 2 + 0;
      }
      if (hi >= pivot16) {
        unsigned pos = atomicAdd(&sh_cnt, 1u);
        if (pos < 512) clist[pos] = i * 8 + q * 2 + 1;
      }
    }
  }
  __syncthreads();
  unsigned ccount = sh_cnt < 512u ? sh_cnt : 512u;
  unsigned Ct = ccount < (unsigned)K ? ccount : (unsigned)K;

  for (int i = tid; i < 512; i += NT) {
    unsigned long long key = 0ull;
    if ((unsigned)i < ccount) {
      int a = clist[i];
      size_t ba = base + a;
      double sd = exp((double)conf[ba * NCP1 + (c + 1)] - (double)marr[ba]) / sarr[ba];
      if (sd >= TH_CONF) {
        unsigned long long db = (unsigned long long)__double_as_longlong(sd);
        key = (db & 0xFFFFFFFFFFFF0000ull) |
              (unsigned long long)(65535u - (unsigned)a);
      }
    }
    cand[i] = key;
  }
  __syncthreads();

  unsigned n2 = (ccount <= 256u) ? 256u : 512u;
  unsigned long long v = ((unsigned)tid < n2) ? cand[tid] : 0ull;
  for (unsigned k2 = 2; k2 <= n2; k2 <<= 1) {
    for (unsigned j = k2 >> 1; j > 0; j >>= 1) {
      unsigned long long p;
      if (j >= 64) {
        __syncthreads();
        if ((unsigned)tid < n2) cand[tid] = v;
        __syncthreads();
        p = ((unsigned)tid < n2) ? cand[tid ^ j] : 0ull;
      } else {
        p = __shfl_xor(v, (int)j, 64);
      }
      if ((unsigned)tid < n2) {
        bool desc = ((tid & (int)k2) == 0);
        bool lower = ((tid & (int)j) == 0);
        bool takemax = (lower == desc);
        bool vge = (v >= p);
        v = takemax ? (vge ? v : p) : (vge ? p : v);
      }
    }
  }
  __syncthreads();
  if ((unsigned)tid < n2) cand[tid] = v;
  __syncthreads();

  if ((unsigned)tid < Ct) {
    unsigned long long key = cand[tid];
    bool valid = (key >> 16) != 0ull;
    double o[4] = {0.0, 0.0, 0.0, 0.0};
    double aa = 0.0;
    if (valid) {
      unsigned a = (65535u - (unsigned)(key & 0xFFFFull)) & (A - 1);
      decode_d(loc, anchor, base + a, a, o);
      aa = (o[2] - o[0]) * (o[3] - o[1]);
    }
    cbd5[tid * 5 + 0] = o[0]; cbd5[tid * 5 + 1] = o[1];
    cbd5[tid * 5 + 2] = o[2]; cbd5[tid * 5 + 3] = o[3];
    cbd5[tid * 5 + 4] = aa;
  }
  __syncthreads();

  int total_iw = (int)Ct * 8;
  for (int id = tid; id < total_iw; id += NT) {
    int i = id % (int)Ct;
    int w = id / (int)Ct;
    double xi0 = cbd5[i * 5 + 0], yi0 = cbd5[i * 5 + 1];
    double xi1 = cbd5[i * 5 + 2], yi1 = cbd5[i * 5 + 3];
    double ai = cbd5[i * 5 + 4];
    unsigned bits = 0;
    int j0 = w * 32;
    for (int jj = 0; jj < 32; ++jj) {
      int j = j0 + jj;
      if (j < (int)Ct) {
        double ltx = fmax(xi0, cbd5[j * 5 + 0]);
        double lty = fmax(yi0, cbd5[j * 5 + 1]);
        double rbx = fmin(xi1, cbd5[j * 5 + 2]);
        double rby = fmin(yi1, cbd5[j * 5 + 3]);
        double iw = fmax(rbx - ltx, 0.0);
        double ih = fmax(rby - lty, 0.0);
        double inter = iw * ih;
        double den = ai + cbd5[j * 5 + 4] - inter + 1e-9;
        if (inter > 0.5 * den) bits |= (1u << jj);
      }
    }
    rows[i * 8 + w] = bits;
  }
  __syncthreads();

  if (tid < 64) {
    unsigned supp = 0;
    for (int i = 0; i < (int)Ct; ++i) {
      unsigned wsrc = __shfl(supp, i >> 5);
      bool kkeep = ((wsrc >> (i & 31)) & 1u) == 0u;
      if (tid == 0) kp[i] = kkeep ? 1u : 0u;
      unsigned rw = (tid < 8) ? rows[i * 8 + tid] : 0u;
      if (kkeep) supp |= rw;
    }
  }
  __syncthreads();

  if (tid < K) {
    bool kkeep = ((unsigned)tid < Ct) && (kp[tid] != 0u) && ((cand[tid] >> 16) != 0ull);
    float o0 = 0.f, o1 = 0.f, o2 = 0.f, o3 = 0.f, o4 = 0.f;
    if (kkeep) {
      o0 = (float)cbd5[tid * 5 + 0]; o1 = (float)cbd5[tid * 5 + 1];
      o2 = (float)cbd5[tid * 5 + 2]; o3 = (float)cbd5[tid * 5 + 3];
      double sd = __longlong_as_double(
          (long long)(cand[tid] & 0xFFFFFFFFFFFF0000ull));
      o4 = (float)sd;
    }
    size_t ob = ((size_t)bc * K + tid) * 5;
    out[ob + 0] = o0; out[ob + 1] = o1; out[ob + 2] = o2;
    out[ob + 3] = o3; out[ob + 4] = o4;
    out[(size_t)B * NC * K * 5 + (size_t)bc * K + tid] = kkeep ? 1.f : 0.f;
  }
}

// ============================ FALLBACK PATH (round-2, passing) ==============
__global__ __launch_bounds__(256) void prep_kernel(
    const float* __restrict__ conf, float* __restrict__ marr,
    double* __restrict__ sarr) {
  int idx = blockIdx.x * 256 + threadIdx.x;
  const float* cp = conf + (size_t)idx * NCP1;
  float x[NCP1];
#pragma unroll
  for (int i = 0; i < NCP1; ++i) x[i] = cp[i];
  float m = x[0];
#pragma unroll
  for (int i = 1; i < NCP1; ++i) m = fmaxf(m, x[i]);
  double S = 0.0;
#pragma unroll
  for (int i = 0; i < NCP1; ++i) S += exp((double)x[i] - (double)m);
  marr[idx] = m;
  sarr[idx] = S;
}

__device__ __forceinline__ double get_sd(const float* __restrict__ conf,
                                         const float* __restrict__ marr,
                                         const double* __restrict__ sarr,
                                         size_t ba, int c) {
  const float* cp = conf + ba * NCP1;
  float m;
  double S;
  if (sarr) {
    m = marr[ba];
    S = sarr[ba];
  } else {
    m = cp[0];
    for (int i = 1; i < NCP1; ++i) m = fmaxf(m, cp[i]);
    S = 0.0;
    for (int i = 0; i < NCP1; ++i) S += exp((double)cp[i] - (double)m);
  }
  return exp((double)cp[c + 1] - (double)m) / S;
}

__global__ __launch_bounds__(256) void select_nms_kernel(
    const float* __restrict__ conf, const float* __restrict__ marr,
    const double* __restrict__ sarr, const float* __restrict__ loc,
    const float* __restrict__ anchor, float* __restrict__ out) {
  __shared__ __align__(16) unsigned short s16[A];
  __shared__ unsigned hist[256];
  __shared__ unsigned scan0[256];
  __shared__ unsigned long long cand[512];
  __shared__ unsigned sh_cnt, sh_selbin, sh_need, sh_ctot;

  double* cbd = (double*)s16;
  double* ar = cbd + K * 4;
  unsigned* rows = (unsigned*)(ar + K);
  unsigned* kp = rows + K * 8;

  int tid = threadIdx.x;
  int bc = blockIdx.x;
  int b = bc / NC, c = bc % NC;
  size_t base = (size_t)b << ABITS;

  for (int a = tid; a < A; a += 256) {
    double sd = get_sd(conf, marr, sarr, base + a, c);
    unsigned short key = 0;
    if (sd >= TH_CONF) {
      float f = (float)sd;
      key = (unsigned short)(__float_as_uint(f) >> 16);
    }
    s16[a] = key;
  }
  __syncthreads();

  unsigned need = K, pfx = 0;
  bool smallcase = false;
  for (int p = 0; p < 2; ++p) {
    hist[tid] = 0;
    __syncthreads();
    for (int a = tid; a < A; a += 256) {
      unsigned v = s16[a];
      if (v && (p == 0 || (v >> 8) == pfx))
        atomicAdd(&hist[(p == 0) ? (v >> 8) : (v & 0xFFu)], 1u);
    }
    __syncthreads();
    scan0[tid] = hist[tid];
    __syncthreads();
    for (int st = 1; st < 256; st <<= 1) {
      unsigned mine = scan0[tid];
      unsigned oth = (tid + st < 256) ? scan0[tid + st] : 0u;
      __syncthreads();
      scan0[tid] = mine + oth;
      __syncthreads();
    }
    if (p == 0) {
      if (tid == 0) sh_ctot = scan0[0];
      __syncthreads();
      if (sh_ctot <= (unsigned)K) { smallcase = true; break; }
    }
    unsigned nxt = (tid == 255) ? 0u : scan0[tid + 1];
    if (scan0[tid] >= need && nxt < need) { sh_selbin = tid; sh_need = need - nxt; }
    __syncthreads();
    pfx = (pfx << 8) | sh_selbin;
    need = sh_need;
    __syncthreads();
  }
  unsigned pivot16 = smallcase ? 0x3D4Cu : pfx;

  if (tid == 0) sh_cnt = 0;
  __syncthreads();
  for (int a = tid; a < A; a += 256) {
    double sd = get_sd(conf, marr, sarr, base + a, c);
    if (sd >= TH_CONF) {
      float f = (float)sd;
      if ((__float_as_uint(f) >> 16) >= pivot16) {
        unsigned pos = atomicAdd(&sh_cnt, 1u);
        if (pos < 512) {
          unsigned long long db = (unsigned long long)__double_as_longlong(sd);
          cand[pos] = (db & 0xFFFFFFFFFFFF0000ull) |
                      (unsigned long long)(65535u - (unsigned)a);
        }
      }
    }
  }
  __syncthreads();
  unsigned ccount = sh_cnt < 512u ? sh_cnt : 512u;
  unsigned Ct = ccount < (unsigned)K ? ccount : (unsigned)K;
  for (int i = tid; i < 512; i += 256)
    if ((unsigned)i >= ccount) cand[i] = 0ull;
  __syncthreads();

  for (unsigned k2 = 2; k2 <= 512; k2 <<= 1) {
    for (unsigned j = k2 >> 1; j > 0; j >>= 1) {
      for (unsigned i = tid; i < 512; i += 256) {
        unsigned ixj = i ^ j;
        if (ixj > i) {
          unsigned long long va = cand[i], vb = cand[ixj];
          bool desc = ((i & k2) == 0);
          if (desc ? (va < vb) : (va > vb)) { cand[i] = vb; cand[ixj] = va; }
        }
      }
      __syncthreads();
    }
  }

  if ((unsigned)tid < Ct) {
    unsigned a = 65535u - (unsigned)(cand[tid] & 0xFFFFull);
    double o[4];
    decode_d(loc, anchor, base + a, a, o);
    cbd[tid * 4 + 0] = o[0]; cbd[tid * 4 + 1] = o[1];
    cbd[tid * 4 + 2] = o[2]; cbd[tid * 4 + 3] = o[3];
    ar[tid] = (o[2] - o[0]) * (o[3] - o[1]);
  }
  __syncthreads();

  for (int id = tid; id < (int)Ct * 8; id += 256) {
    int i = id >> 3, w = id & 7;
    double xi0 = cbd[i * 4 + 0], yi0 = cbd[i * 4 + 1];
    double xi1 = cbd[i * 4 + 2], yi1 = cbd[i * 4 + 3];
    double ai = ar[i];
    unsigned bits = 0;
    int j0 = w * 32;
    for (int jj = 0; jj < 32; ++jj) {
      int j = j0 + jj;
      if (j < (int)Ct) {
        double ltx = fmax(xi0, cbd[j * 4 + 0]);
        double lty = fmax(yi0, cbd[j * 4 + 1]);
        double rbx = fmin(xi1, cbd[j * 4 + 2]);
        double rby = fmin(yi1, cbd[j * 4 + 3]);
        double iw = fmax(rbx - ltx, 0.0);
        double ih = fmax(rby - lty, 0.0);
        double inter = iw * ih;
        double iou = inter / (ai + ar[j] - inter + 1e-9);
        if (iou > TH_IOU) bits |= (1u << jj);
      }
    }
    rows[i * 8 + w] = bits;
  }
  __syncthreads();

  if (tid < 64) {
    unsigned supp = 0;
    for (int i = 0; i < (int)Ct; ++i) {
      unsigned wsrc = __shfl(supp, i >> 5);
      bool kkeep = ((wsrc >> (i & 31)) & 1u) == 0u;
      if (tid == 0) kp[i] = kkeep ? 1u : 0u;
      unsigned rw = (tid < 8) ? rows[i * 8 + tid] : 0u;
      if (kkeep) supp |= rw;
    }
  }
  __syncthreads();

  if (tid < K) {
    bool kkeep = ((unsigned)tid < Ct) && (kp[tid] != 0u);
    float o0 = 0.f, o1 = 0.f, o2 = 0.f, o3 = 0.f, o4 = 0.f;
    if (kkeep) {
      o0 = (float)cbd[tid * 4 + 0]; o1 = (float)cbd[tid * 4 + 1];
      o2 = (float)cbd[tid * 4 + 2]; o3 = (float)cbd[tid * 4 + 3];
      double sd = __longlong_as_double(
          (long long)(cand[tid] & 0xFFFFFFFFFFFF0000ull));
      o4 = (float)sd;
    }
    size_t ob = ((size_t)bc * K + tid) * 5;
    out[ob + 0] = o0; out[ob + 1] = o1; out[ob + 2] = o2;
    out[ob + 3] = o3; out[ob + 4] = o4;
    out[(size_t)B * NC * K * 5 + (size_t)bc * K + tid] = kkeep ? 1.f : 0.f;
  }
}

extern "C" void kernel_launch(void* const* d_in, const int* in_sizes, int n_in,
                              void* d_out, int out_size, void* d_ws, size_t ws_size,
                              hipStream_t stream) {
  (void)in_sizes; (void)n_in; (void)out_size;
  const float* conf = (const float*)d_in[0];
  const float* loc = (const float*)d_in[1];
  const float* anchor = (const float*)d_in[2];
  float* out = (float*)d_out;

  size_t nBA = (size_t)B * A;
  size_t off_sarr = 0;
  size_t off_marr = off_sarr + nBA * sizeof(double);
  size_t off_keys = off_marr + nBA * sizeof(float);
  size_t off_ghist = off_keys + nBA * NC * sizeof(unsigned short);
  size_t ghist_bytes = (size_t)B * NC * NBIN * sizeof(unsigned);
  size_t off_gctr = off_ghist + ghist_bytes;
  size_t gctr_bytes = (size_t)B * NC * sizeof(unsigned);
  size_t off_clist = off_gctr + gctr_bytes;
  size_t clist_bytes = (size_t)B * NC * CAP * sizeof(int);
  size_t need_v7 = off_clist + clist_bytes;         // ~57.3 MB
  size_t need_fast2 = off_gctr;                     // round-6 tier
  size_t need_fast = off_ghist;                     // round-3 tier
  size_t need_mid = nBA * (sizeof(float) + sizeof(double));  // 12 MB

  if (ws_size >= need_fast) {
    double* sarr = (double*)((char*)d_ws + off_sarr);
    float* marr = (float*)((char*)d_ws + off_marr);
    unsigned short* keys = (unsigned short*)((char*)d_ws + off_keys);
    prep_fast<<<(B * A) / 256, 256, 0, stream>>>(conf, marr, sarr, keys);
    if (ws_size >= need_v7) {
      unsigned* ghist = (unsigned*)((char*)d_ws + off_ghist);
      unsigned* gctr = (unsigned*)((char*)d_ws + off_gctr);
      int* clist = (int*)((char*)d_ws + off_clist);
      hipMemsetAsync(ghist, 0, ghist_bytes + gctr_bytes, stream);
      prehist_kernel<<<B * NC * 4, 256, 0, stream>>>(keys, ghist);
      collect_kernel<<<B * NC * 4, 256, 0, stream>>>(keys, ghist, gctr, clist);
      nms_kernel<<<B * NC, 512, 0, stream>>>(conf, marr, sarr, loc, anchor,
                                             gctr, clist, out);
    } else if (ws_size >= need_fast2) {
      unsigned* ghist = (unsigned*)((char*)d_ws + off_ghist);
      hipMemsetAsync(ghist, 0, ghist_bytes, stream);
      prehist_kernel<<<B * NC * 4, 256, 0, stream>>>(keys, ghist);
      select_fast<<<B * NC, 512, 0, stream>>>(conf, marr, sarr, loc, anchor,
                                              keys, ghist, out);
    } else {
      select_fast<<<B * NC, 512, 0, stream>>>(conf, marr, sarr, loc, anchor,
                                              keys, nullptr, out);
    }
  } else if (ws_size >= need_mid) {
    float* marr = (float*)d_ws;
    double* sarr = (double*)((char*)d_ws + nBA * sizeof(float));
    prep_kernel<<<(B * A) / 256, 256, 0, stream>>>(conf, marr, sarr);
    select_nms_kernel<<<B * NC, 256, 0, stream>>>(conf, marr, sarr, loc, anchor, out);
  } else {
    select_nms_kernel<<<B * NC, 256, 0, stream>>>(conf, nullptr, nullptr, loc, anchor, out);
  }
}

// Round 11
// 97.185 us; speedup vs baseline: 2.0121x; 1.0185x over previous
//
#include <hip/hip_runtime.h>

// DetectPostProcess: softmax -> decode -> per-(b,c) top-200 -> greedy NMS.
// Decisions (ordering, top-K membership, IoU>0.5) identical to rounds 2..10
// (f64 everywhere it matters; f32 IoU fast path guarded by exact f64
// recompute within |margin|<=1e-5).
// Round 11: NO hipMemsetAsync (the rocclr fill kernel cost ~50us/replay for
// 1.4MB). prehist writes per-chunk histogram slices unconditionally; collect
// writes per-chunk clist segments + plain-store counts. Zero global atomics,
// zero pre-initialization required.
// Outputs: objs [B,NC,K,5] then keep [B,NC,K] (as 0.0/1.0), flat in d_out.

constexpr int B = 32;
constexpr int A = 32768;     // power of two
constexpr int ABITS = 15;    // log2(A)
constexpr int NCP1 = 21;
constexpr int NC = 20;
constexpr int K = 200;
constexpr int NBIN = 576;    // key range 0x3D4C..0x3F80 = 564 values
constexpr int CSEG = 512;    // per-chunk candidate segment capacity
#define KBASE 0x3D4Cu        // bits(0.05f) >> 16; min nonzero key

#define TH_CONF 0.05
#define TH_IOU  0.5

// ============================ FAST PATH =====================================
// prep_fast: per (b,a): m (f32 max), S (f64 sum), and 20 transposed u16 keys.
__global__ __launch_bounds__(256) void prep_fast(
    const float* __restrict__ conf, float* __restrict__ marr,
    double* __restrict__ sarr, unsigned short* __restrict__ keys) {
  int idx = blockIdx.x * 256 + threadIdx.x;   // 0 .. B*A-1
  int b = idx >> ABITS;
  int a = idx & (A - 1);
  const float* cp = conf + (size_t)idx * NCP1;
  float x[NCP1];
#pragma unroll
  for (int i = 0; i < NCP1; ++i) x[i] = cp[i];
  float m = x[0];
#pragma unroll
  for (int i = 1; i < NCP1; ++i) m = fmaxf(m, x[i]);
  double e[NCP1];
  double S = 0.0;
#pragma unroll
  for (int i = 0; i < NCP1; ++i) {
    e[i] = exp((double)x[i] - (double)m);
    S += e[i];
  }
  marr[idx] = m;
  sarr[idx] = S;
  double rs = 1.0 / S;
  size_t kbase = ((size_t)(b * NC) << ABITS) + a;
#pragma unroll
  for (int c = 0; c < NC; ++c) {
    double sd = e[c + 1] * rs;                 // ~1ulp from e/S; key-grade only
    unsigned short key = 0;
    if (sd >= TH_CONF) {
      float f = (float)sd;
      key = (unsigned short)(__float_as_uint(f) >> 16);
    }
    keys[kbase + ((size_t)c << ABITS)] = key;
  }
}

// prehist: 4 blocks per (b,c); each writes its FULL 576-bin histogram slice
// unconditionally (no zero-init, no global atomics).
__global__ __launch_bounds__(256) void prehist_kernel(
    const unsigned short* __restrict__ keys, unsigned* __restrict__ ghist4) {
  __shared__ unsigned h[NBIN];
  int tid = threadIdx.x;
  int blk = blockIdx.x;          // 0..B*NC*4-1
  int bc = blk >> 2, chunk = blk & 3;
  for (int i = tid; i < NBIN; i += 256) h[i] = 0;
  __syncthreads();
  const uint4* kv = (const uint4*)(keys + ((size_t)bc << ABITS) + chunk * (A / 4));
  for (int i = tid; i < A / 4 / 8; i += 256) {   // 1024 uint4s
    uint4 v = kv[i];
    unsigned w[4] = {v.x, v.y, v.z, v.w};
#pragma unroll
    for (int q = 0; q < 4; ++q) {
      unsigned lo = w[q] & 0xFFFFu, hi = w[q] >> 16;
      if (lo) atomicAdd(&h[min(lo - KBASE, (unsigned)(NBIN - 1))], 1u);
      if (hi) atomicAdd(&h[min(hi - KBASE, (unsigned)(NBIN - 1))], 1u);
    }
  }
  __syncthreads();
  unsigned* grow = ghist4 + (size_t)blk * NBIN;
  for (int i = tid; i < NBIN; i += 256) grow[i] = h[i];
}

// collect_kernel: 4 blocks per (b,c). Wave 0 derives the pivot by summing the
// 4 histogram slices (same counts as rounds 4-10 -> same pivot). Candidates
// staged in LDS, then written to this chunk's own clist segment with a
// plain-store count (no global atomics, no pre-zeroing).
__global__ __launch_bounds__(256) void collect_kernel(
    const unsigned short* __restrict__ keys, const unsigned* __restrict__ ghist4,
    unsigned* __restrict__ gcnt, int* __restrict__ clist4) {
  __shared__ unsigned sh_pivot;
  __shared__ int lbuf[CSEG];
  __shared__ unsigned lcnt;
  int tid = threadIdx.x;
  int blk = blockIdx.x;
  int bc = blk >> 2, chunk = blk & 3;

  if (tid == 0) lcnt = 0;
  if (tid < 64) {
    const unsigned* g0 = ghist4 + (size_t)bc * 4 * NBIN;
    unsigned h[9];
    unsigned lsum = 0;
#pragma unroll
    for (int j = 0; j < 9; ++j) {
      int bin = tid * 9 + j;
      h[j] = g0[bin] + g0[NBIN + bin] + g0[2 * NBIN + bin] + g0[3 * NBIN + bin];
      lsum += h[j];
    }
    unsigned S = lsum;                    // inclusive suffix over lanes
#pragma unroll
    for (int d = 1; d < 64; d <<= 1) {
      unsigned o = __shfl_down(S, d, 64);
      if (tid + d < 64) S += o;
    }
    unsigned total = __shfl(S, 0, 64);
    unsigned t = S - lsum;                // cnt_ge(first bin of lane tid+1)
    unsigned selbin = 0xFFFFFFFFu;
#pragma unroll
    for (int j = 8; j >= 0; --j) {        // walk bins high -> low
      unsigned tj = t + h[j];             // cnt_ge(tid*9 + j)
      if (tj >= (unsigned)K && t < (unsigned)K) selbin = tid * 9 + j;
      t = tj;
    }
#pragma unroll
    for (int d = 1; d < 64; d <<= 1) {    // unique -> min-reduce
      unsigned o = __shfl_xor(selbin, d, 64);
      selbin = min(selbin, o);
    }
    if (tid == 0)
      sh_pivot = (total <= (unsigned)K || selbin == 0xFFFFFFFFu)
                     ? KBASE : (KBASE + selbin);
  }
  __syncthreads();
  unsigned pivot16 = sh_pivot;

  const uint4* kv = (const uint4*)(keys + ((size_t)bc << ABITS) + chunk * (A / 4));
  int abase = chunk * (A / 4);
  for (int i = tid; i < A / 4 / 8; i += 256) {   // 1024 uint4s
    uint4 v = kv[i];
    unsigned w[4] = {v.x, v.y, v.z, v.w};
#pragma unroll
    for (int q = 0; q < 4; ++q) {
      unsigned lo = w[q] & 0xFFFFu, hi = w[q] >> 16;
      if (lo >= pivot16) {
        unsigned pos = atomicAdd(&lcnt, 1u);
        if (pos < (unsigned)CSEG) lbuf[pos] = abase + i * 8 + q * 2 + 0;
      }
      if (hi >= pivot16) {
        unsigned pos = atomicAdd(&lcnt, 1u);
        if (pos < (unsigned)CSEG) lbuf[pos] = abase + i * 8 + q * 2 + 1;
      }
    }
  }
  __syncthreads();
  unsigned n = lcnt < (unsigned)CSEG ? lcnt : (unsigned)CSEG;
  if (tid == 0) gcnt[blk] = n;
  int* seg = clist4 + (size_t)blk * CSEG;
  for (unsigned i = tid; i < n; i += 256) seg[i] = lbuf[i];
}

// f64 box decode for one anchor.
__device__ __forceinline__ void decode_d(const float* __restrict__ loc,
                                         const float* __restrict__ anchor,
                                         size_t ba, int a, double* o) {
  const float* lp = loc + ba * 4;
  const float* ap = anchor + (size_t)a * 4;
  double l0 = lp[0], l1 = lp[1], l2 = lp[2], l3 = lp[3];
  double cx = ap[0], cy = ap[1], aw = ap[2], ah = ap[3];
  double X = (l0 * 0.125) * aw + cx;
  double Y = (l1 * 0.125) * ah + cy;
  double bw = exp(l2 * 0.125) * aw;
  double bh = exp(l3 * 0.125) * ah;
  o[0] = X - bw * 0.5;
  o[1] = Y - bh * 0.5;
  o[2] = X + bw * 0.5;
  o[3] = Y + bh * 0.5;
}

// nms_kernel: one block per (b,c). Concatenate <=4 candidate segments (cap
// 512), exact f64 rescore, shfl bitonic sort, f64 decode, column-major
// upper-triangle IoU, register-resident greedy scan.
__global__ __launch_bounds__(512) void nms_kernel(
    const float* __restrict__ conf, const float* __restrict__ marr,
    const double* __restrict__ sarr, const float* __restrict__ loc,
    const float* __restrict__ anchor, const unsigned* __restrict__ gcnt,
    const int* __restrict__ clist4, float* __restrict__ out) {
  constexpr int NT = 512;
  __shared__ unsigned long long cand[512];
  __shared__ float4 cf4[K];             // f32 box (fast path)
  __shared__ float car[K];              // f32 area
  __shared__ double4 cd4[K];            // f64 box (guard path)
  __shared__ double dar[K];             // f64 area
  __shared__ unsigned cols[K * 8];      // column-major IoU bits: cols[j*8+w5]
  __shared__ unsigned kpw[8];           // keep bit words

  int tid = threadIdx.x;
  int bc = blockIdx.x;
  int b = bc / NC, c = bc % NC;
  size_t base = (size_t)b << ABITS;

  unsigned n0 = min(gcnt[bc * 4 + 0], (unsigned)CSEG);
  unsigned n1 = min(gcnt[bc * 4 + 1], (unsigned)CSEG);
  unsigned n2c = min(gcnt[bc * 4 + 2], (unsigned)CSEG);
  unsigned n3 = min(gcnt[bc * 4 + 3], (unsigned)CSEG);
  unsigned c0 = min(n0, 512u);
  unsigned c1 = min(n1, 512u - c0);
  unsigned c2 = min(n2c, 512u - c0 - c1);
  unsigned c3 = min(n3, 512u - c0 - c1 - c2);
  unsigned o1 = c0, o2 = c0 + c1, o3 = c0 + c1 + c2;
  unsigned ccount = o3 + c3;
  unsigned Ct = ccount < (unsigned)K ? ccount : (unsigned)K;

  // ---- 1. exact f64 scores for candidates; build sort keys ----
  for (int i = tid; i < 512; i += NT) {
    unsigned long long key = 0ull;
    if ((unsigned)i < ccount) {
      unsigned ui = (unsigned)i;
      int chunk, off;
      if (ui < o1) { chunk = 0; off = (int)ui; }
      else if (ui < o2) { chunk = 1; off = (int)(ui - o1); }
      else if (ui < o3) { chunk = 2; off = (int)(ui - o2); }
      else { chunk = 3; off = (int)(ui - o3); }
      int a = clist4[((size_t)bc * 4 + chunk) * CSEG + off];
      size_t ba = base + a;
      double sd = exp((double)conf[ba * NCP1 + (c + 1)] - (double)marr[ba]) / sarr[ba];
      if (sd >= TH_CONF) {
        unsigned long long db = (unsigned long long)__double_as_longlong(sd);
        key = (db & 0xFFFFFFFFFFFF0000ull) |
              (unsigned long long)(65535u - (unsigned)a);
      }
    }
    cand[i] = key;
  }
  __syncthreads();

  // ---- 2. bitonic sort desc (shfl for j<64): (score bits desc, idx asc) ----
  unsigned n2 = (ccount <= 256u) ? 256u : 512u;
  unsigned long long v = ((unsigned)tid < n2) ? cand[tid] : 0ull;
  for (unsigned k2 = 2; k2 <= n2; k2 <<= 1) {
    for (unsigned j = k2 >> 1; j > 0; j >>= 1) {
      unsigned long long p;
      if (j >= 64) {
        __syncthreads();
        if ((unsigned)tid < n2) cand[tid] = v;
        __syncthreads();
        p = ((unsigned)tid < n2) ? cand[tid ^ j] : 0ull;
      } else {
        p = __shfl_xor(v, (int)j, 64);
      }
      if ((unsigned)tid < n2) {
        bool desc = ((tid & (int)k2) == 0);
        bool lower = ((tid & (int)j) == 0);
        bool takemax = (lower == desc);
        bool vge = (v >= p);
        v = takemax ? (vge ? v : p) : (vge ? p : v);
      }
    }
  }
  __syncthreads();
  if ((unsigned)tid < n2) cand[tid] = v;
  __syncthreads();

  // ---- 3. decode candidate boxes (f64) + packed f32/f64 mirrors ----
  if ((unsigned)tid < Ct) {
    unsigned long long key = cand[tid];
    bool valid = (key >> 16) != 0ull;
    double o[4] = {0.0, 0.0, 0.0, 0.0};
    double aa = 0.0;
    if (valid) {
      unsigned a = (65535u - (unsigned)(key & 0xFFFFull)) & (A - 1);
      decode_d(loc, anchor, base + a, a, o);
      aa = (o[2] - o[0]) * (o[3] - o[1]);
    }
    cd4[tid] = make_double4(o[0], o[1], o[2], o[3]);
    dar[tid] = aa;
    cf4[tid] = make_float4((float)o[0], (float)o[1], (float)o[2], (float)o[3]);
    car[tid] = (float)aa;
  }
  __syncthreads();

  // ---- 4. IoU COLUMN words (upper triangle i<j only);
  //         f32 fast path, exact f64 guard when |margin| <= 1e-5 ----
  int Cti = (int)Ct;
  int total_jw = Cti * 7;
  for (int id = tid; id < total_jw; id += NT) {
    int j = id % Cti;
    int w5 = id / Cti;                  // 0..6
    int ilo = w5 * 32;
    unsigned bits = 0;
    if (ilo < j) {
      int ihi = (ilo + 32 < j) ? (ilo + 32) : j;
      float4 bj = cf4[j];
      float aj = car[j];
      for (int i = ilo; i < ihi; ++i) {
        float4 bi = cf4[i];
        float ltx = fmaxf(bi.x, bj.x);
        float lty = fmaxf(bi.y, bj.y);
        float rbx = fminf(bi.z, bj.z);
        float rby = fminf(bi.w, bj.w);
        float iw = fmaxf(rbx - ltx, 0.f);
        float ih = fmaxf(rby - lty, 0.f);
        float inter = iw * ih;
        float den = car[i] + aj - inter + 1e-9f;
        float dmar = inter - 0.5f * den;
        bool bit;
        if (fabsf(dmar) > 1e-5f) {
          bit = dmar > 0.f;
        } else {
          double4 Bi = cd4[i], Bj = cd4[j];
          double LTX = fmax(Bi.x, Bj.x);
          double LTY = fmax(Bi.y, Bj.y);
          double RBX = fmin(Bi.z, Bj.z);
          double RBY = fmin(Bi.w, Bj.w);
          double IW = fmax(RBX - LTX, 0.0);
          double IH = fmax(RBY - LTY, 0.0);
          double INTER = IW * IH;
          double DEN = dar[i] + dar[j] - INTER + 1e-9;
          bit = INTER > 0.5 * DEN;
        }
        if (bit) bits |= 1u << (i - ilo);
      }
    }
    cols[j * 8 + w5] = bits;
  }
  __syncthreads();

  // ---- 5. register-resident greedy scan (wave 0; matches lax.scan) ----
  if (tid < 64) {
    unsigned cb[4][7];                  // [slot][w5]; column j = slot*64 + tid
#pragma unroll
    for (int s = 0; s < 4; ++s) {
      int j = s * 64 + tid;
#pragma unroll
      for (int w5 = 0; w5 < 7; ++w5)
        cb[s][w5] = (j < Cti) ? cols[j * 8 + w5] : 0u;
    }
    unsigned sup[4] = {0u, 0u, 0u, 0u}; // suppressed flag per owned column
    unsigned kw[7] = {0u, 0u, 0u, 0u, 0u, 0u, 0u};
#pragma unroll
    for (int w5 = 0; w5 < 7; ++w5) {
      const int slot = w5 >> 1;
#pragma unroll
      for (int ii = 0; ii < 32; ++ii) {
        int i = w5 * 32 + ii;
        if (i < Cti) {
          int lane = (w5 & 1) * 32 + ii;            // = i & 63 (uniform)
          unsigned sflag = (unsigned)__builtin_amdgcn_readlane(
              (int)sup[slot], lane);
          unsigned km = (sflag == 0u) ? 0xFFFFFFFFu : 0u;
          kw[w5] |= (km & 1u) << ii;
#pragma unroll
          for (int s = 0; s < 4; ++s)
            sup[s] |= ((cb[s][w5] >> ii) & 1u) & km;
        }
      }
    }
    if (tid == 0) {
#pragma unroll
      for (int w5 = 0; w5 < 7; ++w5) kpw[w5] = kw[w5];
      kpw[7] = 0u;
    }
  }
  __syncthreads();

  // ---- 6. write objs + keep ----
  if (tid < K) {
    bool kkeep = ((unsigned)tid < Ct) &&
                 (((kpw[tid >> 5] >> (tid & 31)) & 1u) != 0u) &&
                 ((cand[tid] >> 16) != 0ull);
    float o0 = 0.f, o1v = 0.f, o2v = 0.f, o3v = 0.f, o4 = 0.f;
    if (kkeep) {
      double4 Bi = cd4[tid];
      o0 = (float)Bi.x; o1v = (float)Bi.y; o2v = (float)Bi.z; o3v = (float)Bi.w;
      double sd = __longlong_as_double(
          (long long)(cand[tid] & 0xFFFFFFFFFFFF0000ull));
      o4 = (float)sd;
    }
    size_t ob = ((size_t)bc * K + tid) * 5;
    out[ob + 0] = o0; out[ob + 1] = o1v; out[ob + 2] = o2v;
    out[ob + 3] = o3v; out[ob + 4] = o4;
    out[(size_t)B * NC * K * 5 + (size_t)bc * K + tid] = kkeep ? 1.f : 0.f;
  }
}

// ==================== FALLBACK: round-6 fused select (passing) ==============
__global__ __launch_bounds__(512) void select_fast(
    const float* __restrict__ conf, const float* __restrict__ marr,
    const double* __restrict__ sarr, const float* __restrict__ loc,
    const float* __restrict__ anchor, const unsigned short* __restrict__ keys,
    float* __restrict__ out) {
  constexpr int NT = 512;
  __shared__ unsigned hist[NBIN];
  __shared__ unsigned wtot[8], wsuf[8];
  __shared__ unsigned long long cand[512];
  __shared__ int clist[512];
  __shared__ double cbd5[K * 5];
  __shared__ unsigned rows[K * 8];
  __shared__ unsigned kp[K];
  __shared__ unsigned sh_cnt, sh_selbin, sh_total;

  int tid = threadIdx.x;
  unsigned lane = tid & 63, wid = tid >> 6;
  int bc = blockIdx.x;
  int b = bc / NC, c = bc % NC;
  size_t base = (size_t)b << ABITS;
  const unsigned short* krow = keys + ((size_t)bc << ABITS);
  const uint4* kv = (const uint4*)krow;

  if (tid == 0) sh_cnt = 0;

  for (int i = tid; i < NBIN; i += NT) hist[i] = 0;
  __syncthreads();
  for (int i = tid; i < A / 8; i += NT) {
    uint4 v = kv[i];
    unsigned w[4] = {v.x, v.y, v.z, v.w};
#pragma unroll
    for (int q = 0; q < 4; ++q) {
      unsigned lo = w[q] & 0xFFFFu, hi = w[q] >> 16;
      if (lo) atomicAdd(&hist[min(lo - KBASE, (unsigned)(NBIN - 1))], 1u);
      if (hi) atomicAdd(&hist[min(hi - KBASE, (unsigned)(NBIN - 1))], 1u);
    }
  }
  __syncthreads();
  unsigned h0 = 0, h1 = 0;
  if (tid < NBIN / 2) { h0 = hist[2 * tid]; h1 = hist[2 * tid + 1]; }

  unsigned s = h0 + h1;
  unsigned S = s;
#pragma unroll
  for (int d = 1; d < 64; d <<= 1) {
    unsigned o = __shfl_down(S, d, 64);
    if (lane + d < 64) S += o;
  }
  if (lane == 0) wtot[wid] = S;
  __syncthreads();
  if (tid < 8) {
    unsigned acc = 0;
    for (int w2 = tid + 1; w2 < 8; ++w2) acc += wtot[w2];
    wsuf[tid] = acc;
    if (tid == 0) sh_total = acc + wtot[0];
  }
  __syncthreads();
  unsigned Sfull = S + wsuf[wid];
  unsigned above2 = Sfull - s;
  unsigned cg1 = h1 + above2;
  unsigned cg0 = h0 + cg1;
  if (cg1 >= (unsigned)K && above2 < (unsigned)K) sh_selbin = tid * 2 + 1;
  if (cg0 >= (unsigned)K && cg1 < (unsigned)K) sh_selbin = tid * 2 + 0;
  __syncthreads();
  unsigned pivot16 = (sh_total <= (unsigned)K) ? KBASE : (KBASE + sh_selbin);

  for (int i = tid; i < A / 8; i += NT) {
    uint4 v = kv[i];
    unsigned w[4] = {v.x, v.y, v.z, v.w};
#pragma unroll
    for (int q = 0; q < 4; ++q) {
      unsigned lo = w[q] & 0xFFFFu, hi = w[q] >> 16;
      if (lo >= pivot16) {
        unsigned pos = atomicAdd(&sh_cnt, 1u);
        if (pos < 512) clist[pos] = i * 8 + q * 2 + 0;
      }
      if (hi >= pivot16) {
        unsigned pos = atomicAdd(&sh_cnt, 1u);
        if (pos < 512) clist[pos] = i * 8 + q * 2 + 1;
      }
    }
  }
  __syncthreads();
  unsigned ccount = sh_cnt < 512u ? sh_cnt : 512u;
  unsigned Ct = ccount < (unsigned)K ? ccount : (unsigned)K;

  for (int i = tid; i < 512; i += NT) {
    unsigned long long key = 0ull;
    if ((unsigned)i < ccount) {
      int a = clist[i];
      size_t ba = base + a;
      double sd = exp((double)conf[ba * NCP1 + (c + 1)] - (double)marr[ba]) / sarr[ba];
      if (sd >= TH_CONF) {
        unsigned long long db = (unsigned long long)__double_as_longlong(sd);
        key = (db & 0xFFFFFFFFFFFF0000ull) |
              (unsigned long long)(65535u - (unsigned)a);
      }
    }
    cand[i] = key;
  }
  __syncthreads();

  unsigned n2 = (ccount <= 256u) ? 256u : 512u;
  unsigned long long v = ((unsigned)tid < n2) ? cand[tid] : 0ull;
  for (unsigned k2 = 2; k2 <= n2; k2 <<= 1) {
    for (unsigned j = k2 >> 1; j > 0; j >>= 1) {
      unsigned long long p;
      if (j >= 64) {
        __syncthreads();
        if ((unsigned)tid < n2) cand[tid] = v;
        __syncthreads();
        p = ((unsigned)tid < n2) ? cand[tid ^ j] : 0ull;
      } else {
        p = __shfl_xor(v, (int)j, 64);
      }
      if ((unsigned)tid < n2) {
        bool desc = ((tid & (int)k2) == 0);
        bool lower = ((tid & (int)j) == 0);
        bool takemax = (lower == desc);
        bool vge = (v >= p);
        v = takemax ? (vge ? v : p) : (vge ? p : v);
      }
    }
  }
  __syncthreads();
  if ((unsigned)tid < n2) cand[tid] = v;
  __syncthreads();

  if ((unsigned)tid < Ct) {
    unsigned long long key = cand[tid];
    bool valid = (key >> 16) != 0ull;
    double o[4] = {0.0, 0.0, 0.0, 0.0};
    double aa = 0.0;
    if (valid) {
      unsigned a = (65535u - (unsigned)(key & 0xFFFFull)) & (A - 1);
      decode_d(loc, anchor, base + a, a, o);
      aa = (o[2] - o[0]) * (o[3] - o[1]);
    }
    cbd5[tid * 5 + 0] = o[0]; cbd5[tid * 5 + 1] = o[1];
    cbd5[tid * 5 + 2] = o[2]; cbd5[tid * 5 + 3] = o[3];
    cbd5[tid * 5 + 4] = aa;
  }
  __syncthreads();

  int total_iw = (int)Ct * 8;
  for (int id = tid; id < total_iw; id += NT) {
    int i = id % (int)Ct;
    int w = id / (int)Ct;
    double xi0 = cbd5[i * 5 + 0], yi0 = cbd5[i * 5 + 1];
    double xi1 = cbd5[i * 5 + 2], yi1 = cbd5[i * 5 + 3];
    double ai = cbd5[i * 5 + 4];
    unsigned bits = 0;
    int j0 = w * 32;
    for (int jj = 0; jj < 32; ++jj) {
      int j = j0 + jj;
      if (j < (int)Ct) {
        double ltx = fmax(xi0, cbd5[j * 5 + 0]);
        double lty = fmax(yi0, cbd5[j * 5 + 1]);
        double rbx = fmin(xi1, cbd5[j * 5 + 2]);
        double rby = fmin(yi1, cbd5[j * 5 + 3]);
        double iw = fmax(rbx - ltx, 0.0);
        double ih = fmax(rby - lty, 0.0);
        double inter = iw * ih;
        double den = ai + cbd5[j * 5 + 4] - inter + 1e-9;
        if (inter > 0.5 * den) bits |= (1u << jj);
      }
    }
    rows[i * 8 + w] = bits;
  }
  __syncthreads();

  if (tid < 64) {
    unsigned supp = 0;
    for (int i = 0; i < (int)Ct; ++i) {
      unsigned wsrc = __shfl(supp, i >> 5);
      bool kkeep = ((wsrc >> (i & 31)) & 1u) == 0u;
      if (tid == 0) kp[i] = kkeep ? 1u : 0u;
      unsigned rw = (tid < 8) ? rows[i * 8 + tid] : 0u;
      if (kkeep) supp |= rw;
    }
  }
  __syncthreads();

  if (tid < K) {
    bool kkeep = ((unsigned)tid < Ct) && (kp[tid] != 0u) && ((cand[tid] >> 16) != 0ull);
    float o0 = 0.f, o1 = 0.f, o2 = 0.f, o3 = 0.f, o4 = 0.f;
    if (kkeep) {
      o0 = (float)cbd5[tid * 5 + 0]; o1 = (float)cbd5[tid * 5 + 1];
      o2 = (float)cbd5[tid * 5 + 2]; o3 = (float)cbd5[tid * 5 + 3];
      double sd = __longlong_as_double(
          (long long)(cand[tid] & 0xFFFFFFFFFFFF0000ull));
      o4 = (float)sd;
    }
    size_t ob = ((size_t)bc * K + tid) * 5;
    out[ob + 0] = o0; out[ob + 1] = o1; out[ob + 2] = o2;
    out[ob + 3] = o3; out[ob + 4] = o4;
    out[(size_t)B * NC * K * 5 + (size_t)bc * K + tid] = kkeep ? 1.f : 0.f;
  }
}

// ============================ FALLBACK PATH (round-2, passing) ==============
__global__ __launch_bounds__(256) void prep_kernel(
    const float* __restrict__ conf, float* __restrict__ marr,
    double* __restrict__ sarr) {
  int idx = blockIdx.x * 256 + threadIdx.x;
  const float* cp = conf + (size_t)idx * NCP1;
  float x[NCP1];
#pragma unroll
  for (int i = 0; i < NCP1; ++i) x[i] = cp[i];
  float m = x[0];
#pragma unroll
  for (int i = 1; i < NCP1; ++i) m = fmaxf(m, x[i]);
  double S = 0.0;
#pragma unroll
  for (int i = 0; i < NCP1; ++i) S += exp((double)x[i] - (double)m);
  marr[idx] = m;
  sarr[idx] = S;
}

__device__ __forceinline__ double get_sd(const float* __restrict__ conf,
                                         const float* __restrict__ marr,
                                         const double* __restrict__ sarr,
                                         size_t ba, int c) {
  const float* cp = conf + ba * NCP1;
  float m;
  double S;
  if (sarr) {
    m = marr[ba];
    S = sarr[ba];
  } else {
    m = cp[0];
    for (int i = 1; i < NCP1; ++i) m = fmaxf(m, cp[i]);
    S = 0.0;
    for (int i = 0; i < NCP1; ++i) S += exp((double)cp[i] - (double)m);
  }
  return exp((double)cp[c + 1] - (double)m) / S;
}

__global__ __launch_bounds__(256) void select_nms_kernel(
    const float* __restrict__ conf, const float* __restrict__ marr,
    const double* __restrict__ sarr, const float* __restrict__ loc,
    const float* __restrict__ anchor, float* __restrict__ out) {
  __shared__ __align__(16) unsigned short s16[A];
  __shared__ unsigned hist[256];
  __shared__ unsigned scan0[256];
  __shared__ unsigned long long cand[512];
  __shared__ unsigned sh_cnt, sh_selbin, sh_need, sh_ctot;

  double* cbd = (double*)s16;
  double* ar = cbd + K * 4;
  unsigned* rows = (unsigned*)(ar + K);
  unsigned* kp = rows + K * 8;

  int tid = threadIdx.x;
  int bc = blockIdx.x;
  int b = bc / NC, c = bc % NC;
  size_t base = (size_t)b << ABITS;

  for (int a = tid; a < A; a += 256) {
    double sd = get_sd(conf, marr, sarr, base + a, c);
    unsigned short key = 0;
    if (sd >= TH_CONF) {
      float f = (float)sd;
      key = (unsigned short)(__float_as_uint(f) >> 16);
    }
    s16[a] = key;
  }
  __syncthreads();

  unsigned need = K, pfx = 0;
  bool smallcase = false;
  for (int p = 0; p < 2; ++p) {
    hist[tid] = 0;
    __syncthreads();
    for (int a = tid; a < A; a += 256) {
      unsigned v = s16[a];
      if (v && (p == 0 || (v >> 8) == pfx))
        atomicAdd(&hist[(p == 0) ? (v >> 8) : (v & 0xFFu)], 1u);
    }
    __syncthreads();
    scan0[tid] = hist[tid];
    __syncthreads();
    for (int st = 1; st < 256; st <<= 1) {
      unsigned mine = scan0[tid];
      unsigned oth = (tid + st < 256) ? scan0[tid + st] : 0u;
      __syncthreads();
      scan0[tid] = mine + oth;
      __syncthreads();
    }
    if (p == 0) {
      if (tid == 0) sh_ctot = scan0[0];
      __syncthreads();
      if (sh_ctot <= (unsigned)K) { smallcase = true; break; }
    }
    unsigned nxt = (tid == 255) ? 0u : scan0[tid + 1];
    if (scan0[tid] >= need && nxt < need) { sh_selbin = tid; sh_need = need - nxt; }
    __syncthreads();
    pfx = (pfx << 8) | sh_selbin;
    need = sh_need;
    __syncthreads();
  }
  unsigned pivot16 = smallcase ? 0x3D4Cu : pfx;

  if (tid == 0) sh_cnt = 0;
  __syncthreads();
  for (int a = tid; a < A; a += 256) {
    double sd = get_sd(conf, marr, sarr, base + a, c);
    if (sd >= TH_CONF) {
      float f = (float)sd;
      if ((__float_as_uint(f) >> 16) >= pivot16) {
        unsigned pos = atomicAdd(&sh_cnt, 1u);
        if (pos < 512) {
          unsigned long long db = (unsigned long long)__double_as_longlong(sd);
          cand[pos] = (db & 0xFFFFFFFFFFFF0000ull) |
                      (unsigned long long)(65535u - (unsigned)a);
        }
      }
    }
  }
  __syncthreads();
  unsigned ccount = sh_cnt < 512u ? sh_cnt : 512u;
  unsigned Ct = ccount < (unsigned)K ? ccount : (unsigned)K;
  for (int i = tid; i < 512; i += 256)
    if ((unsigned)i >= ccount) cand[i] = 0ull;
  __syncthreads();

  for (unsigned k2 = 2; k2 <= 512; k2 <<= 1) {
    for (unsigned j = k2 >> 1; j > 0; j >>= 1) {
      for (unsigned i = tid; i < 512; i += 256) {
        unsigned ixj = i ^ j;
        if (ixj > i) {
          unsigned long long va = cand[i], vb = cand[ixj];
          bool desc = ((i & k2) == 0);
          if (desc ? (va < vb) : (va > vb)) { cand[i] = vb; cand[ixj] = va; }
        }
      }
      __syncthreads();
    }
  }

  if ((unsigned)tid < Ct) {
    unsigned a = 65535u - (unsigned)(cand[tid] & 0xFFFFull);
    double o[4];
    decode_d(loc, anchor, base + a, a, o);
    cbd[tid * 4 + 0] = o[0]; cbd[tid * 4 + 1] = o[1];
    cbd[tid * 4 + 2] = o[2]; cbd[tid * 4 + 3] = o[3];
    ar[tid] = (o[2] - o[0]) * (o[3] - o[1]);
  }
  __syncthreads();

  for (int id = tid; id < (int)Ct * 8; id += 256) {
    int i = id >> 3, w = id & 7;
    double xi0 = cbd[i * 4 + 0], yi0 = cbd[i * 4 + 1];
    double xi1 = cbd[i * 4 + 2], yi1 = cbd[i * 4 + 3];
    double ai = ar[i];
    unsigned bits = 0;
    int j0 = w * 32;
    for (int jj = 0; jj < 32; ++jj) {
      int j = j0 + jj;
      if (j < (int)Ct) {
        double ltx = fmax(xi0, cbd[j * 4 + 0]);
        double lty = fmax(yi0, cbd[j * 4 + 1]);
        double rbx = fmin(xi1, cbd[j * 4 + 2]);
        double rby = fmin(yi1, cbd[j * 4 + 3]);
        double iw = fmax(rbx - ltx, 0.0);
        double ih = fmax(rby - lty, 0.0);
        double inter = iw * ih;
        double iou = inter / (ai + ar[j] - inter + 1e-9);
        if (iou > TH_IOU) bits |= (1u << jj);
      }
    }
    rows[i * 8 + w] = bits;
  }
  __syncthreads();

  if (tid < 64) {
    unsigned supp = 0;
    for (int i = 0; i < (int)Ct; ++i) {
      unsigned wsrc = __shfl(supp, i >> 5);
      bool kkeep = ((wsrc >> (i & 31)) & 1u) == 0u;
      if (tid == 0) kp[i] = kkeep ? 1u : 0u;
      unsigned rw = (tid < 8) ? rows[i * 8 + tid] : 0u;
      if (kkeep) supp |= rw;
    }
  }
  __syncthreads();

  if (tid < K) {
    bool kkeep = ((unsigned)tid < Ct) && (kp[tid] != 0u);
    float o0 = 0.f, o1 = 0.f, o2 = 0.f, o3 = 0.f, o4 = 0.f;
    if (kkeep) {
      o0 = (float)cbd[tid * 4 + 0]; o1 = (float)cbd[tid * 4 + 1];
      o2 = (float)cbd[tid * 4 + 2]; o3 = (float)cbd[tid * 4 + 3];
      double sd = __longlong_as_double(
          (long long)(cand[tid] & 0xFFFFFFFFFFFF0000ull));
      o4 = (float)sd;
    }
    size_t ob = ((size_t)bc * K + tid) * 5;
    out[ob + 0] = o0; out[ob + 1] = o1; out[ob + 2] = o2;
    out[ob + 3] = o3; out[ob + 4] = o4;
    out[(size_t)B * NC * K * 5 + (size_t)bc * K + tid] = kkeep ? 1.f : 0.f;
  }
}

extern "C" void kernel_launch(void* const* d_in, const int* in_sizes, int n_in,
                              void* d_out, int out_size, void* d_ws, size_t ws_size,
                              hipStream_t stream) {
  (void)in_sizes; (void)n_in; (void)out_size;
  const float* conf = (const float*)d_in[0];
  const float* loc = (const float*)d_in[1];
  const float* anchor = (const float*)d_in[2];
  float* out = (float*)d_out;

  size_t nBA = (size_t)B * A;
  size_t off_sarr = 0;
  size_t off_marr = off_sarr + nBA * sizeof(double);
  size_t off_keys = off_marr + nBA * sizeof(float);
  size_t off_ghist4 = off_keys + nBA * NC * sizeof(unsigned short);
  size_t ghist4_bytes = (size_t)B * NC * 4 * NBIN * sizeof(unsigned);
  size_t off_gcnt = off_ghist4 + ghist4_bytes;
  size_t gcnt_bytes = (size_t)B * NC * 4 * sizeof(unsigned);
  size_t off_clist4 = off_gcnt + gcnt_bytes;
  size_t clist4_bytes = (size_t)B * NC * 4 * CSEG * sizeof(int);
  size_t need_v11 = off_clist4 + clist4_bytes;      // ~66 MB
  size_t need_fast = off_ghist4;                    // ~54.5 MB (fused tier)
  size_t need_mid = nBA * (sizeof(float) + sizeof(double));  // 12 MB

  if (ws_size >= need_v11) {
    double* sarr = (double*)((char*)d_ws + off_sarr);
    float* marr = (float*)((char*)d_ws + off_marr);
    unsigned short* keys = (unsigned short*)((char*)d_ws + off_keys);
    unsigned* ghist4 = (unsigned*)((char*)d_ws + off_ghist4);
    unsigned* gcnt = (unsigned*)((char*)d_ws + off_gcnt);
    int* clist4 = (int*)((char*)d_ws + off_clist4);
    prep_fast<<<(B * A) / 256, 256, 0, stream>>>(conf, marr, sarr, keys);
    prehist_kernel<<<B * NC * 4, 256, 0, stream>>>(keys, ghist4);
    collect_kernel<<<B * NC * 4, 256, 0, stream>>>(keys, ghist4, gcnt, clist4);
    nms_kernel<<<B * NC, 512, 0, stream>>>(conf, marr, sarr, loc, anchor,
                                           gcnt, clist4, out);
  } else if (ws_size >= need_fast) {
    double* sarr = (double*)((char*)d_ws + off_sarr);
    float* marr = (float*)((char*)d_ws + off_marr);
    unsigned short* keys = (unsigned short*)((char*)d_ws + off_keys);
    prep_fast<<<(B * A) / 256, 256, 0, stream>>>(conf, marr, sarr, keys);
    select_fast<<<B * NC, 512, 0, stream>>>(conf, marr, sarr, loc, anchor,
                                            keys, out);
  } else if (ws_size >= need_mid) {
    float* marr = (float*)d_ws;
    double* sarr = (double*)((char*)d_ws + nBA * sizeof(float));
    prep_kernel<<<(B * A) / 256, 256, 0, stream>>>(conf, marr, sarr);
    select_nms_kernel<<<B * NC, 256, 0, stream>>>(conf, marr, sarr, loc, anchor, out);
  } else {
    select_nms_kernel<<<B * NC, 256, 0, stream>>>(conf, nullptr, nullptr, loc, anchor, out);
  }
}

// Round 12
// 85.697 us; speedup vs baseline: 2.2819x; 1.1341x over previous
//
#include <hip/hip_runtime.h>

// DetectPostProcess: softmax -> decode -> per-(b,c) top-200 -> greedy NMS.
// Decisions (ordering, top-K membership, IoU>0.5) identical to rounds 2..11
// (f64 everywhere it matters; f32 IoU fast path guarded by exact f64
// recompute within |margin|<=1e-5).
// Round 12: selection pipeline re-fused into ONE kernel (prehist/collect/nms
// were paying 2 launch gaps + ghist4/clist4 HBM round-trips purely as
// inter-kernel plumbing). Each phase is the proven implementation:
// r5 in-kernel histogram, r6 shfl pivot, r6 LDS collect, r10 shfl bitonic,
// r10/r11 upper-triangle column IoU + register-resident readlane scan.
// Outputs: objs [B,NC,K,5] then keep [B,NC,K] (as 0.0/1.0), flat in d_out.

constexpr int B = 32;
constexpr int A = 32768;     // power of two
constexpr int ABITS = 15;    // log2(A)
constexpr int NCP1 = 21;
constexpr int NC = 20;
constexpr int K = 200;
constexpr int NBIN = 576;    // key range 0x3D4C..0x3F80 = 564 values
#define KBASE 0x3D4Cu        // bits(0.05f) >> 16; min nonzero key

#define TH_CONF 0.05
#define TH_IOU  0.5

// ============================ FAST PATH =====================================
// prep_fast: per (b,a): m (f32 max), S (f64 sum), and 20 transposed u16 keys.
__global__ __launch_bounds__(256) void prep_fast(
    const float* __restrict__ conf, float* __restrict__ marr,
    double* __restrict__ sarr, unsigned short* __restrict__ keys) {
  int idx = blockIdx.x * 256 + threadIdx.x;   // 0 .. B*A-1
  int b = idx >> ABITS;
  int a = idx & (A - 1);
  const float* cp = conf + (size_t)idx * NCP1;
  float x[NCP1];
#pragma unroll
  for (int i = 0; i < NCP1; ++i) x[i] = cp[i];
  float m = x[0];
#pragma unroll
  for (int i = 1; i < NCP1; ++i) m = fmaxf(m, x[i]);
  double e[NCP1];
  double S = 0.0;
#pragma unroll
  for (int i = 0; i < NCP1; ++i) {
    e[i] = exp((double)x[i] - (double)m);
    S += e[i];
  }
  marr[idx] = m;
  sarr[idx] = S;
  double rs = 1.0 / S;
  size_t kbase = ((size_t)(b * NC) << ABITS) + a;
#pragma unroll
  for (int c = 0; c < NC; ++c) {
    double sd = e[c + 1] * rs;                 // ~1ulp from e/S; key-grade only
    unsigned short key = 0;
    if (sd >= TH_CONF) {
      float f = (float)sd;
      key = (unsigned short)(__float_as_uint(f) >> 16);
    }
    keys[kbase + ((size_t)c << ABITS)] = key;
  }
}

// f64 box decode for one anchor.
__device__ __forceinline__ void decode_d(const float* __restrict__ loc,
                                         const float* __restrict__ anchor,
                                         size_t ba, int a, double* o) {
  const float* lp = loc + ba * 4;
  const float* ap = anchor + (size_t)a * 4;
  double l0 = lp[0], l1 = lp[1], l2 = lp[2], l3 = lp[3];
  double cx = ap[0], cy = ap[1], aw = ap[2], ah = ap[3];
  double X = (l0 * 0.125) * aw + cx;
  double Y = (l1 * 0.125) * ah + cy;
  double bw = exp(l2 * 0.125) * aw;
  double bh = exp(l3 * 0.125) * ah;
  o[0] = X - bw * 0.5;
  o[1] = Y - bh * 0.5;
  o[2] = X + bw * 0.5;
  o[3] = Y + bh * 0.5;
}

// select2: one block per (b,c). Full fused selection + NMS.
__global__ __launch_bounds__(512) void select2_kernel(
    const float* __restrict__ conf, const float* __restrict__ marr,
    const double* __restrict__ sarr, const float* __restrict__ loc,
    const float* __restrict__ anchor, const unsigned short* __restrict__ keys,
    float* __restrict__ out) {
  constexpr int NT = 512;
  __shared__ unsigned hist[NBIN];
  __shared__ unsigned wtot[8], wsuf[8];
  __shared__ unsigned long long cand[512];
  __shared__ int clist[512];
  __shared__ float4 cf4[K];             // f32 box (fast path)
  __shared__ float car[K];              // f32 area
  __shared__ double4 cd4[K];            // f64 box (guard path)
  __shared__ double dar[K];             // f64 area
  __shared__ unsigned cols[K * 8];      // column-major IoU bits: cols[j*8+w5]
  __shared__ unsigned kpw[8];           // keep bit words
  __shared__ unsigned sh_cnt, sh_selbin, sh_total;

  int tid = threadIdx.x;
  unsigned lane = tid & 63, wid = tid >> 6;
  int bc = blockIdx.x;
  int b = bc / NC, c = bc % NC;
  size_t base = (size_t)b << ABITS;
  const uint4* kv = (const uint4*)(keys + ((size_t)bc << ABITS));

  if (tid == 0) sh_cnt = 0;

  // ---- 1. in-kernel 576-bin histogram over the key row ----
  for (int i = tid; i < NBIN; i += NT) hist[i] = 0;
  __syncthreads();
  for (int i = tid; i < A / 8; i += NT) {
    uint4 v = kv[i];
    unsigned w[4] = {v.x, v.y, v.z, v.w};
#pragma unroll
    for (int q = 0; q < 4; ++q) {
      unsigned lo = w[q] & 0xFFFFu, hi = w[q] >> 16;
      if (lo) atomicAdd(&hist[min(lo - KBASE, (unsigned)(NBIN - 1))], 1u);
      if (hi) atomicAdd(&hist[min(hi - KBASE, (unsigned)(NBIN - 1))], 1u);
    }
  }
  __syncthreads();

  // ---- 2. shfl suffix scan (cnt_ge) + exact 16-bit pivot ----
  unsigned h0 = 0, h1 = 0;
  if (tid < NBIN / 2) { h0 = hist[2 * tid]; h1 = hist[2 * tid + 1]; }
  unsigned s = h0 + h1;
  unsigned S = s;
#pragma unroll
  for (int d = 1; d < 64; d <<= 1) {
    unsigned o = __shfl_down(S, d, 64);
    if (lane + d < 64) S += o;
  }
  if (lane == 0) wtot[wid] = S;
  __syncthreads();
  if (tid < 8) {
    unsigned acc = 0;
    for (int w2 = tid + 1; w2 < 8; ++w2) acc += wtot[w2];
    wsuf[tid] = acc;
    if (tid == 0) sh_total = acc + wtot[0];
  }
  __syncthreads();
  unsigned Sfull = S + wsuf[wid];
  unsigned above2 = Sfull - s;
  unsigned cg1 = h1 + above2;
  unsigned cg0 = h0 + cg1;
  if (cg1 >= (unsigned)K && above2 < (unsigned)K) sh_selbin = tid * 2 + 1;
  if (cg0 >= (unsigned)K && cg1 < (unsigned)K) sh_selbin = tid * 2 + 0;
  __syncthreads();
  unsigned pivot16 = (sh_total <= (unsigned)K) ? KBASE : (KBASE + sh_selbin);

  // ---- 3. collect candidate anchor ids into LDS (superset of top-K) ----
  for (int i = tid; i < A / 8; i += NT) {
    uint4 v = kv[i];
    unsigned w[4] = {v.x, v.y, v.z, v.w};
#pragma unroll
    for (int q = 0; q < 4; ++q) {
      unsigned lo = w[q] & 0xFFFFu, hi = w[q] >> 16;
      if (lo >= pivot16) {
        unsigned pos = atomicAdd(&sh_cnt, 1u);
        if (pos < 512) clist[pos] = i * 8 + q * 2 + 0;
      }
      if (hi >= pivot16) {
        unsigned pos = atomicAdd(&sh_cnt, 1u);
        if (pos < 512) clist[pos] = i * 8 + q * 2 + 1;
      }
    }
  }
  __syncthreads();
  unsigned ccount = sh_cnt < 512u ? sh_cnt : 512u;
  unsigned Ct = ccount < (unsigned)K ? ccount : (unsigned)K;

  // ---- 4. exact f64 scores for candidates; build sort keys ----
  for (int i = tid; i < 512; i += NT) {
    unsigned long long key = 0ull;
    if ((unsigned)i < ccount) {
      int a = clist[i];
      size_t ba = base + a;
      double sd = exp((double)conf[ba * NCP1 + (c + 1)] - (double)marr[ba]) / sarr[ba];
      if (sd >= TH_CONF) {
        unsigned long long db = (unsigned long long)__double_as_longlong(sd);
        key = (db & 0xFFFFFFFFFFFF0000ull) |
              (unsigned long long)(65535u - (unsigned)a);
      }
    }
    cand[i] = key;
  }
  __syncthreads();

  // ---- 5. bitonic sort desc (shfl for j<64): (score bits desc, idx asc) ----
  unsigned n2 = (ccount <= 256u) ? 256u : 512u;
  unsigned long long v = ((unsigned)tid < n2) ? cand[tid] : 0ull;
  for (unsigned k2 = 2; k2 <= n2; k2 <<= 1) {
    for (unsigned j = k2 >> 1; j > 0; j >>= 1) {
      unsigned long long p;
      if (j >= 64) {
        __syncthreads();
        if ((unsigned)tid < n2) cand[tid] = v;
        __syncthreads();
        p = ((unsigned)tid < n2) ? cand[tid ^ j] : 0ull;
      } else {
        p = __shfl_xor(v, (int)j, 64);
      }
      if ((unsigned)tid < n2) {
        bool desc = ((tid & (int)k2) == 0);
        bool lower = ((tid & (int)j) == 0);
        bool takemax = (lower == desc);
        bool vge = (v >= p);
        v = takemax ? (vge ? v : p) : (vge ? p : v);
      }
    }
  }
  __syncthreads();
  if ((unsigned)tid < n2) cand[tid] = v;
  __syncthreads();

  // ---- 6. decode candidate boxes (f64) + packed f32/f64 mirrors ----
  if ((unsigned)tid < Ct) {
    unsigned long long key = cand[tid];
    bool valid = (key >> 16) != 0ull;
    double o[4] = {0.0, 0.0, 0.0, 0.0};
    double aa = 0.0;
    if (valid) {
      unsigned a = (65535u - (unsigned)(key & 0xFFFFull)) & (A - 1);
      decode_d(loc, anchor, base + a, a, o);
      aa = (o[2] - o[0]) * (o[3] - o[1]);
    }
    cd4[tid] = make_double4(o[0], o[1], o[2], o[3]);
    dar[tid] = aa;
    cf4[tid] = make_float4((float)o[0], (float)o[1], (float)o[2], (float)o[3]);
    car[tid] = (float)aa;
  }
  __syncthreads();

  // ---- 7. IoU COLUMN words (upper triangle i<j only);
  //         f32 fast path, exact f64 guard when |margin| <= 1e-5 ----
  int Cti = (int)Ct;
  int total_jw = Cti * 7;
  for (int id = tid; id < total_jw; id += NT) {
    int j = id % Cti;
    int w5 = id / Cti;                  // 0..6
    int ilo = w5 * 32;
    unsigned bits = 0;
    if (ilo < j) {
      int ihi = (ilo + 32 < j) ? (ilo + 32) : j;
      float4 bj = cf4[j];
      float aj = car[j];
      for (int i = ilo; i < ihi; ++i) {
        float4 bi = cf4[i];
        float ltx = fmaxf(bi.x, bj.x);
        float lty = fmaxf(bi.y, bj.y);
        float rbx = fminf(bi.z, bj.z);
        float rby = fminf(bi.w, bj.w);
        float iw = fmaxf(rbx - ltx, 0.f);
        float ih = fmaxf(rby - lty, 0.f);
        float inter = iw * ih;
        float den = car[i] + aj - inter + 1e-9f;
        float dmar = inter - 0.5f * den;
        bool bit;
        if (fabsf(dmar) > 1e-5f) {
          bit = dmar > 0.f;
        } else {
          double4 Bi = cd4[i], Bj = cd4[j];
          double LTX = fmax(Bi.x, Bj.x);
          double LTY = fmax(Bi.y, Bj.y);
          double RBX = fmin(Bi.z, Bj.z);
          double RBY = fmin(Bi.w, Bj.w);
          double IW = fmax(RBX - LTX, 0.0);
          double IH = fmax(RBY - LTY, 0.0);
          double INTER = IW * IH;
          double DEN = dar[i] + dar[j] - INTER + 1e-9;
          bit = INTER > 0.5 * DEN;
        }
        if (bit) bits |= 1u << (i - ilo);
      }
    }
    cols[j * 8 + w5] = bits;
  }
  __syncthreads();

  // ---- 8. register-resident greedy scan (wave 0; matches lax.scan) ----
  if (tid < 64) {
    unsigned cb[4][7];                  // [slot][w5]; column j = slot*64 + tid
#pragma unroll
    for (int s2 = 0; s2 < 4; ++s2) {
      int j = s2 * 64 + tid;
#pragma unroll
      for (int w5 = 0; w5 < 7; ++w5)
        cb[s2][w5] = (j < Cti) ? cols[j * 8 + w5] : 0u;
    }
    unsigned sup[4] = {0u, 0u, 0u, 0u}; // suppressed flag per owned column
    unsigned kw[7] = {0u, 0u, 0u, 0u, 0u, 0u, 0u};
#pragma unroll
    for (int w5 = 0; w5 < 7; ++w5) {
      const int slot = w5 >> 1;
#pragma unroll
      for (int ii = 0; ii < 32; ++ii) {
        int i = w5 * 32 + ii;
        if (i < Cti) {
          int lane2 = (w5 & 1) * 32 + ii;           // = i & 63 (uniform)
          unsigned sflag = (unsigned)__builtin_amdgcn_readlane(
              (int)sup[slot], lane2);
          unsigned km = (sflag == 0u) ? 0xFFFFFFFFu : 0u;
          kw[w5] |= (km & 1u) << ii;
#pragma unroll
          for (int s2 = 0; s2 < 4; ++s2)
            sup[s2] |= ((cb[s2][w5] >> ii) & 1u) & km;
        }
      }
    }
    if (tid == 0) {
#pragma unroll
      for (int w5 = 0; w5 < 7; ++w5) kpw[w5] = kw[w5];
      kpw[7] = 0u;
    }
  }
  __syncthreads();

  // ---- 9. write objs + keep ----
  if (tid < K) {
    bool kkeep = ((unsigned)tid < Ct) &&
                 (((kpw[tid >> 5] >> (tid & 31)) & 1u) != 0u) &&
                 ((cand[tid] >> 16) != 0ull);
    float o0 = 0.f, o1v = 0.f, o2v = 0.f, o3v = 0.f, o4 = 0.f;
    if (kkeep) {
      double4 Bi = cd4[tid];
      o0 = (float)Bi.x; o1v = (float)Bi.y; o2v = (float)Bi.z; o3v = (float)Bi.w;
      double sd = __longlong_as_double(
          (long long)(cand[tid] & 0xFFFFFFFFFFFF0000ull));
      o4 = (float)sd;
    }
    size_t ob = ((size_t)bc * K + tid) * 5;
    out[ob + 0] = o0; out[ob + 1] = o1v; out[ob + 2] = o2v;
    out[ob + 3] = o3v; out[ob + 4] = o4;
    out[(size_t)B * NC * K * 5 + (size_t)bc * K + tid] = kkeep ? 1.f : 0.f;
  }
}

// ============================ FALLBACK PATH (round-2, passing) ==============
__global__ __launch_bounds__(256) void prep_kernel(
    const float* __restrict__ conf, float* __restrict__ marr,
    double* __restrict__ sarr) {
  int idx = blockIdx.x * 256 + threadIdx.x;
  const float* cp = conf + (size_t)idx * NCP1;
  float x[NCP1];
#pragma unroll
  for (int i = 0; i < NCP1; ++i) x[i] = cp[i];
  float m = x[0];
#pragma unroll
  for (int i = 1; i < NCP1; ++i) m = fmaxf(m, x[i]);
  double S = 0.0;
#pragma unroll
  for (int i = 0; i < NCP1; ++i) S += exp((double)x[i] - (double)m);
  marr[idx] = m;
  sarr[idx] = S;
}

__device__ __forceinline__ double get_sd(const float* __restrict__ conf,
                                         const float* __restrict__ marr,
                                         const double* __restrict__ sarr,
                                         size_t ba, int c) {
  const float* cp = conf + ba * NCP1;
  float m;
  double S;
  if (sarr) {
    m = marr[ba];
    S = sarr[ba];
  } else {
    m = cp[0];
    for (int i = 1; i < NCP1; ++i) m = fmaxf(m, cp[i]);
    S = 0.0;
    for (int i = 0; i < NCP1; ++i) S += exp((double)cp[i] - (double)m);
  }
  return exp((double)cp[c + 1] - (double)m) / S;
}

__global__ __launch_bounds__(256) void select_nms_kernel(
    const float* __restrict__ conf, const float* __restrict__ marr,
    const double* __restrict__ sarr, const float* __restrict__ loc,
    const float* __restrict__ anchor, float* __restrict__ out) {
  __shared__ __align__(16) unsigned short s16[A];
  __shared__ unsigned hist[256];
  __shared__ unsigned scan0[256];
  __shared__ unsigned long long cand[512];
  __shared__ unsigned sh_cnt, sh_selbin, sh_need, sh_ctot;

  double* cbd = (double*)s16;
  double* ar = cbd + K * 4;
  unsigned* rows = (unsigned*)(ar + K);
  unsigned* kp = rows + K * 8;

  int tid = threadIdx.x;
  int bc = blockIdx.x;
  int b = bc / NC, c = bc % NC;
  size_t base = (size_t)b << ABITS;

  for (int a = tid; a < A; a += 256) {
    double sd = get_sd(conf, marr, sarr, base + a, c);
    unsigned short key = 0;
    if (sd >= TH_CONF) {
      float f = (float)sd;
      key = (unsigned short)(__float_as_uint(f) >> 16);
    }
    s16[a] = key;
  }
  __syncthreads();

  unsigned need = K, pfx = 0;
  bool smallcase = false;
  for (int p = 0; p < 2; ++p) {
    hist[tid] = 0;
    __syncthreads();
    for (int a = tid; a < A; a += 256) {
      unsigned v = s16[a];
      if (v && (p == 0 || (v >> 8) == pfx))
        atomicAdd(&hist[(p == 0) ? (v >> 8) : (v & 0xFFu)], 1u);
    }
    __syncthreads();
    scan0[tid] = hist[tid];
    __syncthreads();
    for (int st = 1; st < 256; st <<= 1) {
      unsigned mine = scan0[tid];
      unsigned oth = (tid + st < 256) ? scan0[tid + st] : 0u;
      __syncthreads();
      scan0[tid] = mine + oth;
      __syncthreads();
    }
    if (p == 0) {
      if (tid == 0) sh_ctot = scan0[0];
      __syncthreads();
      if (sh_ctot <= (unsigned)K) { smallcase = true; break; }
    }
    unsigned nxt = (tid == 255) ? 0u : scan0[tid + 1];
    if (scan0[tid] >= need && nxt < need) { sh_selbin = tid; sh_need = need - nxt; }
    __syncthreads();
    pfx = (pfx << 8) | sh_selbin;
    need = sh_need;
    __syncthreads();
  }
  unsigned pivot16 = smallcase ? 0x3D4Cu : pfx;

  if (tid == 0) sh_cnt = 0;
  __syncthreads();
  for (int a = tid; a < A; a += 256) {
    double sd = get_sd(conf, marr, sarr, base + a, c);
    if (sd >= TH_CONF) {
      float f = (float)sd;
      if ((__float_as_uint(f) >> 16) >= pivot16) {
        unsigned pos = atomicAdd(&sh_cnt, 1u);
        if (pos < 512) {
          unsigned long long db = (unsigned long long)__double_as_longlong(sd);
          cand[pos] = (db & 0xFFFFFFFFFFFF0000ull) |
                      (unsigned long long)(65535u - (unsigned)a);
        }
      }
    }
  }
  __syncthreads();
  unsigned ccount = sh_cnt < 512u ? sh_cnt : 512u;
  unsigned Ct = ccount < (unsigned)K ? ccount : (unsigned)K;
  for (int i = tid; i < 512; i += 256)
    if ((unsigned)i >= ccount) cand[i] = 0ull;
  __syncthreads();

  for (unsigned k2 = 2; k2 <= 512; k2 <<= 1) {
    for (unsigned j = k2 >> 1; j > 0; j >>= 1) {
      for (unsigned i = tid; i < 512; i += 256) {
        unsigned ixj = i ^ j;
        if (ixj > i) {
          unsigned long long va = cand[i], vb = cand[ixj];
          bool desc = ((i & k2) == 0);
          if (desc ? (va < vb) : (va > vb)) { cand[i] = vb; cand[ixj] = va; }
        }
      }
      __syncthreads();
    }
  }

  if ((unsigned)tid < Ct) {
    unsigned a = 65535u - (unsigned)(cand[tid] & 0xFFFFull);
    double o[4];
    decode_d(loc, anchor, base + a, a, o);
    cbd[tid * 4 + 0] = o[0]; cbd[tid * 4 + 1] = o[1];
    cbd[tid * 4 + 2] = o[2]; cbd[tid * 4 + 3] = o[3];
    ar[tid] = (o[2] - o[0]) * (o[3] - o[1]);
  }
  __syncthreads();

  for (int id = tid; id < (int)Ct * 8; id += 256) {
    int i = id >> 3, w = id & 7;
    double xi0 = cbd[i * 4 + 0], yi0 = cbd[i * 4 + 1];
    double xi1 = cbd[i * 4 + 2], yi1 = cbd[i * 4 + 3];
    double ai = ar[i];
    unsigned bits = 0;
    int j0 = w * 32;
    for (int jj = 0; jj < 32; ++jj) {
      int j = j0 + jj;
      if (j < (int)Ct) {
        double ltx = fmax(xi0, cbd[j * 4 + 0]);
        double lty = fmax(yi0, cbd[j * 4 + 1]);
        double rbx = fmin(xi1, cbd[j * 4 + 2]);
        double rby = fmin(yi1, cbd[j * 4 + 3]);
        double iw = fmax(rbx - ltx, 0.0);
        double ih = fmax(rby - lty, 0.0);
        double inter = iw * ih;
        double iou = inter / (ai + ar[j] - inter + 1e-9);
        if (iou > TH_IOU) bits |= (1u << jj);
      }
    }
    rows[i * 8 + w] = bits;
  }
  __syncthreads();

  if (tid < 64) {
    unsigned supp = 0;
    for (int i = 0; i < (int)Ct; ++i) {
      unsigned wsrc = __shfl(supp, i >> 5);
      bool kkeep = ((wsrc >> (i & 31)) & 1u) == 0u;
      if (tid == 0) kp[i] = kkeep ? 1u : 0u;
      unsigned rw = (tid < 8) ? rows[i * 8 + tid] : 0u;
      if (kkeep) supp |= rw;
    }
  }
  __syncthreads();

  if (tid < K) {
    bool kkeep = ((unsigned)tid < Ct) && (kp[tid] != 0u);
    float o0 = 0.f, o1 = 0.f, o2 = 0.f, o3 = 0.f, o4 = 0.f;
    if (kkeep) {
      o0 = (float)cbd[tid * 4 + 0]; o1 = (float)cbd[tid * 4 + 1];
      o2 = (float)cbd[tid * 4 + 2]; o3 = (float)cbd[tid * 4 + 3];
      double sd = __longlong_as_double(
          (long long)(cand[tid] & 0xFFFFFFFFFFFF0000ull));
      o4 = (float)sd;
    }
    size_t ob = ((size_t)bc * K + tid) * 5;
    out[ob + 0] = o0; out[ob + 1] = o1; out[ob + 2] = o2;
    out[ob + 3] = o3; out[ob + 4] = o4;
    out[(size_t)B * NC * K * 5 + (size_t)bc * K + tid] = kkeep ? 1.f : 0.f;
  }
}

extern "C" void kernel_launch(void* const* d_in, const int* in_sizes, int n_in,
                              void* d_out, int out_size, void* d_ws, size_t ws_size,
                              hipStream_t stream) {
  (void)in_sizes; (void)n_in; (void)out_size;
  const float* conf = (const float*)d_in[0];
  const float* loc = (const float*)d_in[1];
  const float* anchor = (const float*)d_in[2];
  float* out = (float*)d_out;

  size_t nBA = (size_t)B * A;
  size_t off_sarr = 0;
  size_t off_marr = off_sarr + nBA * sizeof(double);
  size_t off_keys = off_marr + nBA * sizeof(float);
  size_t need_fast = off_keys + nBA * NC * sizeof(unsigned short);  // ~54.5 MB
  size_t need_mid = nBA * (sizeof(float) + sizeof(double));         // 12 MB

  if (ws_size >= need_fast) {
    double* sarr = (double*)((char*)d_ws + off_sarr);
    float* marr = (float*)((char*)d_ws + off_marr);
    unsigned short* keys = (unsigned short*)((char*)d_ws + off_keys);
    prep_fast<<<(B * A) / 256, 256, 0, stream>>>(conf, marr, sarr, keys);
    select2_kernel<<<B * NC, 512, 0, stream>>>(conf, marr, sarr, loc, anchor,
                                               keys, out);
  } else if (ws_size >= need_mid) {
    float* marr = (float*)d_ws;
    double* sarr = (double*)((char*)d_ws + nBA * sizeof(float));
    prep_kernel<<<(B * A) / 256, 256, 0, stream>>>(conf, marr, sarr);
    select_nms_kernel<<<B * NC, 256, 0, stream>>>(conf, marr, sarr, loc, anchor, out);
  } else {
    select_nms_kernel<<<B * NC, 256, 0, stream>>>(conf, nullptr, nullptr, loc, anchor, out);
  }
}

// Round 13
// 81.597 us; speedup vs baseline: 2.3965x; 1.0502x over previous
//
#include <hip/hip_runtime.h>

// DetectPostProcess: softmax -> decode -> per-(b,c) top-200 -> greedy NMS.
// Decisions (ordering, top-K membership, IoU>0.5) identical to rounds 2..12
// (f64 everywhere it matters; f32 IoU fast path guarded by exact f64
// recompute within |margin|<=1e-5).
// Round 13: key row register-cached (hist pass keeps all 64 keys/thread in
// 32 VGPRs; collect re-reads REGISTERS -> second 40MB key stream eliminated);
// XCD-bijective swizzle groups all classes of an image on one XCD so conf/loc
// gather lines are L2-shared.
// Outputs: objs [B,NC,K,5] then keep [B,NC,K] (as 0.0/1.0), flat in d_out.

constexpr int B = 32;
constexpr int A = 32768;     // power of two
constexpr int ABITS = 15;    // log2(A)
constexpr int NCP1 = 21;
constexpr int NC = 20;
constexpr int K = 200;
constexpr int NBIN = 576;    // key range 0x3D4C..0x3F80 = 564 values
#define KBASE 0x3D4Cu        // bits(0.05f) >> 16; min nonzero key

#define TH_CONF 0.05
#define TH_IOU  0.5

// ============================ FAST PATH =====================================
// prep_fast: per (b,a): m (f32 max), S (f64 sum), and 20 transposed u16 keys.
__global__ __launch_bounds__(256) void prep_fast(
    const float* __restrict__ conf, float* __restrict__ marr,
    double* __restrict__ sarr, unsigned short* __restrict__ keys) {
  int idx = blockIdx.x * 256 + threadIdx.x;   // 0 .. B*A-1
  int b = idx >> ABITS;
  int a = idx & (A - 1);
  const float* cp = conf + (size_t)idx * NCP1;
  float x[NCP1];
#pragma unroll
  for (int i = 0; i < NCP1; ++i) x[i] = cp[i];
  float m = x[0];
#pragma unroll
  for (int i = 1; i < NCP1; ++i) m = fmaxf(m, x[i]);
  double e[NCP1];
  double S = 0.0;
#pragma unroll
  for (int i = 0; i < NCP1; ++i) {
    e[i] = exp((double)x[i] - (double)m);
    S += e[i];
  }
  marr[idx] = m;
  sarr[idx] = S;
  double rs = 1.0 / S;
  size_t kbase = ((size_t)(b * NC) << ABITS) + a;
#pragma unroll
  for (int c = 0; c < NC; ++c) {
    double sd = e[c + 1] * rs;                 // ~1ulp from e/S; key-grade only
    unsigned short key = 0;
    if (sd >= TH_CONF) {
      float f = (float)sd;
      key = (unsigned short)(__float_as_uint(f) >> 16);
    }
    keys[kbase + ((size_t)c << ABITS)] = key;
  }
}

// f64 box decode for one anchor.
__device__ __forceinline__ void decode_d(const float* __restrict__ loc,
                                         const float* __restrict__ anchor,
                                         size_t ba, int a, double* o) {
  const float* lp = loc + ba * 4;
  const float* ap = anchor + (size_t)a * 4;
  double l0 = lp[0], l1 = lp[1], l2 = lp[2], l3 = lp[3];
  double cx = ap[0], cy = ap[1], aw = ap[2], ah = ap[3];
  double X = (l0 * 0.125) * aw + cx;
  double Y = (l1 * 0.125) * ah + cy;
  double bw = exp(l2 * 0.125) * aw;
  double bh = exp(l3 * 0.125) * ah;
  o[0] = X - bw * 0.5;
  o[1] = Y - bh * 0.5;
  o[2] = X + bw * 0.5;
  o[3] = Y + bh * 0.5;
}

// select2: one block per (b,c). Full fused selection + NMS, single key pass.
__global__ __launch_bounds__(512) void select2_kernel(
    const float* __restrict__ conf, const float* __restrict__ marr,
    const double* __restrict__ sarr, const float* __restrict__ loc,
    const float* __restrict__ anchor, const unsigned short* __restrict__ keys,
    float* __restrict__ out) {
  constexpr int NT = 512;
  __shared__ unsigned hist[NBIN];
  __shared__ unsigned wtot[8], wsuf[8];
  __shared__ unsigned long long cand[512];
  __shared__ int clist[512];
  __shared__ float4 cf4[K];             // f32 box (fast path)
  __shared__ float car[K];              // f32 area
  __shared__ double4 cd4[K];            // f64 box (guard path)
  __shared__ double dar[K];             // f64 area
  __shared__ unsigned cols[K * 8];      // column-major IoU bits: cols[j*8+w5]
  __shared__ unsigned kpw[8];           // keep bit words
  __shared__ unsigned sh_cnt, sh_selbin, sh_total;

  int tid = threadIdx.x;
  unsigned lane = tid & 63, wid = tid >> 6;

  // XCD-bijective swizzle: all 20 classes of image b on one XCD (b = B_%8 + ..)
  int B_ = blockIdx.x;
  int x8 = B_ & 7;
  int r8 = B_ >> 3;                      // 0..79
  int b = x8 + 8 * (r8 / NC);            // 0..31
  int c = r8 % NC;
  int bc = b * NC + c;
  size_t base = (size_t)b << ABITS;
  const uint4* kv = (const uint4*)(keys + ((size_t)bc << ABITS));

  if (tid == 0) sh_cnt = 0;

  // ---- 1. single key pass: load 8 uint4 (64 keys) into REGISTERS + hist ----
  for (int i = tid; i < NBIN; i += NT) hist[i] = 0;
  __syncthreads();
  uint4 kreg[8];
#pragma unroll
  for (int it = 0; it < 8; ++it) {
    int i = tid + it * NT;               // < A/8 = 4096
    uint4 v = kv[i];
    kreg[it] = v;
    unsigned w[4] = {v.x, v.y, v.z, v.w};
#pragma unroll
    for (int q = 0; q < 4; ++q) {
      unsigned lo = w[q] & 0xFFFFu, hi = w[q] >> 16;
      if (lo) atomicAdd(&hist[min(lo - KBASE, (unsigned)(NBIN - 1))], 1u);
      if (hi) atomicAdd(&hist[min(hi - KBASE, (unsigned)(NBIN - 1))], 1u);
    }
  }
  __syncthreads();

  // ---- 2. shfl suffix scan (cnt_ge) + exact 16-bit pivot ----
  unsigned h0 = 0, h1 = 0;
  if (tid < NBIN / 2) { h0 = hist[2 * tid]; h1 = hist[2 * tid + 1]; }
  unsigned s = h0 + h1;
  unsigned S = s;
#pragma unroll
  for (int d = 1; d < 64; d <<= 1) {
    unsigned o = __shfl_down(S, d, 64);
    if (lane + d < 64) S += o;
  }
  if (lane == 0) wtot[wid] = S;
  __syncthreads();
  if (tid < 8) {
    unsigned acc = 0;
    for (int w2 = tid + 1; w2 < 8; ++w2) acc += wtot[w2];
    wsuf[tid] = acc;
    if (tid == 0) sh_total = acc + wtot[0];
  }
  __syncthreads();
  unsigned Sfull = S + wsuf[wid];
  unsigned above2 = Sfull - s;
  unsigned cg1 = h1 + above2;
  unsigned cg0 = h0 + cg1;
  if (cg1 >= (unsigned)K && above2 < (unsigned)K) sh_selbin = tid * 2 + 1;
  if (cg0 >= (unsigned)K && cg1 < (unsigned)K) sh_selbin = tid * 2 + 0;
  __syncthreads();
  unsigned pivot16 = (sh_total <= (unsigned)K) ? KBASE : (KBASE + sh_selbin);

  // ---- 3. collect candidate anchor ids FROM REGISTERS (superset of top-K) --
#pragma unroll
  for (int it = 0; it < 8; ++it) {
    int i = tid + it * NT;
    uint4 v = kreg[it];
    unsigned w[4] = {v.x, v.y, v.z, v.w};
#pragma unroll
    for (int q = 0; q < 4; ++q) {
      unsigned lo = w[q] & 0xFFFFu, hi = w[q] >> 16;
      if (lo >= pivot16) {
        unsigned pos = atomicAdd(&sh_cnt, 1u);
        if (pos < 512) clist[pos] = i * 8 + q * 2 + 0;
      }
      if (hi >= pivot16) {
        unsigned pos = atomicAdd(&sh_cnt, 1u);
        if (pos < 512) clist[pos] = i * 8 + q * 2 + 1;
      }
    }
  }
  __syncthreads();
  unsigned ccount = sh_cnt < 512u ? sh_cnt : 512u;
  unsigned Ct = ccount < (unsigned)K ? ccount : (unsigned)K;

  // ---- 4. exact f64 scores for candidates; build sort keys ----
  for (int i = tid; i < 512; i += NT) {
    unsigned long long key = 0ull;
    if ((unsigned)i < ccount) {
      int a = clist[i];
      size_t ba = base + a;
      double sd = exp((double)conf[ba * NCP1 + (c + 1)] - (double)marr[ba]) / sarr[ba];
      if (sd >= TH_CONF) {
        unsigned long long db = (unsigned long long)__double_as_longlong(sd);
        key = (db & 0xFFFFFFFFFFFF0000ull) |
              (unsigned long long)(65535u - (unsigned)a);
      }
    }
    cand[i] = key;
  }
  __syncthreads();

  // ---- 5. bitonic sort desc (shfl for j<64): (score bits desc, idx asc) ----
  unsigned n2 = (ccount <= 256u) ? 256u : 512u;
  unsigned long long v = ((unsigned)tid < n2) ? cand[tid] : 0ull;
  for (unsigned k2 = 2; k2 <= n2; k2 <<= 1) {
    for (unsigned j = k2 >> 1; j > 0; j >>= 1) {
      unsigned long long p;
      if (j >= 64) {
        __syncthreads();
        if ((unsigned)tid < n2) cand[tid] = v;
        __syncthreads();
        p = ((unsigned)tid < n2) ? cand[tid ^ j] : 0ull;
      } else {
        p = __shfl_xor(v, (int)j, 64);
      }
      if ((unsigned)tid < n2) {
        bool desc = ((tid & (int)k2) == 0);
        bool lower = ((tid & (int)j) == 0);
        bool takemax = (lower == desc);
        bool vge = (v >= p);
        v = takemax ? (vge ? v : p) : (vge ? p : v);
      }
    }
  }
  __syncthreads();
  if ((unsigned)tid < n2) cand[tid] = v;
  __syncthreads();

  // ---- 6. decode candidate boxes (f64) + packed f32/f64 mirrors ----
  if ((unsigned)tid < Ct) {
    unsigned long long key = cand[tid];
    bool valid = (key >> 16) != 0ull;
    double o[4] = {0.0, 0.0, 0.0, 0.0};
    double aa = 0.0;
    if (valid) {
      unsigned a = (65535u - (unsigned)(key & 0xFFFFull)) & (A - 1);
      decode_d(loc, anchor, base + a, a, o);
      aa = (o[2] - o[0]) * (o[3] - o[1]);
    }
    cd4[tid] = make_double4(o[0], o[1], o[2], o[3]);
    dar[tid] = aa;
    cf4[tid] = make_float4((float)o[0], (float)o[1], (float)o[2], (float)o[3]);
    car[tid] = (float)aa;
  }
  __syncthreads();

  // ---- 7. IoU COLUMN words (upper triangle i<j only);
  //         f32 fast path, exact f64 guard when |margin| <= 1e-5 ----
  int Cti = (int)Ct;
  int total_jw = Cti * 7;
  for (int id = tid; id < total_jw; id += NT) {
    int j = id % Cti;
    int w5 = id / Cti;                  // 0..6
    int ilo = w5 * 32;
    unsigned bits = 0;
    if (ilo < j) {
      int ihi = (ilo + 32 < j) ? (ilo + 32) : j;
      float4 bj = cf4[j];
      float aj = car[j];
      for (int i = ilo; i < ihi; ++i) {
        float4 bi = cf4[i];
        float ltx = fmaxf(bi.x, bj.x);
        float lty = fmaxf(bi.y, bj.y);
        float rbx = fminf(bi.z, bj.z);
        float rby = fminf(bi.w, bj.w);
        float iw = fmaxf(rbx - ltx, 0.f);
        float ih = fmaxf(rby - lty, 0.f);
        float inter = iw * ih;
        float den = car[i] + aj - inter + 1e-9f;
        float dmar = inter - 0.5f * den;
        bool bit;
        if (fabsf(dmar) > 1e-5f) {
          bit = dmar > 0.f;
        } else {
          double4 Bi = cd4[i], Bj = cd4[j];
          double LTX = fmax(Bi.x, Bj.x);
          double LTY = fmax(Bi.y, Bj.y);
          double RBX = fmin(Bi.z, Bj.z);
          double RBY = fmin(Bi.w, Bj.w);
          double IW = fmax(RBX - LTX, 0.0);
          double IH = fmax(RBY - LTY, 0.0);
          double INTER = IW * IH;
          double DEN = dar[i] + dar[j] - INTER + 1e-9;
          bit = INTER > 0.5 * DEN;
        }
        if (bit) bits |= 1u << (i - ilo);
      }
    }
    cols[j * 8 + w5] = bits;
  }
  __syncthreads();

  // ---- 8. register-resident greedy scan (wave 0; matches lax.scan) ----
  if (tid < 64) {
    unsigned cb[4][7];                  // [slot][w5]; column j = slot*64 + tid
#pragma unroll
    for (int s2 = 0; s2 < 4; ++s2) {
      int j = s2 * 64 + tid;
#pragma unroll
      for (int w5 = 0; w5 < 7; ++w5)
        cb[s2][w5] = (j < Cti) ? cols[j * 8 + w5] : 0u;
    }
    unsigned sup[4] = {0u, 0u, 0u, 0u}; // suppressed flag per owned column
    unsigned kw[7] = {0u, 0u, 0u, 0u, 0u, 0u, 0u};
#pragma unroll
    for (int w5 = 0; w5 < 7; ++w5) {
      const int slot = w5 >> 1;
#pragma unroll
      for (int ii = 0; ii < 32; ++ii) {
        int i = w5 * 32 + ii;
        if (i < Cti) {
          int lane2 = (w5 & 1) * 32 + ii;           // = i & 63 (uniform)
          unsigned sflag = (unsigned)__builtin_amdgcn_readlane(
              (int)sup[slot], lane2);
          unsigned km = (sflag == 0u) ? 0xFFFFFFFFu : 0u;
          kw[w5] |= (km & 1u) << ii;
#pragma unroll
          for (int s2 = 0; s2 < 4; ++s2)
            sup[s2] |= ((cb[s2][w5] >> ii) & 1u) & km;
        }
      }
    }
    if (tid == 0) {
#pragma unroll
      for (int w5 = 0; w5 < 7; ++w5) kpw[w5] = kw[w5];
      kpw[7] = 0u;
    }
  }
  __syncthreads();

  // ---- 9. write objs + keep ----
  if (tid < K) {
    bool kkeep = ((unsigned)tid < Ct) &&
                 (((kpw[tid >> 5] >> (tid & 31)) & 1u) != 0u) &&
                 ((cand[tid] >> 16) != 0ull);
    float o0 = 0.f, o1v = 0.f, o2v = 0.f, o3v = 0.f, o4 = 0.f;
    if (kkeep) {
      double4 Bi = cd4[tid];
      o0 = (float)Bi.x; o1v = (float)Bi.y; o2v = (float)Bi.z; o3v = (float)Bi.w;
      double sd = __longlong_as_double(
          (long long)(cand[tid] & 0xFFFFFFFFFFFF0000ull));
      o4 = (float)sd;
    }
    size_t ob = ((size_t)bc * K + tid) * 5;
    out[ob + 0] = o0; out[ob + 1] = o1v; out[ob + 2] = o2v;
    out[ob + 3] = o3v; out[ob + 4] = o4;
    out[(size_t)B * NC * K * 5 + (size_t)bc * K + tid] = kkeep ? 1.f : 0.f;
  }
}

// ============================ FALLBACK PATH (round-2, passing) ==============
__global__ __launch_bounds__(256) void prep_kernel(
    const float* __restrict__ conf, float* __restrict__ marr,
    double* __restrict__ sarr) {
  int idx = blockIdx.x * 256 + threadIdx.x;
  const float* cp = conf + (size_t)idx * NCP1;
  float x[NCP1];
#pragma unroll
  for (int i = 0; i < NCP1; ++i) x[i] = cp[i];
  float m = x[0];
#pragma unroll
  for (int i = 1; i < NCP1; ++i) m = fmaxf(m, x[i]);
  double S = 0.0;
#pragma unroll
  for (int i = 0; i < NCP1; ++i) S += exp((double)x[i] - (double)m);
  marr[idx] = m;
  sarr[idx] = S;
}

__device__ __forceinline__ double get_sd(const float* __restrict__ conf,
                                         const float* __restrict__ marr,
                                         const double* __restrict__ sarr,
                                         size_t ba, int c) {
  const float* cp = conf + ba * NCP1;
  float m;
  double S;
  if (sarr) {
    m = marr[ba];
    S = sarr[ba];
  } else {
    m = cp[0];
    for (int i = 1; i < NCP1; ++i) m = fmaxf(m, cp[i]);
    S = 0.0;
    for (int i = 0; i < NCP1; ++i) S += exp((double)cp[i] - (double)m);
  }
  return exp((double)cp[c + 1] - (double)m) / S;
}

__global__ __launch_bounds__(256) void select_nms_kernel(
    const float* __restrict__ conf, const float* __restrict__ marr,
    const double* __restrict__ sarr, const float* __restrict__ loc,
    const float* __restrict__ anchor, float* __restrict__ out) {
  __shared__ __align__(16) unsigned short s16[A];
  __shared__ unsigned hist[256];
  __shared__ unsigned scan0[256];
  __shared__ unsigned long long cand[512];
  __shared__ unsigned sh_cnt, sh_selbin, sh_need, sh_ctot;

  double* cbd = (double*)s16;
  double* ar = cbd + K * 4;
  unsigned* rows = (unsigned*)(ar + K);
  unsigned* kp = rows + K * 8;

  int tid = threadIdx.x;
  int bc = blockIdx.x;
  int b = bc / NC, c = bc % NC;
  size_t base = (size_t)b << ABITS;

  for (int a = tid; a < A; a += 256) {
    double sd = get_sd(conf, marr, sarr, base + a, c);
    unsigned short key = 0;
    if (sd >= TH_CONF) {
      float f = (float)sd;
      key = (unsigned short)(__float_as_uint(f) >> 16);
    }
    s16[a] = key;
  }
  __syncthreads();

  unsigned need = K, pfx = 0;
  bool smallcase = false;
  for (int p = 0; p < 2; ++p) {
    hist[tid] = 0;
    __syncthreads();
    for (int a = tid; a < A; a += 256) {
      unsigned v = s16[a];
      if (v && (p == 0 || (v >> 8) == pfx))
        atomicAdd(&hist[(p == 0) ? (v >> 8) : (v & 0xFFu)], 1u);
    }
    __syncthreads();
    scan0[tid] = hist[tid];
    __syncthreads();
    for (int st = 1; st < 256; st <<= 1) {
      unsigned mine = scan0[tid];
      unsigned oth = (tid + st < 256) ? scan0[tid + st] : 0u;
      __syncthreads();
      scan0[tid] = mine + oth;
      __syncthreads();
    }
    if (p == 0) {
      if (tid == 0) sh_ctot = scan0[0];
      __syncthreads();
      if (sh_ctot <= (unsigned)K) { smallcase = true; break; }
    }
    unsigned nxt = (tid == 255) ? 0u : scan0[tid + 1];
    if (scan0[tid] >= need && nxt < need) { sh_selbin = tid; sh_need = need - nxt; }
    __syncthreads();
    pfx = (pfx << 8) | sh_selbin;
    need = sh_need;
    __syncthreads();
  }
  unsigned pivot16 = smallcase ? 0x3D4Cu : pfx;

  if (tid == 0) sh_cnt = 0;
  __syncthreads();
  for (int a = tid; a < A; a += 256) {
    double sd = get_sd(conf, marr, sarr, base + a, c);
    if (sd >= TH_CONF) {
      float f = (float)sd;
      if ((__float_as_uint(f) >> 16) >= pivot16) {
        unsigned pos = atomicAdd(&sh_cnt, 1u);
        if (pos < 512) {
          unsigned long long db = (unsigned long long)__double_as_longlong(sd);
          cand[pos] = (db & 0xFFFFFFFFFFFF0000ull) |
                      (unsigned long long)(65535u - (unsigned)a);
        }
      }
    }
  }
  __syncthreads();
  unsigned ccount = sh_cnt < 512u ? sh_cnt : 512u;
  unsigned Ct = ccount < (unsigned)K ? ccount : (unsigned)K;
  for (int i = tid; i < 512; i += 256)
    if ((unsigned)i >= ccount) cand[i] = 0ull;
  __syncthreads();

  for (unsigned k2 = 2; k2 <= 512; k2 <<= 1) {
    for (unsigned j = k2 >> 1; j > 0; j >>= 1) {
      for (unsigned i = tid; i < 512; i += 256) {
        unsigned ixj = i ^ j;
        if (ixj > i) {
          unsigned long long va = cand[i], vb = cand[ixj];
          bool desc = ((i & k2) == 0);
          if (desc ? (va < vb) : (va > vb)) { cand[i] = vb; cand[ixj] = va; }
        }
      }
      __syncthreads();
    }
  }

  if ((unsigned)tid < Ct) {
    unsigned a = 65535u - (unsigned)(cand[tid] & 0xFFFFull);
    double o[4];
    decode_d(loc, anchor, base + a, a, o);
    cbd[tid * 4 + 0] = o[0]; cbd[tid * 4 + 1] = o[1];
    cbd[tid * 4 + 2] = o[2]; cbd[tid * 4 + 3] = o[3];
    ar[tid] = (o[2] - o[0]) * (o[3] - o[1]);
  }
  __syncthreads();

  for (int id = tid; id < (int)Ct * 8; id += 256) {
    int i = id >> 3, w = id & 7;
    double xi0 = cbd[i * 4 + 0], yi0 = cbd[i * 4 + 1];
    double xi1 = cbd[i * 4 + 2], yi1 = cbd[i * 4 + 3];
    double ai = ar[i];
    unsigned bits = 0;
    int j0 = w * 32;
    for (int jj = 0; jj < 32; ++jj) {
      int j = j0 + jj;
      if (j < (int)Ct) {
        double ltx = fmax(xi0, cbd[j * 4 + 0]);
        double lty = fmax(yi0, cbd[j * 4 + 1]);
        double rbx = fmin(xi1, cbd[j * 4 + 2]);
        double rby = fmin(yi1, cbd[j * 4 + 3]);
        double iw = fmax(rbx - ltx, 0.0);
        double ih = fmax(rby - lty, 0.0);
        double inter = iw * ih;
        double iou = inter / (ai + ar[j] - inter + 1e-9);
        if (iou > TH_IOU) bits |= (1u << jj);
      }
    }
    rows[i * 8 + w] = bits;
  }
  __syncthreads();

  if (tid < 64) {
    unsigned supp = 0;
    for (int i = 0; i < (int)Ct; ++i) {
      unsigned wsrc = __shfl(supp, i >> 5);
      bool kkeep = ((wsrc >> (i & 31)) & 1u) == 0u;
      if (tid == 0) kp[i] = kkeep ? 1u : 0u;
      unsigned rw = (tid < 8) ? rows[i * 8 + tid] : 0u;
      if (kkeep) supp |= rw;
    }
  }
  __syncthreads();

  if (tid < K) {
    bool kkeep = ((unsigned)tid < Ct) && (kp[tid] != 0u);
    float o0 = 0.f, o1 = 0.f, o2 = 0.f, o3 = 0.f, o4 = 0.f;
    if (kkeep) {
      o0 = (float)cbd[tid * 4 + 0]; o1 = (float)cbd[tid * 4 + 1];
      o2 = (float)cbd[tid * 4 + 2]; o3 = (float)cbd[tid * 4 + 3];
      double sd = __longlong_as_double(
          (long long)(cand[tid] & 0xFFFFFFFFFFFF0000ull));
      o4 = (float)sd;
    }
    size_t ob = ((size_t)bc * K + tid) * 5;
    out[ob + 0] = o0; out[ob + 1] = o1; out[ob + 2] = o2;
    out[ob + 3] = o3; out[ob + 4] = o4;
    out[(size_t)B * NC * K * 5 + (size_t)bc * K + tid] = kkeep ? 1.f : 0.f;
  }
}

extern "C" void kernel_launch(void* const* d_in, const int* in_sizes, int n_in,
                              void* d_out, int out_size, void* d_ws, size_t ws_size,
                              hipStream_t stream) {
  (void)in_sizes; (void)n_in; (void)out_size;
  const float* conf = (const float*)d_in[0];
  const float* loc = (const float*)d_in[1];
  const float* anchor = (const float*)d_in[2];
  float* out = (float*)d_out;

  size_t nBA = (size_t)B * A;
  size_t off_sarr = 0;
  size_t off_marr = off_sarr + nBA * sizeof(double);
  size_t off_keys = off_marr + nBA * sizeof(float);
  size_t need_fast = off_keys + nBA * NC * sizeof(unsigned short);  // ~54.5 MB
  size_t need_mid = nBA * (sizeof(float) + sizeof(double));         // 12 MB

  if (ws_size >= need_fast) {
    double* sarr = (double*)((char*)d_ws + off_sarr);
    float* marr = (float*)((char*)d_ws + off_marr);
    unsigned short* keys = (unsigned short*)((char*)d_ws + off_keys);
    prep_fast<<<(B * A) / 256, 256, 0, stream>>>(conf, marr, sarr, keys);
    select2_kernel<<<B * NC, 512, 0, stream>>>(conf, marr, sarr, loc, anchor,
                                               keys, out);
  } else if (ws_size >= need_mid) {
    float* marr = (float*)d_ws;
    double* sarr = (double*)((char*)d_ws + nBA * sizeof(float));
    prep_kernel<<<(B * A) / 256, 256, 0, stream>>>(conf, marr, sarr);
    select_nms_kernel<<<B * NC, 256, 0, stream>>>(conf, marr, sarr, loc, anchor, out);
  } else {
    select_nms_kernel<<<B * NC, 256, 0, stream>>>(conf, nullptr, nullptr, loc, anchor, out);
  }
}